// Round 1
// baseline (683.149 us; speedup 1.0000x reference)
//
#include <hip/hip_runtime.h>

#define NB 8
#define NWAY 16
#define NBASE 8000
#define FEAT 512
#define SEM 300
#define CAT (FEAT + SEM)  // 812
#define HLD 304           // padded h leading dim (16B-aligned rows)

typedef __attribute__((ext_vector_type(8))) short bf16x8;
typedef __attribute__((ext_vector_type(4))) float f32x4;
typedef __attribute__((ext_vector_type(8))) unsigned short us8;
typedef __attribute__((ext_vector_type(4))) unsigned short us4;
typedef __attribute__((ext_vector_type(2))) unsigned short us2;
typedef unsigned short us;

__device__ __forceinline__ us f2bf(float x) {
    union { float f; unsigned int u; } v; v.f = x;
    unsigned int r = v.u + 0x7FFFu + ((v.u >> 16) & 1u);
    return (us)(r >> 16);
}
__device__ __forceinline__ float bf2f(us u) {
    union { unsigned int u; float f; } v; v.u = ((unsigned int)u) << 16;
    return v.f;
}

// =============== workspace byte offsets (all 16B aligned) ===============
constexpr long O_BWH   = 0L;            // 8*8000*512*2 = 65,536,000
constexpr long O_H     = 65536000L;     // 8*8000*304*2 = 38,912,000
constexpr long O_W1T   = 104448000L;    // 320*320*2 = 204,800
constexpr long O_W2T   = 104652800L;    // 204,800
constexpr long O_QWT   = 104857600L;    // 512*832*2 = 851,968
constexpr long O_WVST  = 106496000L;    // 512*512*2 = 524,288
constexpr long O_FCWT  = 107020288L;    // 524,288
constexpr long O_PQT   = 107544576L;    // 8*16*840*2 = 215,040
constexpr long O_PMAX  = 107759616L;    // 8*16*63*4 = 32,256
constexpr long O_PSUM  = 107791872L;    // 32,256
constexpr long O_RMAX  = 107824128L;    // 512
constexpr long O_RINV  = 107824640L;    // 512
constexpr long O_F     = 107825152L;
constexpr long O_MBW   = O_F;            // 16,384 (mbw) + 9,600 (mh) contiguous
constexpr long O_MH    = O_F + 16384;
constexpr long O_GV    = O_F + 25984;    // 16,384
constexpr long O_GS    = O_F + 42368;    // 9,600
constexpr long O_PSEMR = O_F + 77952;    // 128*304*4 = 155,648 (raw psem, f32)
constexpr long O_OV    = O_F + 233600;   // 128*512*4 = 262,144 (ov accumulator)
constexpr long O_QVISR = O_F + 540800;   // 128*512*4 = 262,144 (raw qvis, f32)
constexpr long O_CC    = O_F + 802944;   // 512

// =============== weight prep: bf16 transposes (+ case 5: zero mbw/mh) ===============
__global__ void k_prep(const float* __restrict__ w1, const float* __restrict__ w2,
                       const float* __restrict__ wqs, const float* __restrict__ wqss,
                       const float* __restrict__ wvs, const float* __restrict__ fcw,
                       us* __restrict__ w1t, us* __restrict__ w2t, us* __restrict__ qwT,
                       us* __restrict__ wvsT, us* __restrict__ fcwT, float* __restrict__ mz) {
    long e = (long)blockIdx.x * 256 + threadIdx.x;
    switch (blockIdx.y) {
    case 0: if (e < 320 * 320) { int n = e / 320, k = e % 320;
            w1t[e] = f2bf((n < SEM && k < SEM) ? w1[(long)k * SEM + n] : 0.f); } break;
    case 1: if (e < 320 * 320) { int n = e / 320, k = e % 320;
            w2t[e] = f2bf((n < SEM && k < SEM) ? w2[(long)k * SEM + n] : 0.f); } break;
    case 2: if (e < 512 * 832) { int n = e / 832, k = e % 832;
            float v = 0.f;
            if (k < FEAT) v = wqs[(long)k * FEAT + n];
            else if (k < CAT) v = wqss[(long)(k - FEAT) * FEAT + n];
            qwT[e] = f2bf(v); } break;
    case 3: if (e < 512 * 512) { int n = e / 512, k = e % 512;
            wvsT[e] = f2bf(wvs[(long)k * FEAT + n]); } break;
    case 4: if (e < 512 * 512) { int n = e / 512, k = e % 512;
            fcwT[e] = f2bf(fcw[(long)k * FEAT + n]); } break;
    case 5: if (e < NB * FEAT + NB * SEM) mz[e] = 0.f; break;
    }
}

// =============== bw -> bf16 + column sums: unroll-4, LDS-reduced atomics ===============
__global__ void k_cvt_bw(const float* __restrict__ bw, us* __restrict__ bwh,
                         float* __restrict__ mbw) {
    __shared__ float red[128][4];
    int b = blockIdx.x, ch = blockIdx.y;  // 125 chunks of 64 rows
    int t = threadIdx.x;
    int cg = t & 127, rs = t >> 7;
    long base = ((long)b * NBASE + (long)ch * 64) * FEAT + cg * 4;
    float s0 = 0.f, s1 = 0.f, s2 = 0.f, s3 = 0.f;
    for (int r0 = rs * 4; r0 < 64; r0 += 8) {
        float4 v[4];
        #pragma unroll
        for (int u = 0; u < 4; ++u)
            v[u] = *(const float4*)(bw + base + (long)(r0 + u) * FEAT);
        #pragma unroll
        for (int u = 0; u < 4; ++u) {
            us4 o; o.x = f2bf(v[u].x); o.y = f2bf(v[u].y); o.z = f2bf(v[u].z); o.w = f2bf(v[u].w);
            *(us4*)(bwh + base + (long)(r0 + u) * FEAT) = o;
            s0 += v[u].x; s1 += v[u].y; s2 += v[u].z; s3 += v[u].w;
        }
    }
    if (rs == 1) { red[cg][0] = s0; red[cg][1] = s1; red[cg][2] = s2; red[cg][3] = s3; }
    __syncthreads();
    if (rs == 0) {
        atomicAdd(&mbw[b * FEAT + cg * 4 + 0], s0 + red[cg][0]);
        atomicAdd(&mbw[b * FEAT + cg * 4 + 1], s1 + red[cg][1]);
        atomicAdd(&mbw[b * FEAT + cg * 4 + 2], s2 + red[cg][2]);
        atomicAdd(&mbw[b * FEAT + cg * 4 + 3], s3 + red[cg][3]);
    }
}

// =============== h = leaky(bsm @ W1 + b1), BM=128, per-batch grid (63, NB) ===============
__global__ __launch_bounds__(256, 2) void k_hgemm_mfma(const float* __restrict__ X,
        const us* __restrict__ W1T, const float* __restrict__ b1,
        us* __restrict__ H, float* __restrict__ mh) {
    __shared__ char smem[128 * 304 * 2];  // 77,824 B
    us (*As)[72] = (us(*)[72])smem;                    // 128*72*2 = 18,432
    us (*Bs)[72] = (us(*)[72])(smem + 18432);          // 320*72*2 = 46,080
    us (*Cs)[HLD] = (us(*)[HLD])smem;                  // epilogue alias
    const int b = blockIdx.y;
    const int bm = blockIdx.x * 128;
    const int t = threadIdx.x;
    const int wv = t >> 6, lane = t & 63;
    const int m16 = lane & 15, q = lane >> 4;
    const long rowbase = (long)b * NBASE;
    f32x4 acc[8][5];
    #pragma unroll
    for (int i = 0; i < 8; ++i)
        #pragma unroll
        for (int j = 0; j < 5; ++j) acc[i][j] = (f32x4){0.f, 0.f, 0.f, 0.f};
    for (int ks = 0; ks < 5; ++ks) {
        const int k0 = ks * 64;
        #pragma unroll
        for (int it = 0; it < 8; ++it) {
            int c = t + it * 256;
            int row = c >> 4, j = c & 15;
            int gk = k0 + j * 4;
            float4 v = make_float4(0.f, 0.f, 0.f, 0.f);
            if (gk < SEM && bm + row < NBASE)
                v = *(const float4*)(X + (rowbase + bm + row) * SEM + gk);
            us4 u; u.x = f2bf(v.x); u.y = f2bf(v.y); u.z = f2bf(v.z); u.w = f2bf(v.w);
            *(us4*)(&As[row][j * 4]) = u;
        }
        #pragma unroll
        for (int it = 0; it < 10; ++it) {
            int c = t + it * 256;
            int n = c >> 3, j = c & 7;
            int4 v = *(const int4*)(W1T + (long)n * 320 + k0 + j * 8);
            *(int4*)(&Bs[n][j * 8]) = v;
        }
        __syncthreads();
        #pragma unroll
        for (int kc = 0; kc < 64; kc += 32) {
            bf16x8 a[8], bb[5];
            #pragma unroll
            for (int rt = 0; rt < 8; ++rt)
                a[rt] = *(const bf16x8*)(&As[rt * 16 + m16][kc + q * 8]);
            #pragma unroll
            for (int ct = 0; ct < 5; ++ct)
                bb[ct] = *(const bf16x8*)(&Bs[(wv * 5 + ct) * 16 + m16][kc + q * 8]);
            #pragma unroll
            for (int rt = 0; rt < 8; ++rt)
                #pragma unroll
                for (int ct = 0; ct < 5; ++ct)
                    acc[rt][ct] = __builtin_amdgcn_mfma_f32_16x16x32_bf16(a[rt], bb[ct], acc[rt][ct], 0, 0, 0);
        }
        __syncthreads();
    }
    float csum[5] = {0.f, 0.f, 0.f, 0.f, 0.f};
    #pragma unroll
    for (int ct = 0; ct < 5; ++ct) {
        int col = (wv * 5 + ct) * 16 + m16;
        float bias = (col < SEM) ? b1[col] : 0.f;
        #pragma unroll
        for (int rt = 0; rt < 8; ++rt) {
            int rl = rt * 16 + q * 4;
            #pragma unroll
            for (int r = 0; r < 4; ++r) {
                float v = acc[rt][ct][r] + bias;
                v = v > 0.f ? v : 0.1f * v;
                if (col < SEM && bm + rl + r < NBASE) {
                    Cs[rl + r][col] = f2bf(v);
                    csum[ct] += v;
                }
            }
        }
    }
    if (t < 128) *(us4*)(&Cs[t][300]) = (us4){0, 0, 0, 0};
    #pragma unroll
    for (int ct = 0; ct < 5; ++ct) {
        float s = csum[ct];
        s += __shfl_xor(s, 16);
        s += __shfl_xor(s, 32);
        int col = (wv * 5 + ct) * 16 + m16;
        if (q == 0 && col < SEM) atomicAdd(&mh[b * SEM + col], s);
    }
    __syncthreads();
    for (int i = t; i < 128 * 76; i += 256) {
        int row = i / 76, j = i % 76;
        if (bm + row < NBASE)
            *(us4*)(H + (rowbase + bm + row) * HLD + j * 4) = *(const us4*)(&Cs[row][j * 4]);
    }
}

// =============== fused avg + gates: grid (13, NB) ===============
__global__ void k_gates(const float* __restrict__ mbw, const float* __restrict__ mh,
                        const float* __restrict__ mw2, const float* __restrict__ mb2,
                        const float* __restrict__ vfw, const float* __restrict__ vfb,
                        const float* __restrict__ sfw, const float* __restrict__ sfb,
                        float* __restrict__ gv, float* __restrict__ gs) {
    int tile = blockIdx.x, b = blockIdx.y, t = threadIdx.x;
    __shared__ float avgL[CAT];
    __shared__ float mhL[SEM];
    __shared__ float red[4][64];
    const float invN = 1.0f / NBASE;
    for (int i = t; i < SEM; i += 256) mhL[i] = mh[b * SEM + i] * invN;
    for (int i = t; i < FEAT; i += 256) avgL[i] = mbw[b * FEAT + i] * invN;
    __syncthreads();
    for (int s = t; s < SEM; s += 256) {
        float a = mb2[s];
        for (int c = 0; c < SEM; ++c) a += mhL[c] * mw2[(long)c * SEM + s];
        avgL[FEAT + s] = a;
    }
    __syncthreads();
    int l = t & 63, kq = t >> 6;
    float a = 0.f;
    if (tile < 8) {
        int f = tile * 64 + l;
        for (int c = kq * 203; c < kq * 203 + 203; ++c) a += avgL[c] * vfw[(long)c * FEAT + f];
        red[kq][l] = a;
        __syncthreads();
        if (kq == 0) {
            float s = red[0][l] + red[1][l] + red[2][l] + red[3][l] + vfb[f];
            gv[b * FEAT + f] = 1.f + 1.f / (1.f + expf(-s));
        }
    } else {
        int fs = (tile - 8) * 64 + l;
        if (fs < SEM)
            for (int c = kq * 203; c < kq * 203 + 203; ++c) a += avgL[c] * sfw[(long)c * SEM + fs];
        red[kq][l] = a;
        __syncthreads();
        if (kq == 0 && fs < SEM) {
            float s = red[0][l] + red[1][l] + red[2][l] + red[3][l] + sfb[fs];
            gs[b * SEM + fs] = 1.f + 1.f / (1.f + expf(-s));
        }
    }
}

// =============== fused support chain: MLP -> ssc -> qtot -> qvis_raw/psem_raw ===============
// One block per batch b (16 rows). All intermediates stay in LDS.
__global__ __launch_bounds__(256) void k_support(
        const float* __restrict__ ssm, const float* __restrict__ sf,
        const us* __restrict__ w1t, const us* __restrict__ w2t,
        const float* __restrict__ b1, const float* __restrict__ b2,
        const us* __restrict__ qwT, const float* __restrict__ wks,
        const float* __restrict__ wkss,
        float* __restrict__ qvisr, float* __restrict__ psemr) {
    __shared__ us Ss[16][328];   // ssm bf16, padded (stride 656B -> conflict-free)
    __shared__ us H1[16][328];   // hidden layer
    __shared__ us Aq[16][840];   // [sf(512) | ssc(300) | zeros] padded
    __shared__ us Qs[16][520];   // qtot bf16
    const int bx = blockIdx.x;
    const int t = threadIdx.x;
    const int wv = t >> 6, lane = t & 63;
    const int m16 = lane & 15, q = lane >> 4;
    const long r0 = (long)bx * NWAY;

    // phase 1: stage ssm -> Ss (zero-pad to 328), sf -> Aq[:,0:512], zero Aq[:,812:840)
    for (int i = t; i < 16 * 82; i += 256) {
        int r = i / 82, c4 = (i % 82) * 4;
        us4 u = (us4){0, 0, 0, 0};
        if (c4 < SEM) {
            float4 v = *(const float4*)(ssm + (r0 + r) * SEM + c4);
            u.x = f2bf(v.x); u.y = f2bf(v.y); u.z = f2bf(v.z); u.w = f2bf(v.w);
        }
        *(us4*)(&Ss[r][c4]) = u;
    }
    for (int i = t; i < 16 * 128; i += 256) {
        int r = i >> 7, c4 = (i & 127) * 4;
        float4 v = *(const float4*)(sf + (r0 + r) * FEAT + c4);
        us4 u; u.x = f2bf(v.x); u.y = f2bf(v.y); u.z = f2bf(v.z); u.w = f2bf(v.w);
        *(us4*)(&Aq[r][c4]) = u;
    }
    for (int i = t; i < 16 * 28; i += 256) Aq[i / 28][812 + (i % 28)] = 0;
    __syncthreads();

    // phase 2: H1 = leaky(Ss @ w1t^T + b1); per-wave N-slice of 80 cols
    {
        f32x4 acc[5];
        #pragma unroll
        for (int i = 0; i < 5; ++i) acc[i] = (f32x4){0.f, 0.f, 0.f, 0.f};
        for (int ks = 0; ks < 10; ++ks) {
            bf16x8 a = *(const bf16x8*)(&Ss[m16][ks * 32 + q * 8]);
            #pragma unroll
            for (int ct = 0; ct < 5; ++ct) {
                int nr = wv * 80 + ct * 16 + m16;
                bf16x8 bb = *(const bf16x8*)(w1t + (long)nr * 320 + ks * 32 + q * 8);
                acc[ct] = __builtin_amdgcn_mfma_f32_16x16x32_bf16(a, bb, acc[ct], 0, 0, 0);
            }
        }
        #pragma unroll
        for (int ct = 0; ct < 5; ++ct) {
            int col = wv * 80 + ct * 16 + m16;
            float bias = (col < SEM) ? b1[col] : 0.f;
            #pragma unroll
            for (int r = 0; r < 4; ++r) {
                float v = acc[ct][r] + bias;
                v = v > 0.f ? v : 0.1f * v;
                H1[q * 4 + r][col] = (col < SEM) ? f2bf(v) : (us)0;
            }
        }
    }
    __syncthreads();

    // phase 3: ssc = H1 @ w2t^T + b2 -> Aq[:,512:812)
    {
        f32x4 acc[5];
        #pragma unroll
        for (int i = 0; i < 5; ++i) acc[i] = (f32x4){0.f, 0.f, 0.f, 0.f};
        for (int ks = 0; ks < 10; ++ks) {
            bf16x8 a = *(const bf16x8*)(&H1[m16][ks * 32 + q * 8]);
            #pragma unroll
            for (int ct = 0; ct < 5; ++ct) {
                int nr = wv * 80 + ct * 16 + m16;
                bf16x8 bb = *(const bf16x8*)(w2t + (long)nr * 320 + ks * 32 + q * 8);
                acc[ct] = __builtin_amdgcn_mfma_f32_16x16x32_bf16(a, bb, acc[ct], 0, 0, 0);
            }
        }
        #pragma unroll
        for (int ct = 0; ct < 5; ++ct) {
            int col = wv * 80 + ct * 16 + m16;
            if (col < SEM) {
                float bias = b2[col];
                #pragma unroll
                for (int r = 0; r < 4; ++r)
                    Aq[q * 4 + r][512 + col] = f2bf(acc[ct][r] + bias);
            }
        }
    }
    __syncthreads();

    // phase 4: qtot = Aq @ qwT^T (K=832) -> Qs; per-wave N-slice of 128
    {
        f32x4 acc[8];
        #pragma unroll
        for (int i = 0; i < 8; ++i) acc[i] = (f32x4){0.f, 0.f, 0.f, 0.f};
        for (int ks = 0; ks < 26; ++ks) {
            bf16x8 a = *(const bf16x8*)(&Aq[m16][ks * 32 + q * 8]);
            #pragma unroll
            for (int ct = 0; ct < 8; ++ct) {
                int nr = wv * 128 + ct * 16 + m16;
                bf16x8 bb = *(const bf16x8*)(qwT + (long)nr * 832 + ks * 32 + q * 8);
                acc[ct] = __builtin_amdgcn_mfma_f32_16x16x32_bf16(a, bb, acc[ct], 0, 0, 0);
            }
        }
        #pragma unroll
        for (int ct = 0; ct < 8; ++ct) {
            int col = wv * 128 + ct * 16 + m16;
            #pragma unroll
            for (int r = 0; r < 4; ++r) Qs[q * 4 + r][col] = f2bf(acc[ct][r]);
        }
    }
    __syncthreads();

    // phase 5: qvis_raw = Qs @ wks^T (fp32 B), N=512
    {
        f32x4 acc[8];
        #pragma unroll
        for (int i = 0; i < 8; ++i) acc[i] = (f32x4){0.f, 0.f, 0.f, 0.f};
        for (int ks = 0; ks < 16; ++ks) {
            bf16x8 a = *(const bf16x8*)(&Qs[m16][ks * 32 + q * 8]);
            #pragma unroll
            for (int ct = 0; ct < 8; ++ct) {
                int nr = wv * 128 + ct * 16 + m16;
                const float* bp = wks + (long)nr * FEAT + ks * 32 + q * 8;
                float4 x = *(const float4*)bp;
                float4 y = *(const float4*)(bp + 4);
                bf16x8 bb;
                bb[0] = (short)f2bf(x.x); bb[1] = (short)f2bf(x.y);
                bb[2] = (short)f2bf(x.z); bb[3] = (short)f2bf(x.w);
                bb[4] = (short)f2bf(y.x); bb[5] = (short)f2bf(y.y);
                bb[6] = (short)f2bf(y.z); bb[7] = (short)f2bf(y.w);
                acc[ct] = __builtin_amdgcn_mfma_f32_16x16x32_bf16(a, bb, acc[ct], 0, 0, 0);
            }
        }
        #pragma unroll
        for (int ct = 0; ct < 8; ++ct) {
            int col = wv * 128 + ct * 16 + m16;
            #pragma unroll
            for (int r = 0; r < 4; ++r)
                qvisr[(r0 + q * 4 + r) * FEAT + col] = acc[ct][r];
        }
    }

    // phase 6: psem_raw = Qs @ wkss^T (fp32 B), N=300
    {
        f32x4 acc[5];
        #pragma unroll
        for (int i = 0; i < 5; ++i) acc[i] = (f32x4){0.f, 0.f, 0.f, 0.f};
        for (int ks = 0; ks < 16; ++ks) {
            bf16x8 a = *(const bf16x8*)(&Qs[m16][ks * 32 + q * 8]);
            #pragma unroll
            for (int ct = 0; ct < 5; ++ct) {
                int nr = wv * 80 + ct * 16 + m16;
                bf16x8 bb = (bf16x8){0, 0, 0, 0, 0, 0, 0, 0};
                if (nr < SEM) {
                    const float* bp = wkss + (long)nr * FEAT + ks * 32 + q * 8;
                    float4 x = *(const float4*)bp;
                    float4 y = *(const float4*)(bp + 4);
                    bb[0] = (short)f2bf(x.x); bb[1] = (short)f2bf(x.y);
                    bb[2] = (short)f2bf(x.z); bb[3] = (short)f2bf(x.w);
                    bb[4] = (short)f2bf(y.x); bb[5] = (short)f2bf(y.y);
                    bb[6] = (short)f2bf(y.z); bb[7] = (short)f2bf(y.w);
                }
                acc[ct] = __builtin_amdgcn_mfma_f32_16x16x32_bf16(a, bb, acc[ct], 0, 0, 0);
            }
        }
        #pragma unroll
        for (int ct = 0; ct < 5; ++ct) {
            int col = wv * 80 + ct * 16 + m16;
            if (col < SEM) {
                #pragma unroll
                for (int r = 0; r < 4; ++r)
                    psemr[(r0 + q * 4 + r) * HLD + col] = acc[ct][r];
            }
        }
    }
}

// =============== post-gate: pqt assembly + psem@W2^T + cconst ===============
__global__ __launch_bounds__(256) void k_s2(
        const float* __restrict__ qvisr, const float* __restrict__ psemr,
        const float* __restrict__ gv, const float* __restrict__ gs,
        const float* __restrict__ mw2, const float* __restrict__ b2,
        us* __restrict__ pqt, float* __restrict__ cconst) {
    __shared__ us Ps[16][328];     // gated psem bf16
    __shared__ float Psf[16][304]; // gated psem f32 (for cconst)
    const int bx = blockIdx.x;
    const int t = threadIdx.x;
    const int wv = t >> 6, lane = t & 63;
    const int m16 = lane & 15, q = lane >> 4;
    const long r0 = (long)bx * NWAY;
    for (int i = t; i < 16 * 82; i += 256) {
        int r = i / 82, c4 = (i % 82) * 4;
        us4 u = (us4){0, 0, 0, 0};
        if (c4 < SEM) {
            float4 v = *(const float4*)(psemr + (r0 + r) * HLD + c4);
            float4 g = *(const float4*)(gs + bx * SEM + c4);
            float p0 = v.x * g.x, p1 = v.y * g.y, p2 = v.z * g.z, p3 = v.w * g.w;
            Psf[r][c4 + 0] = p0; Psf[r][c4 + 1] = p1;
            Psf[r][c4 + 2] = p2; Psf[r][c4 + 3] = p3;
            u.x = f2bf(p0); u.y = f2bf(p1); u.z = f2bf(p2); u.w = f2bf(p3);
        }
        *(us4*)(&Ps[r][c4]) = u;
    }
    for (int i = t; i < 16 * 128; i += 256) {
        int r = i >> 7, c4 = (i & 127) * 4;
        float4 v = *(const float4*)(qvisr + (r0 + r) * FEAT + c4);
        float4 g = *(const float4*)(gv + bx * FEAT + c4);
        us4 u; u.x = f2bf(v.x * g.x); u.y = f2bf(v.y * g.y);
        u.z = f2bf(v.z * g.z); u.w = f2bf(v.w * g.w);
        *(us4*)(pqt + (r0 + r) * 840 + c4) = u;
    }
    for (int i = t; i < 16 * 28; i += 256) pqt[(r0 + i / 28) * 840 + 812 + (i % 28)] = 0;
    __syncthreads();
    {
        int w = t >> 4, l = t & 15;
        float a = 0.f;
        for (int s = l; s < SEM; s += 16) a += Psf[w][s] * b2[s];
        a += __shfl_xor(a, 1); a += __shfl_xor(a, 2);
        a += __shfl_xor(a, 4); a += __shfl_xor(a, 8);
        if (l == 0) cconst[bx * NWAY + w] = a;
    }
    f32x4 acc[5];
    #pragma unroll
    for (int i = 0; i < 5; ++i) acc[i] = (f32x4){0.f, 0.f, 0.f, 0.f};
    for (int ks = 0; ks < 10; ++ks) {
        bf16x8 a = *(const bf16x8*)(&Ps[m16][ks * 32 + q * 8]);
        #pragma unroll
        for (int ct = 0; ct < 5; ++ct) {
            int nr = wv * 80 + ct * 16 + m16;
            bf16x8 bb = (bf16x8){0, 0, 0, 0, 0, 0, 0, 0};
            if (nr < SEM) {
                int k = ks * 32 + q * 8;
                if (k + 8 <= SEM) {
                    const float* bp = mw2 + (long)nr * SEM + k;
                    float4 x = *(const float4*)bp;
                    float4 y = *(const float4*)(bp + 4);
                    bb[0] = (short)f2bf(x.x); bb[1] = (short)f2bf(x.y);
                    bb[2] = (short)f2bf(x.z); bb[3] = (short)f2bf(x.w);
                    bb[4] = (short)f2bf(y.x); bb[5] = (short)f2bf(y.y);
                    bb[6] = (short)f2bf(y.z); bb[7] = (short)f2bf(y.w);
                } else {
                    #pragma unroll
                    for (int j = 0; j < 8; ++j) {
                        float v = (k + j < SEM) ? mw2[(long)nr * SEM + k + j] : 0.f;
                        bb[j] = (short)f2bf(v);
                    }
                }
            }
            acc[ct] = __builtin_amdgcn_mfma_f32_16x16x32_bf16(a, bb, acc[ct], 0, 0, 0);
        }
    }
    #pragma unroll
    for (int ct = 0; ct < 5; ++ct) {
        int col = wv * 80 + ct * 16 + m16;
        if (col < SEM) {
            #pragma unroll
            for (int r = 0; r < 4; ++r)
                pqt[(r0 + q * 4 + r) * 840 + 512 + col] = f2bf(acc[ct][r]);
        }
    }
}

// =============== scores + fused per-block softmax partials (KB=64 stages) ===============
__global__ __launch_bounds__(256) void k_scores_mfma(const us* __restrict__ bwh,
        const us* __restrict__ h, const us* __restrict__ pqt,
        const float* __restrict__ cconst, float* __restrict__ scores,
        float* __restrict__ pmax, float* __restrict__ psum) {
    __shared__ us As[128][72];       // [m][64k] +8 pad
    __shared__ us Bs[NWAY][840];
    __shared__ float sred[4][16];
    const int b = blockIdx.y;
    const int bm = blockIdx.x * 128;
    const int t = threadIdx.x;
    const int wv = t >> 6, lane = t & 63;
    const int m16 = lane & 15, q = lane >> 4;
    for (int c = t; c < NWAY * 105; c += 256) {
        int n = c / 105, j = c % 105;
        *(int4*)(&Bs[n][j * 8]) = *(const int4*)(pqt + ((long)b * NWAY + n) * 840 + j * 8);
    }
    f32x4 acc[2];
    acc[0] = (f32x4){0, 0, 0, 0};
    acc[1] = (f32x4){0, 0, 0, 0};
    for (int ks = 0; ks < 13; ++ks) {
        int k0 = ks * 64;
        #pragma unroll
        for (int it = 0; it < 4; ++it) {
            int c = t + it * 256;
            int row = c >> 3, j = c & 7;
            int gm = bm + row, gk = k0 + j * 8;
            us8 u = (us8){0, 0, 0, 0, 0, 0, 0, 0};
            if (gk < FEAT)      u = *(const us8*)(bwh + ((long)b * NBASE + gm) * FEAT + gk);
            else if (gk < CAT)  u = *(const us8*)(h + ((long)b * NBASE + gm) * HLD + (gk - FEAT));
            *(us8*)(&As[row][j * 8]) = u;
        }
        __syncthreads();
        #pragma unroll
        for (int kc = 0; kc < 64; kc += 32) {
            bf16x8 bb = *(const bf16x8*)(&Bs[m16][k0 + kc + q * 8]);
            #pragma unroll
            for (int rt = 0; rt < 2; ++rt) {
                bf16x8 a = *(const bf16x8*)(&As[wv * 32 + rt * 16 + m16][kc + q * 8]);
                acc[rt] = __builtin_amdgcn_mfma_f32_16x16x32_bf16(a, bb, acc[rt], 0, 0, 0);
            }
        }
        __syncthreads();
    }
    const float invT = 0.04419417382415922f;  // 1/sqrt(512)
    float cadd = cconst[b * NWAY + m16];
    float vals[8];
    #pragma unroll
    for (int rt = 0; rt < 2; ++rt) {
        int nrow = bm + wv * 32 + rt * 16 + q * 4;
        #pragma unroll
        for (int r = 0; r < 4; ++r) {
            float v = (nrow + r < NBASE) ? (acc[rt][r] + cadd) * invT : -1e30f;
            vals[rt * 4 + r] = v;
        }
        if (nrow + 3 < NBASE) {
            float4 st = make_float4(vals[rt * 4], vals[rt * 4 + 1], vals[rt * 4 + 2], vals[rt * 4 + 3]);
            *(float4*)(scores + ((long)b * NWAY + m16) * NBASE + nrow) = st;
        } else {
            for (int r = 0; r < 4; ++r)
                if (nrow + r < NBASE)
                    scores[((long)b * NWAY + m16) * NBASE + nrow + r] = vals[rt * 4 + r];
        }
    }
    float lm = vals[0];
    #pragma unroll
    for (int i = 1; i < 8; ++i) lm = fmaxf(lm, vals[i]);
    lm = fmaxf(lm, __shfl_xor(lm, 16));
    lm = fmaxf(lm, __shfl_xor(lm, 32));
    if (q == 0) sred[wv][m16] = lm;
    __syncthreads();
    float bmax = fmaxf(fmaxf(sred[0][m16], sred[1][m16]), fmaxf(sred[2][m16], sred[3][m16]));
    __syncthreads();
    float ls = 0.f;
    #pragma unroll
    for (int i = 0; i < 8; ++i) ls += __expf(vals[i] - bmax);
    ls += __shfl_xor(ls, 16);
    ls += __shfl_xor(ls, 32);
    if (q == 0) sred[wv][m16] = ls;
    __syncthreads();
    if (wv == 0 && lane < 16) {
        float tot = sred[0][m16] + sred[1][m16] + sred[2][m16] + sred[3][m16];
        pmax[((long)b * NWAY + m16) * 63 + blockIdx.x] = bmax;
        psum[((long)b * NWAY + m16) * 63 + blockIdx.x] = tot;
    }
}

// =============== combine partials -> row max & 1/sum (+ zero ov) ===============
__global__ void k_combine(const float* __restrict__ pmax, const float* __restrict__ psum,
                          float* __restrict__ rmax, float* __restrict__ rinv,
                          float* __restrict__ ov) {
    int b = blockIdx.x, t = threadIdx.x;
    float4 z = make_float4(0.f, 0.f, 0.f, 0.f);
    for (int i = t; i < 2048; i += 256)
        *(float4*)(ov + ((long)b * 2048 + i) * 4) = z;
    int w = t >> 4, l = t & 15;
    long base = ((long)b * NWAY + w) * 63;
    float m = -1e30f;
    for (int i = l; i < 63; i += 16) m = fmaxf(m, pmax[base + i]);
    m = fmaxf(m, __shfl_xor(m, 1)); m = fmaxf(m, __shfl_xor(m, 2));
    m = fmaxf(m, __shfl_xor(m, 4)); m = fmaxf(m, __shfl_xor(m, 8));
    float s = 0.f;
    for (int i = l; i < 63; i += 16) s += psum[base + i] * __expf(pmax[base + i] - m);
    s += __shfl_xor(s, 1); s += __shfl_xor(s, 2);
    s += __shfl_xor(s, 4); s += __shfl_xor(s, 8);
    if (l == 0) { rmax[b * NWAY + w] = m; rinv[b * NWAY + w] = 1.0f / s; }
}

// =============== ov = softmax(scores) @ bwh, exp fused, unroll-8 ===============
__global__ void k_ov(const float* __restrict__ scores, const float* __restrict__ rmax,
                     const float* __restrict__ rinv, const us* __restrict__ bwh,
                     float* __restrict__ ov) {
    int b = blockIdx.x, ch = blockIdx.y;  // 50 chunks of 160 rows
    int t = threadIdx.x;
    __shared__ float pr[NWAY][160];
    for (int i = t; i < NWAY * 160; i += 256) {
        int w = i / 160, j = i % 160;
        float sc = scores[((long)b * NWAY + w) * NBASE + (long)ch * 160 + j];
        pr[w][j] = __expf(sc - rmax[b * NWAY + w]) * rinv[b * NWAY + w];
    }
    __syncthreads();
    float a0[NWAY], a1[NWAY];
    #pragma unroll
    for (int w = 0; w < NWAY; ++w) { a0[w] = 0.f; a1[w] = 0.f; }
    const us* bp = bwh + ((long)b * NBASE + (long)ch * 160) * FEAT + 2 * t;
    for (int j0 = 0; j0 < 160; j0 += 8) {
        us2 u[8];
        #pragma unroll
        for (int uu = 0; uu < 8; ++uu)
            u[uu] = *(const us2*)(bp + (long)(j0 + uu) * FEAT);
        #pragma unroll
        for (int uu = 0; uu < 8; ++uu) {
            float v0 = bf2f(u[uu].x), v1 = bf2f(u[uu].y);
            #pragma unroll
            for (int w = 0; w < NWAY; ++w) {
                a0[w] += pr[w][j0 + uu] * v0;
                a1[w] += pr[w][j0 + uu] * v1;
            }
        }
    }
    for (int w = 0; w < NWAY; ++w) {
        atomicAdd(&ov[((long)b * NWAY + w) * FEAT + 2 * t], a0[w]);
        atomicAdd(&ov[((long)b * NWAY + w) * FEAT + 2 * t + 1], a1[w]);
    }
}

// =============== fused output: out = (ov @ wvsT) @ fcwT + sf ===============
__global__ __launch_bounds__(256) void k_out(const float* __restrict__ ov,
        const us* __restrict__ wvsT, const us* __restrict__ fcwT,
        const float* __restrict__ sf, float* __restrict__ out) {
    __shared__ us Os[16][520];
    __shared__ us Ts[16][520];
    const int bx = blockIdx.x;
    const int t = threadIdx.x;
    const int wv = t >> 6, lane = t & 63;
    const int m16 = lane & 15, q = lane >> 4;
    const long r0 = (long)bx * NWAY;
    for (int i = t; i < 16 * 128; i += 256) {
        int r = i >> 7, c4 = (i & 127) * 4;
        float4 v = *(const float4*)(ov + (r0 + r) * FEAT + c4);
        us4 u; u.x = f2bf(v.x); u.y = f2bf(v.y); u.z = f2bf(v.z); u.w = f2bf(v.w);
        *(us4*)(&Os[r][c4]) = u;
    }
    __syncthreads();
    {
        f32x4 acc[8];
        #pragma unroll
        for (int i = 0; i < 8; ++i) acc[i] = (f32x4){0.f, 0.f, 0.f, 0.f};
        for (int ks = 0; ks < 16; ++ks) {
            bf16x8 a = *(const bf16x8*)(&Os[m16][ks * 32 + q * 8]);
            #pragma unroll
            for (int ct = 0; ct < 8; ++ct) {
                int nr = wv * 128 + ct * 16 + m16;
                bf16x8 bb = *(const bf16x8*)(wvsT + (long)nr * 512 + ks * 32 + q * 8);
                acc[ct] = __builtin_amdgcn_mfma_f32_16x16x32_bf16(a, bb, acc[ct], 0, 0, 0);
            }
        }
        #pragma unroll
        for (int ct = 0; ct < 8; ++ct) {
            int col = wv * 128 + ct * 16 + m16;
            #pragma unroll
            for (int r = 0; r < 4; ++r) Ts[q * 4 + r][col] = f2bf(acc[ct][r]);
        }
    }
    __syncthreads();
    {
        f32x4 acc[8];
        #pragma unroll
        for (int i = 0; i < 8; ++i) acc[i] = (f32x4){0.f, 0.f, 0.f, 0.f};
        for (int ks = 0; ks < 16; ++ks) {
            bf16x8 a = *(const bf16x8*)(&Ts[m16][ks * 32 + q * 8]);
            #pragma unroll
            for (int ct = 0; ct < 8; ++ct) {
                int nr = wv * 128 + ct * 16 + m16;
                bf16x8 bb = *(const bf16x8*)(fcwT + (long)nr * 512 + ks * 32 + q * 8);
                acc[ct] = __builtin_amdgcn_mfma_f32_16x16x32_bf16(a, bb, acc[ct], 0, 0, 0);
            }
        }
        #pragma unroll
        for (int ct = 0; ct < 8; ++ct) {
            int col = wv * 128 + ct * 16 + m16;
            #pragma unroll
            for (int r = 0; r < 4; ++r) {
                long row = r0 + q * 4 + r;
                out[row * FEAT + col] = acc[ct][r] + sf[row * FEAT + col];
            }
        }
    }
}

extern "C" void kernel_launch(void* const* d_in, const int* in_sizes, int n_in,
                              void* d_out, int out_size, void* d_ws, size_t ws_size,
                              hipStream_t stream) {
    (void)in_sizes; (void)n_in; (void)out_size; (void)ws_size;
    const float* sf   = (const float*)d_in[0];
    const float* bw   = (const float*)d_in[1];
    const float* ssm  = (const float*)d_in[2];
    const float* bsm  = (const float*)d_in[3];
    const float* mw1  = (const float*)d_in[4];
    const float* mb1  = (const float*)d_in[5];
    const float* mw2  = (const float*)d_in[6];
    const float* mb2  = (const float*)d_in[7];
    const float* vfw  = (const float*)d_in[8];
    const float* vfb  = (const float*)d_in[9];
    const float* sfw  = (const float*)d_in[10];
    const float* sfb  = (const float*)d_in[11];
    const float* wqs  = (const float*)d_in[12];
    const float* wks  = (const float*)d_in[13];
    const float* wvs  = (const float*)d_in[14];
    const float* wqss = (const float*)d_in[15];
    const float* wkss = (const float*)d_in[16];
    const float* fcw  = (const float*)d_in[17];

    float* out = (float*)d_out;
    float* scores = out + NB * NWAY * FEAT;  // d_out = [out | attn_score]

    char* wsb = (char*)d_ws;
    us* bwh    = (us*)(wsb + O_BWH);
    us* h      = (us*)(wsb + O_H);
    us* w1t    = (us*)(wsb + O_W1T);
    us* w2t    = (us*)(wsb + O_W2T);
    us* qwT    = (us*)(wsb + O_QWT);
    us* wvsT   = (us*)(wsb + O_WVST);
    us* fcwT   = (us*)(wsb + O_FCWT);
    us* pqt    = (us*)(wsb + O_PQT);
    float* pmax   = (float*)(wsb + O_PMAX);
    float* psum   = (float*)(wsb + O_PSUM);
    float* rmax   = (float*)(wsb + O_RMAX);
    float* rinv   = (float*)(wsb + O_RINV);
    float* mbw    = (float*)(wsb + O_MBW);
    float* mh     = (float*)(wsb + O_MH);
    float* gv     = (float*)(wsb + O_GV);
    float* gs     = (float*)(wsb + O_GS);
    float* psemr  = (float*)(wsb + O_PSEMR);
    float* ov     = (float*)(wsb + O_OV);
    float* qvisr  = (float*)(wsb + O_QVISR);
    float* cconst = (float*)(wsb + O_CC);

    k_prep<<<dim3(1664, 6), 256, 0, stream>>>(mw1, mw2, wqs, wqss, wvs, fcw,
                                              w1t, w2t, qwT, wvsT, fcwT, mbw);
    k_support<<<NB, 256, 0, stream>>>(ssm, sf, w1t, w2t, mb1, mb2, qwT, wks, wkss,
                                      qvisr, psemr);
    k_cvt_bw<<<dim3(NB, 125), 256, 0, stream>>>(bw, bwh, mbw);
    k_hgemm_mfma<<<dim3(63, NB), 256, 0, stream>>>(bsm, w1t, mb1, h, mh);
    k_gates<<<dim3(13, NB), 256, 0, stream>>>(mbw, mh, mw2, mb2, vfw, vfb, sfw, sfb, gv, gs);
    k_s2<<<NB, 256, 0, stream>>>(qvisr, psemr, gv, gs, mw2, mb2, pqt, cconst);
    k_scores_mfma<<<dim3(63, NB), 256, 0, stream>>>(bwh, h, pqt, cconst, scores, pmax, psum);
    k_combine<<<NB, 256, 0, stream>>>(pmax, psum, rmax, rinv, ov);
    k_ov<<<dim3(NB, 50), 256, 0, stream>>>(scores, rmax, rinv, bwh, ov);
    k_out<<<NB, 256, 0, stream>>>(ov, wvsT, fcwT, sf, out);
}

// Round 2
// 658.445 us; speedup vs baseline: 1.0375x; 1.0375x over previous
//
#include <hip/hip_runtime.h>

#define NB 8
#define NWAY 16
#define NBASE 8000
#define FEAT 512
#define SEM 300
#define CAT (FEAT + SEM)  // 812
#define HLD 304           // padded h leading dim (16B-aligned rows)

typedef __attribute__((ext_vector_type(8))) short bf16x8;
typedef __attribute__((ext_vector_type(4))) float f32x4;
typedef __attribute__((ext_vector_type(8))) unsigned short us8;
typedef __attribute__((ext_vector_type(4))) unsigned short us4;
typedef __attribute__((ext_vector_type(2))) unsigned short us2;
typedef unsigned short us;

__device__ __forceinline__ us f2bf(float x) {
    union { float f; unsigned int u; } v; v.f = x;
    unsigned int r = v.u + 0x7FFFu + ((v.u >> 16) & 1u);
    return (us)(r >> 16);
}
__device__ __forceinline__ float bf2f(us u) {
    union { unsigned int u; float f; } v; v.u = ((unsigned int)u) << 16;
    return v.f;
}

// =============== workspace byte offsets (all 16B aligned) ===============
constexpr long O_BWH   = 0L;            // 8*8000*512*2 = 65,536,000
constexpr long O_H     = 65536000L;     // 8*8000*304*2 = 38,912,000
constexpr long O_W1T   = 104448000L;    // 320*320*2 = 204,800
constexpr long O_W2T   = 104652800L;    // 204,800
constexpr long O_QWT   = 104857600L;    // 512*832*2 = 851,968
constexpr long O_WVST  = 106496000L;    // 512*512*2 = 524,288
constexpr long O_FCWT  = 107020288L;    // 524,288
constexpr long O_PQT   = 107544576L;    // 8*16*840*2 = 215,040
constexpr long O_PMAX  = 107759616L;    // 8*16*63*4 = 32,256
constexpr long O_PSUM  = 107791872L;    // 32,256
constexpr long O_RMAX  = 107824128L;    // 512
constexpr long O_RINV  = 107824640L;    // 512
constexpr long O_F     = 107825152L;
constexpr long O_MBW   = O_F;            // 16,384 (mbw) + 9,600 (mh) contiguous
constexpr long O_MH    = O_F + 16384;
constexpr long O_GV    = O_F + 25984;    // 16,384
constexpr long O_GS    = O_F + 42368;    // 9,600
constexpr long O_PSEMR = O_F + 77952;    // 128*304*4 = 155,648 (raw psem, f32)
constexpr long O_OV    = O_F + 233600;   // 128*512*4 = 262,144 (ov accumulator)
constexpr long O_QVISR = O_F + 540800;   // 128*512*4 = 262,144 (raw qvis, f32)
constexpr long O_CC    = O_F + 802944;   // 512
constexpr long O_WKST  = O_F + 803456;   // 512*512*2 = 524,288 (wks bf16)
constexpr long O_WKSST = O_F + 1327744;  // 320*512*2 = 327,680 (wkss bf16, row-pad)
constexpr long O_W2N   = O_F + 1655424;  // 320*320*2 = 204,800 (mw2 bf16 natural)

// =============== weight prep: bf16 converts/transposes + zero mbw/mh ===============
__global__ void k_prep(const float* __restrict__ w1, const float* __restrict__ w2,
                       const float* __restrict__ wqs, const float* __restrict__ wqss,
                       const float* __restrict__ wvs, const float* __restrict__ fcw,
                       const float* __restrict__ wks, const float* __restrict__ wkss,
                       us* __restrict__ w1t, us* __restrict__ w2t, us* __restrict__ qwT,
                       us* __restrict__ wvsT, us* __restrict__ fcwT,
                       us* __restrict__ wksT, us* __restrict__ wkssT, us* __restrict__ w2n,
                       float* __restrict__ mz) {
    long e = (long)blockIdx.x * 256 + threadIdx.x;
    switch (blockIdx.y) {
    case 0: if (e < 320 * 320) { int n = e / 320, k = e % 320;
            w1t[e] = f2bf((n < SEM && k < SEM) ? w1[(long)k * SEM + n] : 0.f); } break;
    case 1: if (e < 320 * 320) { int n = e / 320, k = e % 320;
            w2t[e] = f2bf((n < SEM && k < SEM) ? w2[(long)k * SEM + n] : 0.f); } break;
    case 2: if (e < 512 * 832) { int n = e / 832, k = e % 832;
            float v = 0.f;
            if (k < FEAT) v = wqs[(long)k * FEAT + n];
            else if (k < CAT) v = wqss[(long)(k - FEAT) * FEAT + n];
            qwT[e] = f2bf(v); } break;
    case 3: if (e < 512 * 512) { int n = e / 512, k = e % 512;
            wvsT[e] = f2bf(wvs[(long)k * FEAT + n]); } break;
    case 4: if (e < 512 * 512) { int n = e / 512, k = e % 512;
            fcwT[e] = f2bf(fcw[(long)k * FEAT + n]); } break;
    case 5: if (e < NB * FEAT + NB * SEM) mz[e] = 0.f; break;
    case 6: if (e < 512 * 512) wksT[e] = f2bf(wks[e]); break;           // [fi][fo], straight
    case 7: if (e < 320 * 512) { int n = e / 512, k = e % 512;
            wkssT[e] = (n < SEM) ? f2bf(wkss[(long)n * FEAT + k]) : (us)0; } break;
    case 8: if (e < 320 * 320) { int n = e / 320, k = e % 320;
            w2n[e] = (n < SEM && k < SEM) ? f2bf(w2[(long)n * SEM + k]) : (us)0; } break;
    }
}

// =============== bw -> bf16 + column sums: unroll-4, LDS-reduced atomics ===============
__global__ void k_cvt_bw(const float* __restrict__ bw, us* __restrict__ bwh,
                         float* __restrict__ mbw) {
    __shared__ float red[128][4];
    int b = blockIdx.x, ch = blockIdx.y;  // 125 chunks of 64 rows
    int t = threadIdx.x;
    int cg = t & 127, rs = t >> 7;
    long base = ((long)b * NBASE + (long)ch * 64) * FEAT + cg * 4;
    float s0 = 0.f, s1 = 0.f, s2 = 0.f, s3 = 0.f;
    for (int r0 = rs * 4; r0 < 64; r0 += 8) {
        float4 v[4];
        #pragma unroll
        for (int u = 0; u < 4; ++u)
            v[u] = *(const float4*)(bw + base + (long)(r0 + u) * FEAT);
        #pragma unroll
        for (int u = 0; u < 4; ++u) {
            us4 o; o.x = f2bf(v[u].x); o.y = f2bf(v[u].y); o.z = f2bf(v[u].z); o.w = f2bf(v[u].w);
            *(us4*)(bwh + base + (long)(r0 + u) * FEAT) = o;
            s0 += v[u].x; s1 += v[u].y; s2 += v[u].z; s3 += v[u].w;
        }
    }
    if (rs == 1) { red[cg][0] = s0; red[cg][1] = s1; red[cg][2] = s2; red[cg][3] = s3; }
    __syncthreads();
    if (rs == 0) {
        atomicAdd(&mbw[b * FEAT + cg * 4 + 0], s0 + red[cg][0]);
        atomicAdd(&mbw[b * FEAT + cg * 4 + 1], s1 + red[cg][1]);
        atomicAdd(&mbw[b * FEAT + cg * 4 + 2], s2 + red[cg][2]);
        atomicAdd(&mbw[b * FEAT + cg * 4 + 3], s3 + red[cg][3]);
    }
}

// =============== h = leaky(bsm @ W1 + b1), BM=128, per-batch grid (63, NB) ===============
__global__ __launch_bounds__(256, 2) void k_hgemm_mfma(const float* __restrict__ X,
        const us* __restrict__ W1T, const float* __restrict__ b1,
        us* __restrict__ H, float* __restrict__ mh) {
    __shared__ char smem[128 * 304 * 2];  // 77,824 B
    us (*As)[72] = (us(*)[72])smem;                    // 128*72*2 = 18,432
    us (*Bs)[72] = (us(*)[72])(smem + 18432);          // 320*72*2 = 46,080
    us (*Cs)[HLD] = (us(*)[HLD])smem;                  // epilogue alias
    const int b = blockIdx.y;
    const int bm = blockIdx.x * 128;
    const int t = threadIdx.x;
    const int wv = t >> 6, lane = t & 63;
    const int m16 = lane & 15, q = lane >> 4;
    const long rowbase = (long)b * NBASE;
    f32x4 acc[8][5];
    #pragma unroll
    for (int i = 0; i < 8; ++i)
        #pragma unroll
        for (int j = 0; j < 5; ++j) acc[i][j] = (f32x4){0.f, 0.f, 0.f, 0.f};
    for (int ks = 0; ks < 5; ++ks) {
        const int k0 = ks * 64;
        #pragma unroll
        for (int it = 0; it < 8; ++it) {
            int c = t + it * 256;
            int row = c >> 4, j = c & 15;
            int gk = k0 + j * 4;
            float4 v = make_float4(0.f, 0.f, 0.f, 0.f);
            if (gk < SEM && bm + row < NBASE)
                v = *(const float4*)(X + (rowbase + bm + row) * SEM + gk);
            us4 u; u.x = f2bf(v.x); u.y = f2bf(v.y); u.z = f2bf(v.z); u.w = f2bf(v.w);
            *(us4*)(&As[row][j * 4]) = u;
        }
        #pragma unroll
        for (int it = 0; it < 10; ++it) {
            int c = t + it * 256;
            int n = c >> 3, j = c & 7;
            int4 v = *(const int4*)(W1T + (long)n * 320 + k0 + j * 8);
            *(int4*)(&Bs[n][j * 8]) = v;
        }
        __syncthreads();
        #pragma unroll
        for (int kc = 0; kc < 64; kc += 32) {
            bf16x8 a[8], bb[5];
            #pragma unroll
            for (int rt = 0; rt < 8; ++rt)
                a[rt] = *(const bf16x8*)(&As[rt * 16 + m16][kc + q * 8]);
            #pragma unroll
            for (int ct = 0; ct < 5; ++ct)
                bb[ct] = *(const bf16x8*)(&Bs[(wv * 5 + ct) * 16 + m16][kc + q * 8]);
            #pragma unroll
            for (int rt = 0; rt < 8; ++rt)
                #pragma unroll
                for (int ct = 0; ct < 5; ++ct)
                    acc[rt][ct] = __builtin_amdgcn_mfma_f32_16x16x32_bf16(a[rt], bb[ct], acc[rt][ct], 0, 0, 0);
        }
        __syncthreads();
    }
    float csum[5] = {0.f, 0.f, 0.f, 0.f, 0.f};
    #pragma unroll
    for (int ct = 0; ct < 5; ++ct) {
        int col = (wv * 5 + ct) * 16 + m16;
        float bias = (col < SEM) ? b1[col] : 0.f;
        #pragma unroll
        for (int rt = 0; rt < 8; ++rt) {
            int rl = rt * 16 + q * 4;
            #pragma unroll
            for (int r = 0; r < 4; ++r) {
                float v = acc[rt][ct][r] + bias;
                v = v > 0.f ? v : 0.1f * v;
                if (col < SEM && bm + rl + r < NBASE) {
                    Cs[rl + r][col] = f2bf(v);
                    csum[ct] += v;
                }
            }
        }
    }
    if (t < 128) *(us4*)(&Cs[t][300]) = (us4){0, 0, 0, 0};
    #pragma unroll
    for (int ct = 0; ct < 5; ++ct) {
        float s = csum[ct];
        s += __shfl_xor(s, 16);
        s += __shfl_xor(s, 32);
        int col = (wv * 5 + ct) * 16 + m16;
        if (q == 0 && col < SEM) atomicAdd(&mh[b * SEM + col], s);
    }
    __syncthreads();
    for (int i = t; i < 128 * 76; i += 256) {
        int row = i / 76, j = i % 76;
        if (bm + row < NBASE)
            *(us4*)(H + (rowbase + bm + row) * HLD + j * 4) = *(const us4*)(&Cs[row][j * 4]);
    }
}

// =============== fused avg + gates: grid (13, NB) ===============
__global__ void k_gates(const float* __restrict__ mbw, const float* __restrict__ mh,
                        const float* __restrict__ mw2, const float* __restrict__ mb2,
                        const float* __restrict__ vfw, const float* __restrict__ vfb,
                        const float* __restrict__ sfw, const float* __restrict__ sfb,
                        float* __restrict__ gv, float* __restrict__ gs) {
    int tile = blockIdx.x, b = blockIdx.y, t = threadIdx.x;
    __shared__ float avgL[CAT];
    __shared__ float mhL[SEM];
    __shared__ float red[4][64];
    const float invN = 1.0f / NBASE;
    for (int i = t; i < SEM; i += 256) mhL[i] = mh[b * SEM + i] * invN;
    for (int i = t; i < FEAT; i += 256) avgL[i] = mbw[b * FEAT + i] * invN;
    __syncthreads();
    for (int s = t; s < SEM; s += 256) {
        float a = mb2[s];
        for (int c = 0; c < SEM; ++c) a += mhL[c] * mw2[(long)c * SEM + s];
        avgL[FEAT + s] = a;
    }
    __syncthreads();
    int l = t & 63, kq = t >> 6;
    float a = 0.f;
    if (tile < 8) {
        int f = tile * 64 + l;
        for (int c = kq * 203; c < kq * 203 + 203; ++c) a += avgL[c] * vfw[(long)c * FEAT + f];
        red[kq][l] = a;
        __syncthreads();
        if (kq == 0) {
            float s = red[0][l] + red[1][l] + red[2][l] + red[3][l] + vfb[f];
            gv[b * FEAT + f] = 1.f + 1.f / (1.f + expf(-s));
        }
    } else {
        int fs = (tile - 8) * 64 + l;
        if (fs < SEM)
            for (int c = kq * 203; c < kq * 203 + 203; ++c) a += avgL[c] * sfw[(long)c * SEM + fs];
        red[kq][l] = a;
        __syncthreads();
        if (kq == 0 && fs < SEM) {
            float s = red[0][l] + red[1][l] + red[2][l] + red[3][l] + sfb[fs];
            gs[b * SEM + fs] = 1.f + 1.f / (1.f + expf(-s));
        }
    }
}

// =============== support chain, parallel decomposition: grid (13, 2) ===============
// blockIdx.x = nslot (0-7: qvis 64-col tile; 8-12: psem 64-col tile), blockIdx.y = m-half.
// Each block: 64 rows. Phases: A h1 -> B ssc -> C full qtot (redundant) -> D its slice.
__global__ __launch_bounds__(256) void k_sup(
        const float* __restrict__ ssm, const float* __restrict__ sf,
        const us* __restrict__ w1t, const us* __restrict__ w2t,
        const float* __restrict__ b1, const float* __restrict__ b2,
        const us* __restrict__ qwT, const us* __restrict__ wksT,
        const us* __restrict__ wkssT,
        float* __restrict__ qvisr, float* __restrict__ psemr) {
    __shared__ char smem[108544];
    us (*Sc)[328] = (us(*)[328])smem;              // 41,984 B
    us (*H1)[328] = (us(*)[328])(smem + 41984);    // 41,984 B (aliased by Qs after phase B)
    us (*Qs)[520] = (us(*)[520])(smem + 41984);    // 66,560 B
    const int nslot = blockIdx.x;
    const int row0 = blockIdx.y * 64;
    const int t = threadIdx.x;
    const int wv = t >> 6, lane = t & 63;
    const int m16 = lane & 15, q = lane >> 4;

    // ---- phase A: H1 = leaky(ssm @ w1t^T + b1); wave cols [wv*80, +80)
    {
        f32x4 acc[4][5];
        #pragma unroll
        for (int i = 0; i < 4; ++i)
            #pragma unroll
            for (int j = 0; j < 5; ++j) acc[i][j] = (f32x4){0.f, 0.f, 0.f, 0.f};
        for (int ks = 0; ks < 10; ++ks) {
            const int k = ks * 32 + q * 8;
            bf16x8 a[4];
            #pragma unroll
            for (int mt = 0; mt < 4; ++mt) {
                const float* ap = ssm + (long)(row0 + mt * 16 + m16) * SEM + k;
                bf16x8 av = (bf16x8){0, 0, 0, 0, 0, 0, 0, 0};
                if (k + 8 <= SEM) {
                    float4 x = *(const float4*)ap, y = *(const float4*)(ap + 4);
                    av[0] = (short)f2bf(x.x); av[1] = (short)f2bf(x.y);
                    av[2] = (short)f2bf(x.z); av[3] = (short)f2bf(x.w);
                    av[4] = (short)f2bf(y.x); av[5] = (short)f2bf(y.y);
                    av[6] = (short)f2bf(y.z); av[7] = (short)f2bf(y.w);
                } else if (k < SEM) {
                    #pragma unroll
                    for (int j = 0; j < 8; ++j)
                        if (k + j < SEM) av[j] = (short)f2bf(ap[j]);
                }
                a[mt] = av;
            }
            #pragma unroll
            for (int ct = 0; ct < 5; ++ct) {
                const int n = wv * 80 + ct * 16 + m16;
                bf16x8 bb = *(const bf16x8*)(w1t + (long)n * 320 + k);
                #pragma unroll
                for (int mt = 0; mt < 4; ++mt)
                    acc[mt][ct] = __builtin_amdgcn_mfma_f32_16x16x32_bf16(a[mt], bb, acc[mt][ct], 0, 0, 0);
            }
        }
        #pragma unroll
        for (int ct = 0; ct < 5; ++ct) {
            const int col = wv * 80 + ct * 16 + m16;
            const float bias = (col < SEM) ? b1[col] : 0.f;
            #pragma unroll
            for (int mt = 0; mt < 4; ++mt)
                #pragma unroll
                for (int r = 0; r < 4; ++r) {
                    float v = acc[mt][ct][r] + bias;
                    v = v > 0.f ? v : 0.1f * v;
                    H1[mt * 16 + q * 4 + r][col] = (col < SEM) ? f2bf(v) : (us)0;
                }
        }
    }
    __syncthreads();

    // ---- phase B: Sc = H1 @ w2t^T + b2
    {
        f32x4 acc[4][5];
        #pragma unroll
        for (int i = 0; i < 4; ++i)
            #pragma unroll
            for (int j = 0; j < 5; ++j) acc[i][j] = (f32x4){0.f, 0.f, 0.f, 0.f};
        for (int ks = 0; ks < 10; ++ks) {
            const int k = ks * 32 + q * 8;
            bf16x8 a[4];
            #pragma unroll
            for (int mt = 0; mt < 4; ++mt)
                a[mt] = *(const bf16x8*)(&H1[mt * 16 + m16][k]);
            #pragma unroll
            for (int ct = 0; ct < 5; ++ct) {
                const int n = wv * 80 + ct * 16 + m16;
                bf16x8 bb = *(const bf16x8*)(w2t + (long)n * 320 + k);
                #pragma unroll
                for (int mt = 0; mt < 4; ++mt)
                    acc[mt][ct] = __builtin_amdgcn_mfma_f32_16x16x32_bf16(a[mt], bb, acc[mt][ct], 0, 0, 0);
            }
        }
        #pragma unroll
        for (int ct = 0; ct < 5; ++ct) {
            const int col = wv * 80 + ct * 16 + m16;
            const float bias = (col < SEM) ? b2[col] : 0.f;
            #pragma unroll
            for (int mt = 0; mt < 4; ++mt)
                #pragma unroll
                for (int r = 0; r < 4; ++r)
                    Sc[mt * 16 + q * 4 + r][col] = (col < SEM) ? f2bf(acc[mt][ct][r] + bias) : (us)0;
        }
    }
    __syncthreads();  // Sc ready; H1 reads done (Qs may now clobber H1)

    // ---- phase C: Qs = [sf | Sc | 0] @ qwT^T (K=832); wave cols [wv*128, +128) in 2 halves
    #pragma unroll
    for (int half = 0; half < 2; ++half) {
        f32x4 acc[4][4];
        #pragma unroll
        for (int i = 0; i < 4; ++i)
            #pragma unroll
            for (int j = 0; j < 4; ++j) acc[i][j] = (f32x4){0.f, 0.f, 0.f, 0.f};
        for (int ks = 0; ks < 26; ++ks) {
            const int k = ks * 32 + q * 8;
            bf16x8 a[4];
            if (k < FEAT) {
                #pragma unroll
                for (int mt = 0; mt < 4; ++mt) {
                    const float* ap = sf + (long)(row0 + mt * 16 + m16) * FEAT + k;
                    float4 x = *(const float4*)ap, y = *(const float4*)(ap + 4);
                    bf16x8 av;
                    av[0] = (short)f2bf(x.x); av[1] = (short)f2bf(x.y);
                    av[2] = (short)f2bf(x.z); av[3] = (short)f2bf(x.w);
                    av[4] = (short)f2bf(y.x); av[5] = (short)f2bf(y.y);
                    av[6] = (short)f2bf(y.z); av[7] = (short)f2bf(y.w);
                    a[mt] = av;
                }
            } else {
                #pragma unroll
                for (int mt = 0; mt < 4; ++mt)
                    a[mt] = *(const bf16x8*)(&Sc[mt * 16 + m16][k - FEAT]);
            }
            #pragma unroll
            for (int ct = 0; ct < 4; ++ct) {
                const int n = wv * 128 + half * 64 + ct * 16 + m16;
                bf16x8 bb = *(const bf16x8*)(qwT + (long)n * 832 + k);
                #pragma unroll
                for (int mt = 0; mt < 4; ++mt)
                    acc[mt][ct] = __builtin_amdgcn_mfma_f32_16x16x32_bf16(a[mt], bb, acc[mt][ct], 0, 0, 0);
            }
        }
        #pragma unroll
        for (int ct = 0; ct < 4; ++ct) {
            const int col = wv * 128 + half * 64 + ct * 16 + m16;
            #pragma unroll
            for (int mt = 0; mt < 4; ++mt)
                #pragma unroll
                for (int r = 0; r < 4; ++r)
                    Qs[mt * 16 + q * 4 + r][col] = f2bf(acc[mt][ct][r]);
        }
    }
    __syncthreads();

    // ---- phase D: this block's 64-col slice of qvis_raw or psem_raw
    {
        const bool isv = (nslot < 8);
        const int ncol0 = isv ? nslot * 64 : (nslot - 8) * 64;
        const us* BT = isv ? wksT : wkssT;
        f32x4 acc[4];
        #pragma unroll
        for (int i = 0; i < 4; ++i) acc[i] = (f32x4){0.f, 0.f, 0.f, 0.f};
        const int n = ncol0 + wv * 16 + m16;
        for (int ks = 0; ks < 16; ++ks) {
            const int k = ks * 32 + q * 8;
            bf16x8 bb = *(const bf16x8*)(BT + (long)n * 512 + k);
            #pragma unroll
            for (int mt = 0; mt < 4; ++mt) {
                bf16x8 a = *(const bf16x8*)(&Qs[mt * 16 + m16][k]);
                acc[mt] = __builtin_amdgcn_mfma_f32_16x16x32_bf16(a, bb, acc[mt], 0, 0, 0);
            }
        }
        const int col = n;
        #pragma unroll
        for (int mt = 0; mt < 4; ++mt)
            #pragma unroll
            for (int r = 0; r < 4; ++r) {
                const int gr = row0 + mt * 16 + q * 4 + r;
                if (isv) qvisr[(long)gr * FEAT + col] = acc[mt][r];
                else if (col < SEM) psemr[(long)gr * HLD + col] = acc[mt][r];
            }
    }
}

// =============== post-gate: pqt assembly + psem@W2^T + cconst ===============
__global__ __launch_bounds__(256) void k_s2(
        const float* __restrict__ qvisr, const float* __restrict__ psemr,
        const float* __restrict__ gv, const float* __restrict__ gs,
        const us* __restrict__ w2n, const float* __restrict__ b2,
        us* __restrict__ pqt, float* __restrict__ cconst) {
    __shared__ us Ps[16][328];     // gated psem bf16
    __shared__ float Psf[16][304]; // gated psem f32 (for cconst)
    const int bx = blockIdx.x;
    const int t = threadIdx.x;
    const int wv = t >> 6, lane = t & 63;
    const int m16 = lane & 15, q = lane >> 4;
    const long r0 = (long)bx * NWAY;
    for (int i = t; i < 16 * 82; i += 256) {
        int r = i / 82, c4 = (i % 82) * 4;
        us4 u = (us4){0, 0, 0, 0};
        if (c4 < SEM) {
            float4 v = *(const float4*)(psemr + (r0 + r) * HLD + c4);
            float4 g = *(const float4*)(gs + bx * SEM + c4);
            float p0 = v.x * g.x, p1 = v.y * g.y, p2 = v.z * g.z, p3 = v.w * g.w;
            Psf[r][c4 + 0] = p0; Psf[r][c4 + 1] = p1;
            Psf[r][c4 + 2] = p2; Psf[r][c4 + 3] = p3;
            u.x = f2bf(p0); u.y = f2bf(p1); u.z = f2bf(p2); u.w = f2bf(p3);
        }
        *(us4*)(&Ps[r][c4]) = u;
    }
    for (int i = t; i < 16 * 128; i += 256) {
        int r = i >> 7, c4 = (i & 127) * 4;
        float4 v = *(const float4*)(qvisr + (r0 + r) * FEAT + c4);
        float4 g = *(const float4*)(gv + bx * FEAT + c4);
        us4 u; u.x = f2bf(v.x * g.x); u.y = f2bf(v.y * g.y);
        u.z = f2bf(v.z * g.z); u.w = f2bf(v.w * g.w);
        *(us4*)(pqt + (r0 + r) * 840 + c4) = u;
    }
    for (int i = t; i < 16 * 28; i += 256) pqt[(r0 + i / 28) * 840 + 812 + (i % 28)] = 0;
    __syncthreads();
    {
        int w = t >> 4, l = t & 15;
        float a = 0.f;
        for (int s = l; s < SEM; s += 16) a += Psf[w][s] * b2[s];
        a += __shfl_xor(a, 1); a += __shfl_xor(a, 2);
        a += __shfl_xor(a, 4); a += __shfl_xor(a, 8);
        if (l == 0) cconst[bx * NWAY + w] = a;
    }
    f32x4 acc[5];
    #pragma unroll
    for (int i = 0; i < 5; ++i) acc[i] = (f32x4){0.f, 0.f, 0.f, 0.f};
    for (int ks = 0; ks < 10; ++ks) {
        bf16x8 a = *(const bf16x8*)(&Ps[m16][ks * 32 + q * 8]);
        #pragma unroll
        for (int ct = 0; ct < 5; ++ct) {
            int nr = wv * 80 + ct * 16 + m16;
            bf16x8 bb = *(const bf16x8*)(w2n + (long)nr * 320 + ks * 32 + q * 8);
            acc[ct] = __builtin_amdgcn_mfma_f32_16x16x32_bf16(a, bb, acc[ct], 0, 0, 0);
        }
    }
    #pragma unroll
    for (int ct = 0; ct < 5; ++ct) {
        int col = wv * 80 + ct * 16 + m16;
        if (col < SEM) {
            #pragma unroll
            for (int r = 0; r < 4; ++r)
                pqt[(r0 + q * 4 + r) * 840 + 512 + col] = f2bf(acc[ct][r]);
        }
    }
}

// =============== scores + fused per-block softmax partials (KB=64 stages) ===============
__global__ __launch_bounds__(256) void k_scores_mfma(const us* __restrict__ bwh,
        const us* __restrict__ h, const us* __restrict__ pqt,
        const float* __restrict__ cconst, float* __restrict__ scores,
        float* __restrict__ pmax, float* __restrict__ psum) {
    __shared__ us As[128][72];       // [m][64k] +8 pad
    __shared__ us Bs[NWAY][840];
    __shared__ float sred[4][16];
    const int b = blockIdx.y;
    const int bm = blockIdx.x * 128;
    const int t = threadIdx.x;
    const int wv = t >> 6, lane = t & 63;
    const int m16 = lane & 15, q = lane >> 4;
    for (int c = t; c < NWAY * 105; c += 256) {
        int n = c / 105, j = c % 105;
        *(int4*)(&Bs[n][j * 8]) = *(const int4*)(pqt + ((long)b * NWAY + n) * 840 + j * 8);
    }
    f32x4 acc[2];
    acc[0] = (f32x4){0, 0, 0, 0};
    acc[1] = (f32x4){0, 0, 0, 0};
    for (int ks = 0; ks < 13; ++ks) {
        int k0 = ks * 64;
        #pragma unroll
        for (int it = 0; it < 4; ++it) {
            int c = t + it * 256;
            int row = c >> 3, j = c & 7;
            int gm = bm + row, gk = k0 + j * 8;
            us8 u = (us8){0, 0, 0, 0, 0, 0, 0, 0};
            if (gk < FEAT)      u = *(const us8*)(bwh + ((long)b * NBASE + gm) * FEAT + gk);
            else if (gk < CAT)  u = *(const us8*)(h + ((long)b * NBASE + gm) * HLD + (gk - FEAT));
            *(us8*)(&As[row][j * 8]) = u;
        }
        __syncthreads();
        #pragma unroll
        for (int kc = 0; kc < 64; kc += 32) {
            bf16x8 bb = *(const bf16x8*)(&Bs[m16][k0 + kc + q * 8]);
            #pragma unroll
            for (int rt = 0; rt < 2; ++rt) {
                bf16x8 a = *(const bf16x8*)(&As[wv * 32 + rt * 16 + m16][kc + q * 8]);
                acc[rt] = __builtin_amdgcn_mfma_f32_16x16x32_bf16(a, bb, acc[rt], 0, 0, 0);
            }
        }
        __syncthreads();
    }
    const float invT = 0.04419417382415922f;  // 1/sqrt(512)
    float cadd = cconst[b * NWAY + m16];
    float vals[8];
    #pragma unroll
    for (int rt = 0; rt < 2; ++rt) {
        int nrow = bm + wv * 32 + rt * 16 + q * 4;
        #pragma unroll
        for (int r = 0; r < 4; ++r) {
            float v = (nrow + r < NBASE) ? (acc[rt][r] + cadd) * invT : -1e30f;
            vals[rt * 4 + r] = v;
        }
        if (nrow + 3 < NBASE) {
            float4 st = make_float4(vals[rt * 4], vals[rt * 4 + 1], vals[rt * 4 + 2], vals[rt * 4 + 3]);
            *(float4*)(scores + ((long)b * NWAY + m16) * NBASE + nrow) = st;
        } else {
            for (int r = 0; r < 4; ++r)
                if (nrow + r < NBASE)
                    scores[((long)b * NWAY + m16) * NBASE + nrow + r] = vals[rt * 4 + r];
        }
    }
    float lm = vals[0];
    #pragma unroll
    for (int i = 1; i < 8; ++i) lm = fmaxf(lm, vals[i]);
    lm = fmaxf(lm, __shfl_xor(lm, 16));
    lm = fmaxf(lm, __shfl_xor(lm, 32));
    if (q == 0) sred[wv][m16] = lm;
    __syncthreads();
    float bmax = fmaxf(fmaxf(sred[0][m16], sred[1][m16]), fmaxf(sred[2][m16], sred[3][m16]));
    __syncthreads();
    float ls = 0.f;
    #pragma unroll
    for (int i = 0; i < 8; ++i) ls += __expf(vals[i] - bmax);
    ls += __shfl_xor(ls, 16);
    ls += __shfl_xor(ls, 32);
    if (q == 0) sred[wv][m16] = ls;
    __syncthreads();
    if (wv == 0 && lane < 16) {
        float tot = sred[0][m16] + sred[1][m16] + sred[2][m16] + sred[3][m16];
        pmax[((long)b * NWAY + m16) * 63 + blockIdx.x] = bmax;
        psum[((long)b * NWAY + m16) * 63 + blockIdx.x] = tot;
    }
}

// =============== combine partials -> row max & 1/sum (+ zero ov) ===============
__global__ void k_combine(const float* __restrict__ pmax, const float* __restrict__ psum,
                          float* __restrict__ rmax, float* __restrict__ rinv,
                          float* __restrict__ ov) {
    int b = blockIdx.x, t = threadIdx.x;
    float4 z = make_float4(0.f, 0.f, 0.f, 0.f);
    for (int i = t; i < 2048; i += 256)
        *(float4*)(ov + ((long)b * 2048 + i) * 4) = z;
    int w = t >> 4, l = t & 15;
    long base = ((long)b * NWAY + w) * 63;
    float m = -1e30f;
    for (int i = l; i < 63; i += 16) m = fmaxf(m, pmax[base + i]);
    m = fmaxf(m, __shfl_xor(m, 1)); m = fmaxf(m, __shfl_xor(m, 2));
    m = fmaxf(m, __shfl_xor(m, 4)); m = fmaxf(m, __shfl_xor(m, 8));
    float s = 0.f;
    for (int i = l; i < 63; i += 16) s += psum[base + i] * __expf(pmax[base + i] - m);
    s += __shfl_xor(s, 1); s += __shfl_xor(s, 2);
    s += __shfl_xor(s, 4); s += __shfl_xor(s, 8);
    if (l == 0) { rmax[b * NWAY + w] = m; rinv[b * NWAY + w] = 1.0f / s; }
}

// =============== ov = softmax(scores) @ bwh, exp fused, unroll-8 ===============
__global__ void k_ov(const float* __restrict__ scores, const float* __restrict__ rmax,
                     const float* __restrict__ rinv, const us* __restrict__ bwh,
                     float* __restrict__ ov) {
    int b = blockIdx.x, ch = blockIdx.y;  // 50 chunks of 160 rows
    int t = threadIdx.x;
    __shared__ float pr[NWAY][160];
    for (int i = t; i < NWAY * 160; i += 256) {
        int w = i / 160, j = i % 160;
        float sc = scores[((long)b * NWAY + w) * NBASE + (long)ch * 160 + j];
        pr[w][j] = __expf(sc - rmax[b * NWAY + w]) * rinv[b * NWAY + w];
    }
    __syncthreads();
    float a0[NWAY], a1[NWAY];
    #pragma unroll
    for (int w = 0; w < NWAY; ++w) { a0[w] = 0.f; a1[w] = 0.f; }
    const us* bp = bwh + ((long)b * NBASE + (long)ch * 160) * FEAT + 2 * t;
    for (int j0 = 0; j0 < 160; j0 += 8) {
        us2 u[8];
        #pragma unroll
        for (int uu = 0; uu < 8; ++uu)
            u[uu] = *(const us2*)(bp + (long)(j0 + uu) * FEAT);
        #pragma unroll
        for (int uu = 0; uu < 8; ++uu) {
            float v0 = bf2f(u[uu].x), v1 = bf2f(u[uu].y);
            #pragma unroll
            for (int w = 0; w < NWAY; ++w) {
                a0[w] += pr[w][j0 + uu] * v0;
                a1[w] += pr[w][j0 + uu] * v1;
            }
        }
    }
    for (int w = 0; w < NWAY; ++w) {
        atomicAdd(&ov[((long)b * NWAY + w) * FEAT + 2 * t], a0[w]);
        atomicAdd(&ov[((long)b * NWAY + w) * FEAT + 2 * t + 1], a1[w]);
    }
}

// =============== fused output: out = (ov @ wvsT) @ fcwT + sf ===============
__global__ __launch_bounds__(256) void k_out(const float* __restrict__ ov,
        const us* __restrict__ wvsT, const us* __restrict__ fcwT,
        const float* __restrict__ sf, float* __restrict__ out) {
    __shared__ us Os[16][520];
    __shared__ us Ts[16][520];
    const int bx = blockIdx.x;
    const int t = threadIdx.x;
    const int wv = t >> 6, lane = t & 63;
    const int m16 = lane & 15, q = lane >> 4;
    const long r0 = (long)bx * NWAY;
    for (int i = t; i < 16 * 128; i += 256) {
        int r = i >> 7, c4 = (i & 127) * 4;
        float4 v = *(const float4*)(ov + (r0 + r) * FEAT + c4);
        us4 u; u.x = f2bf(v.x); u.y = f2bf(v.y); u.z = f2bf(v.z); u.w = f2bf(v.w);
        *(us4*)(&Os[r][c4]) = u;
    }
    __syncthreads();
    {
        f32x4 acc[8];
        #pragma unroll
        for (int i = 0; i < 8; ++i) acc[i] = (f32x4){0.f, 0.f, 0.f, 0.f};
        for (int ks = 0; ks < 16; ++ks) {
            bf16x8 a = *(const bf16x8*)(&Os[m16][ks * 32 + q * 8]);
            #pragma unroll
            for (int ct = 0; ct < 8; ++ct) {
                int nr = wv * 128 + ct * 16 + m16;
                bf16x8 bb = *(const bf16x8*)(wvsT + (long)nr * 512 + ks * 32 + q * 8);
                acc[ct] = __builtin_amdgcn_mfma_f32_16x16x32_bf16(a, bb, acc[ct], 0, 0, 0);
            }
        }
        #pragma unroll
        for (int ct = 0; ct < 8; ++ct) {
            int col = wv * 128 + ct * 16 + m16;
            #pragma unroll
            for (int r = 0; r < 4; ++r) Ts[q * 4 + r][col] = f2bf(acc[ct][r]);
        }
    }
    __syncthreads();
    {
        f32x4 acc[8];
        #pragma unroll
        for (int i = 0; i < 8; ++i) acc[i] = (f32x4){0.f, 0.f, 0.f, 0.f};
        for (int ks = 0; ks < 16; ++ks) {
            bf16x8 a = *(const bf16x8*)(&Ts[m16][ks * 32 + q * 8]);
            #pragma unroll
            for (int ct = 0; ct < 8; ++ct) {
                int nr = wv * 128 + ct * 16 + m16;
                bf16x8 bb = *(const bf16x8*)(fcwT + (long)nr * 512 + ks * 32 + q * 8);
                acc[ct] = __builtin_amdgcn_mfma_f32_16x16x32_bf16(a, bb, acc[ct], 0, 0, 0);
            }
        }
        #pragma unroll
        for (int ct = 0; ct < 8; ++ct) {
            int col = wv * 128 + ct * 16 + m16;
            #pragma unroll
            for (int r = 0; r < 4; ++r) {
                long row = r0 + q * 4 + r;
                out[row * FEAT + col] = acc[ct][r] + sf[row * FEAT + col];
            }
        }
    }
}

extern "C" void kernel_launch(void* const* d_in, const int* in_sizes, int n_in,
                              void* d_out, int out_size, void* d_ws, size_t ws_size,
                              hipStream_t stream) {
    (void)in_sizes; (void)n_in; (void)out_size; (void)ws_size;
    const float* sf   = (const float*)d_in[0];
    const float* bw   = (const float*)d_in[1];
    const float* ssm  = (const float*)d_in[2];
    const float* bsm  = (const float*)d_in[3];
    const float* mw1  = (const float*)d_in[4];
    const float* mb1  = (const float*)d_in[5];
    const float* mw2  = (const float*)d_in[6];
    const float* mb2  = (const float*)d_in[7];
    const float* vfw  = (const float*)d_in[8];
    const float* vfb  = (const float*)d_in[9];
    const float* sfw  = (const float*)d_in[10];
    const float* sfb  = (const float*)d_in[11];
    const float* wqs  = (const float*)d_in[12];
    const float* wks  = (const float*)d_in[13];
    const float* wvs  = (const float*)d_in[14];
    const float* wqss = (const float*)d_in[15];
    const float* wkss = (const float*)d_in[16];
    const float* fcw  = (const float*)d_in[17];

    float* out = (float*)d_out;
    float* scores = out + NB * NWAY * FEAT;  // d_out = [out | attn_score]

    char* wsb = (char*)d_ws;
    us* bwh    = (us*)(wsb + O_BWH);
    us* h      = (us*)(wsb + O_H);
    us* w1t    = (us*)(wsb + O_W1T);
    us* w2t    = (us*)(wsb + O_W2T);
    us* qwT    = (us*)(wsb + O_QWT);
    us* wvsT   = (us*)(wsb + O_WVST);
    us* fcwT   = (us*)(wsb + O_FCWT);
    us* pqt    = (us*)(wsb + O_PQT);
    us* wksT   = (us*)(wsb + O_WKST);
    us* wkssT  = (us*)(wsb + O_WKSST);
    us* w2n    = (us*)(wsb + O_W2N);
    float* pmax   = (float*)(wsb + O_PMAX);
    float* psum   = (float*)(wsb + O_PSUM);
    float* rmax   = (float*)(wsb + O_RMAX);
    float* rinv   = (float*)(wsb + O_RINV);
    float* mbw    = (float*)(wsb + O_MBW);
    float* mh     = (float*)(wsb + O_MH);
    float* gv     = (float*)(wsb + O_GV);
    float* gs     = (float*)(wsb + O_GS);
    float* psemr  = (float*)(wsb + O_PSEMR);
    float* ov     = (float*)(wsb + O_OV);
    float* qvisr  = (float*)(wsb + O_QVISR);
    float* cconst = (float*)(wsb + O_CC);

    k_prep<<<dim3(1664, 9), 256, 0, stream>>>(mw1, mw2, wqs, wqss, wvs, fcw, wks, wkss,
                                              w1t, w2t, qwT, wvsT, fcwT, wksT, wkssT, w2n, mbw);
    k_sup<<<dim3(13, 2), 256, 0, stream>>>(ssm, sf, w1t, w2t, mb1, mb2, qwT, wksT, wkssT,
                                           qvisr, psemr);
    k_cvt_bw<<<dim3(NB, 125), 256, 0, stream>>>(bw, bwh, mbw);
    k_hgemm_mfma<<<dim3(63, NB), 256, 0, stream>>>(bsm, w1t, mb1, h, mh);
    k_gates<<<dim3(13, NB), 256, 0, stream>>>(mbw, mh, mw2, mb2, vfw, vfb, sfw, sfb, gv, gs);
    k_s2<<<NB, 256, 0, stream>>>(qvisr, psemr, gv, gs, w2n, mb2, pqt, cconst);
    k_scores_mfma<<<dim3(63, NB), 256, 0, stream>>>(bwh, h, pqt, cconst, scores, pmax, psum);
    k_combine<<<NB, 256, 0, stream>>>(pmax, psum, rmax, rinv, ov);
    k_ov<<<dim3(NB, 50), 256, 0, stream>>>(scores, rmax, rinv, bwh, ov);
    k_out<<<NB, 256, 0, stream>>>(ov, wvsT, fcwT, sf, out);
}

// Round 4
// 568.998 us; speedup vs baseline: 1.2006x; 1.1572x over previous
//
#include <hip/hip_runtime.h>

#define NB 8
#define NWAY 16
#define NBASE 8000
#define FEAT 512
#define SEM 300
#define CAT (FEAT + SEM)  // 812
#define HLD 304           // padded h leading dim (16B-aligned rows)

typedef __attribute__((ext_vector_type(8))) short bf16x8;
typedef __attribute__((ext_vector_type(4))) float f32x4;
typedef __attribute__((ext_vector_type(8))) unsigned short us8;
typedef __attribute__((ext_vector_type(4))) unsigned short us4;
typedef __attribute__((ext_vector_type(2))) unsigned short us2;
typedef unsigned short us;

__device__ __forceinline__ us f2bf(float x) {
    union { float f; unsigned int u; } v; v.f = x;
    unsigned int r = v.u + 0x7FFFu + ((v.u >> 16) & 1u);
    return (us)(r >> 16);
}
__device__ __forceinline__ float bf2f(us u) {
    union { unsigned int u; float f; } v; v.u = ((unsigned int)u) << 16;
    return v.f;
}

// =============== workspace byte offsets (all 16B aligned) ===============
constexpr long O_BWH   = 0L;            // 8*8000*512*2 = 65,536,000
constexpr long O_H     = 65536000L;     // 8*8000*304*2 = 38,912,000
constexpr long O_W1T   = 104448000L;    // 320*320*2 = 204,800
constexpr long O_W2T   = 104652800L;    // 204,800
constexpr long O_QWT   = 104857600L;    // 512*832*2 = 851,968
constexpr long O_WVST  = 106496000L;    // 512*512*2 = 524,288
constexpr long O_FCWT  = 107020288L;    // 524,288
constexpr long O_PQT   = 107544576L;    // 8*16*840*2 = 215,040
constexpr long O_PMAX  = 107759616L;    // 8*16*63*4 = 32,256
constexpr long O_PSUM  = 107791872L;    // 32,256
constexpr long O_RMAX  = 107824128L;    // 512
constexpr long O_RINV  = 107824640L;    // 512
constexpr long O_F     = 107825152L;
constexpr long O_MBW   = O_F;            // 16,384 (mbw) + 9,600 (mh) contiguous
constexpr long O_MH    = O_F + 16384;
constexpr long O_GV    = O_F + 25984;    // 16,384
constexpr long O_GS    = O_F + 42368;    // 9,600
// time-multiplexed zone A (77,952..233,600):
//   ssmh bf16 128x320 (L1->L2), then qtotg bf16 128x512 (L4->L5)
constexpr long O_SSMH  = O_F + 77952;    // 81,920
constexpr long O_QTG   = O_F + 77952;    // 131,072 (aliases ssmh, disjoint in time)
constexpr long O_OV    = O_F + 233600;   // 128*512*4 = 262,144 (ov accumulator)
// time-multiplexed zone B (540,800..802,944):
//   sfh bf16 128x512 (L1->L4) @ +0, then psemG bf16 128x320 (L5->L6) @ +0
//   h1g bf16 128x320 (L2->L3) @ +131,072
constexpr long O_SFH   = O_F + 540800;   // 131,072
constexpr long O_PSG   = O_F + 540800;   // 81,920 (aliases sfh, disjoint in time)
constexpr long O_H1G   = O_F + 671872;   // 81,920
constexpr long O_CC    = O_F + 802944;   // 512
constexpr long O_WKST  = O_F + 803456;   // 512*512*2 = 524,288 (wks bf16)
constexpr long O_WKSST = O_F + 1327744;  // 320*512*2 = 327,680 (wkss bf16, row-pad)
constexpr long O_W2N   = O_F + 1655424;  // 320*320*2 = 204,800 (mw2 bf16 natural)
constexpr long O_SSCG  = O_F + 1860224;  // 128*320*2 = 81,920 (ssc bf16, L3->L4)

// =============== weight prep: bf16 converts/transposes + zero scratch ===============
__global__ void k_prep(const float* __restrict__ w1, const float* __restrict__ w2,
                       const float* __restrict__ wqs, const float* __restrict__ wqss,
                       const float* __restrict__ wvs, const float* __restrict__ fcw,
                       const float* __restrict__ wks, const float* __restrict__ wkss,
                       const float* __restrict__ sf, const float* __restrict__ ssm,
                       us* __restrict__ w1t, us* __restrict__ w2t, us* __restrict__ qwT,
                       us* __restrict__ wvsT, us* __restrict__ fcwT,
                       us* __restrict__ wksT, us* __restrict__ wkssT, us* __restrict__ w2n,
                       us* __restrict__ sfh, us* __restrict__ ssmh,
                       float* __restrict__ mz, float* __restrict__ cz, us* __restrict__ pqt) {
    long e = (long)blockIdx.x * 256 + threadIdx.x;
    switch (blockIdx.y) {
    case 0: if (e < 320 * 320) { int n = e / 320, k = e % 320;
            w1t[e] = f2bf((n < SEM && k < SEM) ? w1[(long)k * SEM + n] : 0.f); } break;
    case 1: if (e < 320 * 320) { int n = e / 320, k = e % 320;
            w2t[e] = f2bf((n < SEM && k < SEM) ? w2[(long)k * SEM + n] : 0.f); } break;
    case 2: if (e < 512 * 832) { int n = e / 832, k = e % 832;
            float v = 0.f;
            if (k < FEAT) v = wqs[(long)k * FEAT + n];
            else if (k < CAT) v = wqss[(long)(k - FEAT) * FEAT + n];
            qwT[e] = f2bf(v); } break;
    case 3: if (e < 512 * 512) { int n = e / 512, k = e % 512;
            wvsT[e] = f2bf(wvs[(long)k * FEAT + n]); } break;
    case 4: if (e < 512 * 512) { int n = e / 512, k = e % 512;
            fcwT[e] = f2bf(fcw[(long)k * FEAT + n]); } break;
    case 5:
        if (e < NB * FEAT + NB * SEM) mz[e] = 0.f;               // mbw + mh
        if (e < NB * NWAY) cz[e] = 0.f;                          // cconst
        if (e < 128 * 28) pqt[(e / 28) * 840 + 812 + (e % 28)] = 0;  // pqt pad cols
        break;
    case 6: if (e < 512 * 512) wksT[e] = f2bf(wks[e]); break;           // [fi][fo], straight
    case 7: if (e < 320 * 512) { int n = e / 512, k = e % 512;
            wkssT[e] = (n < SEM) ? f2bf(wkss[(long)n * FEAT + k]) : (us)0; } break;
    case 8: if (e < 320 * 320) { int n = e / 320, k = e % 320;
            w2n[e] = (n < SEM && k < SEM) ? f2bf(w2[(long)n * SEM + k]) : (us)0; } break;
    case 9: if (e < 128 * 512) sfh[e] = f2bf(sf[e]); break;
    case 10: if (e < 128 * 320) { int n = e / 320, k = e % 320;
            ssmh[e] = (k < SEM) ? f2bf(ssm[(long)n * SEM + k]) : (us)0; } break;
    }
}

// =============== L2: bw->bf16 + colsums, fused with mlp1 (h1) ===============
// blocks 0..9: mlp1 (h1 = leaky(ssm @ w1 + b1), 64rows x 64cols per block)
// blocks 10..1009: cvt_bw
__global__ __launch_bounds__(256) void k_cvt_mlp1(
        const float* __restrict__ bw, us* __restrict__ bwh, float* __restrict__ mbw,
        const us* __restrict__ ssmh, const us* __restrict__ w1t,
        const float* __restrict__ b1, us* __restrict__ h1g) {
    __shared__ float red[128][4];
    const int bid = blockIdx.x;
    const int t = threadIdx.x;
    if (bid < 10) {
        const int ctile = bid % 5, rh = bid / 5;
        const int wv = t >> 6, lane = t & 63;
        const int m16 = lane & 15, q = lane >> 4;
        const int nc0 = ctile * 64;
        const int n = nc0 + wv * 16 + m16;
        f32x4 acc[4];
        #pragma unroll
        for (int i = 0; i < 4; ++i) acc[i] = (f32x4){0.f, 0.f, 0.f, 0.f};
        for (int ks = 0; ks < 10; ++ks) {
            const int k = ks * 32 + q * 8;
            bf16x8 bb = *(const bf16x8*)(w1t + (long)n * 320 + k);
            #pragma unroll
            for (int mt = 0; mt < 4; ++mt) {
                bf16x8 a = *(const bf16x8*)(ssmh + (long)(rh * 64 + mt * 16 + m16) * 320 + k);
                acc[mt] = __builtin_amdgcn_mfma_f32_16x16x32_bf16(a, bb, acc[mt], 0, 0, 0);
            }
        }
        const int col = n;
        const float bias = (col < SEM) ? b1[col] : 0.f;
        #pragma unroll
        for (int mt = 0; mt < 4; ++mt)
            #pragma unroll
            for (int r = 0; r < 4; ++r) {
                float v = acc[mt][r] + bias;
                v = v > 0.f ? v : 0.1f * v;
                const int gr = rh * 64 + mt * 16 + q * 4 + r;
                h1g[(long)gr * 320 + col] = (col < SEM) ? f2bf(v) : (us)0;
            }
        return;
    }
    const int fb = bid - 10;
    const int b = fb / 125, ch = fb % 125;
    int cg = t & 127, rs = t >> 7;
    long base = ((long)b * NBASE + (long)ch * 64) * FEAT + cg * 4;
    float s0 = 0.f, s1 = 0.f, s2 = 0.f, s3 = 0.f;
    for (int r0 = rs * 4; r0 < 64; r0 += 8) {
        float4 v[4];
        #pragma unroll
        for (int u = 0; u < 4; ++u)
            v[u] = *(const float4*)(bw + base + (long)(r0 + u) * FEAT);
        #pragma unroll
        for (int u = 0; u < 4; ++u) {
            us4 o; o.x = f2bf(v[u].x); o.y = f2bf(v[u].y); o.z = f2bf(v[u].z); o.w = f2bf(v[u].w);
            *(us4*)(bwh + base + (long)(r0 + u) * FEAT) = o;
            s0 += v[u].x; s1 += v[u].y; s2 += v[u].z; s3 += v[u].w;
        }
    }
    if (rs == 1) { red[cg][0] = s0; red[cg][1] = s1; red[cg][2] = s2; red[cg][3] = s3; }
    __syncthreads();
    if (rs == 0) {
        atomicAdd(&mbw[b * FEAT + cg * 4 + 0], s0 + red[cg][0]);
        atomicAdd(&mbw[b * FEAT + cg * 4 + 1], s1 + red[cg][1]);
        atomicAdd(&mbw[b * FEAT + cg * 4 + 2], s2 + red[cg][2]);
        atomicAdd(&mbw[b * FEAT + cg * 4 + 3], s3 + red[cg][3]);
    }
}

// =============== L3: h-GEMM fused with mlp2 (ssc) ===============
// blocks 0..9: mlp2 (ssc = h1 @ w2 + b2); blocks 10..513: hgemm
__global__ __launch_bounds__(256, 2) void k_hg_mlp2(const float* __restrict__ X,
        const us* __restrict__ W1T, const float* __restrict__ b1,
        us* __restrict__ H, float* __restrict__ mh,
        const us* __restrict__ h1g, const us* __restrict__ w2t,
        const float* __restrict__ b2, us* __restrict__ sscg) {
    __shared__ char smem[128 * 304 * 2];  // 77,824 B
    const int bid = blockIdx.x;
    const int t = threadIdx.x;
    const int wv = t >> 6, lane = t & 63;
    const int m16 = lane & 15, q = lane >> 4;
    if (bid < 10) {
        const int ctile = bid % 5, rh = bid / 5;
        const int n = ctile * 64 + wv * 16 + m16;
        f32x4 acc[4];
        #pragma unroll
        for (int i = 0; i < 4; ++i) acc[i] = (f32x4){0.f, 0.f, 0.f, 0.f};
        for (int ks = 0; ks < 10; ++ks) {
            const int k = ks * 32 + q * 8;
            bf16x8 bb = *(const bf16x8*)(w2t + (long)n * 320 + k);
            #pragma unroll
            for (int mt = 0; mt < 4; ++mt) {
                bf16x8 a = *(const bf16x8*)(h1g + (long)(rh * 64 + mt * 16 + m16) * 320 + k);
                acc[mt] = __builtin_amdgcn_mfma_f32_16x16x32_bf16(a, bb, acc[mt], 0, 0, 0);
            }
        }
        const int col = n;
        const float bias = (col < SEM) ? b2[col] : 0.f;
        #pragma unroll
        for (int mt = 0; mt < 4; ++mt)
            #pragma unroll
            for (int r = 0; r < 4; ++r) {
                const int gr = rh * 64 + mt * 16 + q * 4 + r;
                sscg[(long)gr * 320 + col] = (col < SEM) ? f2bf(acc[mt][r] + bias) : (us)0;
            }
        return;
    }
    us (*As)[72] = (us(*)[72])smem;                    // 128*72*2 = 18,432
    us (*Bs)[72] = (us(*)[72])(smem + 18432);          // 320*72*2 = 46,080
    us (*Cs)[HLD] = (us(*)[HLD])smem;                  // epilogue alias
    const int fb = bid - 10;
    const int b = fb / 63;
    const int bm = (fb % 63) * 128;
    const long rowbase = (long)b * NBASE;
    f32x4 acc[8][5];
    #pragma unroll
    for (int i = 0; i < 8; ++i)
        #pragma unroll
        for (int j = 0; j < 5; ++j) acc[i][j] = (f32x4){0.f, 0.f, 0.f, 0.f};
    for (int ks = 0; ks < 5; ++ks) {
        const int k0 = ks * 64;
        #pragma unroll
        for (int it = 0; it < 8; ++it) {
            int c = t + it * 256;
            int row = c >> 4, j = c & 15;
            int gk = k0 + j * 4;
            float4 v = make_float4(0.f, 0.f, 0.f, 0.f);
            if (gk < SEM && bm + row < NBASE)
                v = *(const float4*)(X + (rowbase + bm + row) * SEM + gk);
            us4 u; u.x = f2bf(v.x); u.y = f2bf(v.y); u.z = f2bf(v.z); u.w = f2bf(v.w);
            *(us4*)(&As[row][j * 4]) = u;
        }
        #pragma unroll
        for (int it = 0; it < 10; ++it) {
            int c = t + it * 256;
            int n = c >> 3, j = c & 7;
            int4 v = *(const int4*)(W1T + (long)n * 320 + k0 + j * 8);
            *(int4*)(&Bs[n][j * 8]) = v;
        }
        __syncthreads();
        #pragma unroll
        for (int kc = 0; kc < 64; kc += 32) {
            bf16x8 a[8], bb[5];
            #pragma unroll
            for (int rt = 0; rt < 8; ++rt)
                a[rt] = *(const bf16x8*)(&As[rt * 16 + m16][kc + q * 8]);
            #pragma unroll
            for (int ct = 0; ct < 5; ++ct)
                bb[ct] = *(const bf16x8*)(&Bs[(wv * 5 + ct) * 16 + m16][kc + q * 8]);
            #pragma unroll
            for (int rt = 0; rt < 8; ++rt)
                #pragma unroll
                for (int ct = 0; ct < 5; ++ct)
                    acc[rt][ct] = __builtin_amdgcn_mfma_f32_16x16x32_bf16(a[rt], bb[ct], acc[rt][ct], 0, 0, 0);
        }
        __syncthreads();
    }
    float csum[5] = {0.f, 0.f, 0.f, 0.f, 0.f};
    #pragma unroll
    for (int ct = 0; ct < 5; ++ct) {
        int col = (wv * 5 + ct) * 16 + m16;
        float bias = (col < SEM) ? b1[col] : 0.f;
        #pragma unroll
        for (int rt = 0; rt < 8; ++rt) {
            int rl = rt * 16 + q * 4;
            #pragma unroll
            for (int r = 0; r < 4; ++r) {
                float v = acc[rt][ct][r] + bias;
                v = v > 0.f ? v : 0.1f * v;
                if (col < SEM && bm + rl + r < NBASE) {
                    Cs[rl + r][col] = f2bf(v);
                    csum[ct] += v;
                }
            }
        }
    }
    if (t < 128) *(us4*)(&Cs[t][300]) = (us4){0, 0, 0, 0};
    #pragma unroll
    for (int ct = 0; ct < 5; ++ct) {
        float s = csum[ct];
        s += __shfl_xor(s, 16);
        s += __shfl_xor(s, 32);
        int col = (wv * 5 + ct) * 16 + m16;
        if (q == 0 && col < SEM) atomicAdd(&mh[b * SEM + col], s);
    }
    __syncthreads();
    for (int i = t; i < 128 * 76; i += 256) {
        int row = i / 76, j = i % 76;
        if (bm + row < NBASE)
            *(us4*)(H + (rowbase + bm + row) * HLD + j * 4) = *(const us4*)(&Cs[row][j * 4]);
    }
}

// =============== L4: gates fused with qtot ===============
// blocks 0..15: qtot = [sf|ssc] @ qwT^T; blocks 16..119: gates
__global__ __launch_bounds__(256) void k_gates_qtot(
        const float* __restrict__ mbw, const float* __restrict__ mh,
        const float* __restrict__ mw2, const float* __restrict__ mb2,
        const float* __restrict__ vfw, const float* __restrict__ vfb,
        const float* __restrict__ sfw, const float* __restrict__ sfb,
        float* __restrict__ gv, float* __restrict__ gs,
        const us* __restrict__ sfh, const us* __restrict__ sscg,
        const us* __restrict__ qwT, us* __restrict__ qtotg) {
    __shared__ float avgL[CAT];
    __shared__ float mhL[SEM];
    __shared__ float red[4][64];
    const int bid = blockIdx.x;
    const int t = threadIdx.x;
    if (bid < 16) {
        const int ctile = bid % 8, rh = bid / 8;
        const int wv = t >> 6, lane = t & 63;
        const int m16 = lane & 15, q = lane >> 4;
        const int n = ctile * 64 + wv * 16 + m16;
        f32x4 acc[4];
        #pragma unroll
        for (int i = 0; i < 4; ++i) acc[i] = (f32x4){0.f, 0.f, 0.f, 0.f};
        for (int ks = 0; ks < 26; ++ks) {
            const int k = ks * 32 + q * 8;
            bf16x8 bb = *(const bf16x8*)(qwT + (long)n * 832 + k);
            #pragma unroll
            for (int mt = 0; mt < 4; ++mt) {
                const int gr = rh * 64 + mt * 16 + m16;
                bf16x8 a = (k < FEAT)
                    ? *(const bf16x8*)(sfh + (long)gr * 512 + k)
                    : *(const bf16x8*)(sscg + (long)gr * 320 + (k - FEAT));
                acc[mt] = __builtin_amdgcn_mfma_f32_16x16x32_bf16(a, bb, acc[mt], 0, 0, 0);
            }
        }
        #pragma unroll
        for (int mt = 0; mt < 4; ++mt)
            #pragma unroll
            for (int r = 0; r < 4; ++r) {
                const int gr = rh * 64 + mt * 16 + q * 4 + r;
                qtotg[(long)gr * 512 + n] = f2bf(acc[mt][r]);
            }
        return;
    }
    const int tile = (bid - 16) % 13, b = (bid - 16) / 13;
    const float invN = 1.0f / NBASE;
    for (int i = t; i < SEM; i += 256) mhL[i] = mh[b * SEM + i] * invN;
    for (int i = t; i < FEAT; i += 256) avgL[i] = mbw[b * FEAT + i] * invN;
    __syncthreads();
    for (int s = t; s < SEM; s += 256) {
        float a = mb2[s];
        for (int c = 0; c < SEM; ++c) a += mhL[c] * mw2[(long)c * SEM + s];
        avgL[FEAT + s] = a;
    }
    __syncthreads();
    int l = t & 63, kq = t >> 6;
    float a = 0.f;
    if (tile < 8) {
        int f = tile * 64 + l;
        for (int c = kq * 203; c < kq * 203 + 203; ++c) a += avgL[c] * vfw[(long)c * FEAT + f];
        red[kq][l] = a;
        __syncthreads();
        if (kq == 0) {
            float s = red[0][l] + red[1][l] + red[2][l] + red[3][l] + vfb[f];
            gv[b * FEAT + f] = 1.f + 1.f / (1.f + expf(-s));
        }
    } else {
        int fs = (tile - 8) * 64 + l;
        if (fs < SEM)
            for (int c = kq * 203; c < kq * 203 + 203; ++c) a += avgL[c] * sfw[(long)c * SEM + fs];
        red[kq][l] = a;
        __syncthreads();
        if (kq == 0 && fs < SEM) {
            float s = red[0][l] + red[1][l] + red[2][l] + red[3][l] + sfb[fs];
            gs[b * SEM + fs] = 1.f + 1.f / (1.f + expf(-s));
        }
    }
}

// =============== L5: projections + gate apply + pqt assembly + cconst partials ===============
// 26 blocks: nslot 0..7 -> qvis 64-col tile into pqt[:,0:512); 8..12 -> psem tile
__global__ __launch_bounds__(256) void k_projgate(
        const us* __restrict__ qtotg, const us* __restrict__ wksT,
        const us* __restrict__ wkssT, const float* __restrict__ gv,
        const float* __restrict__ gs, const float* __restrict__ b2,
        us* __restrict__ pqt, us* __restrict__ psemG, float* __restrict__ cconst) {
    const int bid = blockIdx.x;
    const int nslot = bid % 13, rh = bid / 13;
    const int t = threadIdx.x;
    const int wv = t >> 6, lane = t & 63;
    const int m16 = lane & 15, q = lane >> 4;
    const bool isv = (nslot < 8);
    const int nc0 = isv ? nslot * 64 : (nslot - 8) * 64;
    const us* BT = isv ? wksT : wkssT;
    const int n = nc0 + wv * 16 + m16;
    f32x4 acc[4];
    #pragma unroll
    for (int i = 0; i < 4; ++i) acc[i] = (f32x4){0.f, 0.f, 0.f, 0.f};
    for (int ks = 0; ks < 16; ++ks) {
        const int k = ks * 32 + q * 8;
        bf16x8 bb = *(const bf16x8*)(BT + (long)n * 512 + k);
        #pragma unroll
        for (int mt = 0; mt < 4; ++mt) {
            bf16x8 a = *(const bf16x8*)(qtotg + (long)(rh * 64 + mt * 16 + m16) * 512 + k);
            acc[mt] = __builtin_amdgcn_mfma_f32_16x16x32_bf16(a, bb, acc[mt], 0, 0, 0);
        }
    }
    const int col = n;
    if (isv) {
        #pragma unroll
        for (int mt = 0; mt < 4; ++mt)
            #pragma unroll
            for (int r = 0; r < 4; ++r) {
                const int gr = rh * 64 + mt * 16 + q * 4 + r;
                const int b = gr >> 4;
                pqt[(long)gr * 840 + col] = f2bf(acc[mt][r] * gv[b * FEAT + col]);
            }
    } else {
        const float b2c = (col < SEM) ? b2[col] : 0.f;
        #pragma unroll
        for (int mt = 0; mt < 4; ++mt)
            #pragma unroll
            for (int r = 0; r < 4; ++r) {
                const int gr = rh * 64 + mt * 16 + q * 4 + r;
                const int b = gr >> 4;
                float p = (col < SEM) ? acc[mt][r] * gs[b * SEM + col] : 0.f;
                psemG[(long)gr * 320 + col] = (col < SEM) ? f2bf(p) : (us)0;
                float ps = p * b2c;  // cconst = dot(psem_gated, b2)
                ps += __shfl_xor(ps, 1); ps += __shfl_xor(ps, 2);
                ps += __shfl_xor(ps, 4); ps += __shfl_xor(ps, 8);
                if (m16 == 0) atomicAdd(&cconst[b * NWAY + (gr & 15)], ps);
            }
    }
}

// =============== L6: pqt[:,512:812) = psemG @ w2n^T ===============
__global__ __launch_bounds__(256) void k_sem2(const us* __restrict__ psemG,
        const us* __restrict__ w2n, us* __restrict__ pqt) {
    const int bid = blockIdx.x;
    const int ctile = bid % 5, rh = bid / 5;
    const int t = threadIdx.x;
    const int wv = t >> 6, lane = t & 63;
    const int m16 = lane & 15, q = lane >> 4;
    const int n = ctile * 64 + wv * 16 + m16;
    f32x4 acc[4];
    #pragma unroll
    for (int i = 0; i < 4; ++i) acc[i] = (f32x4){0.f, 0.f, 0.f, 0.f};
    for (int ks = 0; ks < 10; ++ks) {
        const int k = ks * 32 + q * 8;
        bf16x8 bb = *(const bf16x8*)(w2n + (long)n * 320 + k);
        #pragma unroll
        for (int mt = 0; mt < 4; ++mt) {
            bf16x8 a = *(const bf16x8*)(psemG + (long)(rh * 64 + mt * 16 + m16) * 320 + k);
            acc[mt] = __builtin_amdgcn_mfma_f32_16x16x32_bf16(a, bb, acc[mt], 0, 0, 0);
        }
    }
    const int col = n;
    if (col < SEM) {
        #pragma unroll
        for (int mt = 0; mt < 4; ++mt)
            #pragma unroll
            for (int r = 0; r < 4; ++r) {
                const int gr = rh * 64 + mt * 16 + q * 4 + r;
                pqt[(long)gr * 840 + 512 + col] = f2bf(acc[mt][r]);
            }
    }
}

// =============== scores + fused per-block softmax partials (KB=64 stages) ===============
__global__ __launch_bounds__(256) void k_scores_mfma(const us* __restrict__ bwh,
        const us* __restrict__ h, const us* __restrict__ pqt,
        const float* __restrict__ cconst, float* __restrict__ scores,
        float* __restrict__ pmax, float* __restrict__ psum) {
    __shared__ us As[128][72];       // [m][64k] +8 pad
    __shared__ us Bs[NWAY][840];
    __shared__ float sred[4][16];
    const int b = blockIdx.y;
    const int bm = blockIdx.x * 128;
    const int t = threadIdx.x;
    const int wv = t >> 6, lane = t & 63;
    const int m16 = lane & 15, q = lane >> 4;
    for (int c = t; c < NWAY * 105; c += 256) {
        int n = c / 105, j = c % 105;
        *(int4*)(&Bs[n][j * 8]) = *(const int4*)(pqt + ((long)b * NWAY + n) * 840 + j * 8);
    }
    f32x4 acc[2];
    acc[0] = (f32x4){0, 0, 0, 0};
    acc[1] = (f32x4){0, 0, 0, 0};
    for (int ks = 0; ks < 13; ++ks) {
        int k0 = ks * 64;
        #pragma unroll
        for (int it = 0; it < 4; ++it) {
            int c = t + it * 256;
            int row = c >> 3, j = c & 7;
            int gm = bm + row, gk = k0 + j * 8;
            us8 u = (us8){0, 0, 0, 0, 0, 0, 0, 0};
            if (gk < FEAT)      u = *(const us8*)(bwh + ((long)b * NBASE + gm) * FEAT + gk);
            else if (gk < CAT)  u = *(const us8*)(h + ((long)b * NBASE + gm) * HLD + (gk - FEAT));
            *(us8*)(&As[row][j * 8]) = u;
        }
        __syncthreads();
        #pragma unroll
        for (int kc = 0; kc < 64; kc += 32) {
            bf16x8 bb = *(const bf16x8*)(&Bs[m16][k0 + kc + q * 8]);
            #pragma unroll
            for (int rt = 0; rt < 2; ++rt) {
                bf16x8 a = *(const bf16x8*)(&As[wv * 32 + rt * 16 + m16][kc + q * 8]);
                acc[rt] = __builtin_amdgcn_mfma_f32_16x16x32_bf16(a, bb, acc[rt], 0, 0, 0);
            }
        }
        __syncthreads();
    }
    const float invT = 0.04419417382415922f;  // 1/sqrt(512)
    float cadd = cconst[b * NWAY + m16];
    float vals[8];
    #pragma unroll
    for (int rt = 0; rt < 2; ++rt) {
        int nrow = bm + wv * 32 + rt * 16 + q * 4;
        #pragma unroll
        for (int r = 0; r < 4; ++r) {
            float v = (nrow + r < NBASE) ? (acc[rt][r] + cadd) * invT : -1e30f;
            vals[rt * 4 + r] = v;
        }
        if (nrow + 3 < NBASE) {
            float4 st = make_float4(vals[rt * 4], vals[rt * 4 + 1], vals[rt * 4 + 2], vals[rt * 4 + 3]);
            *(float4*)(scores + ((long)b * NWAY + m16) * NBASE + nrow) = st;
        } else {
            for (int r = 0; r < 4; ++r)
                if (nrow + r < NBASE)
                    scores[((long)b * NWAY + m16) * NBASE + nrow + r] = vals[rt * 4 + r];
        }
    }
    float lm = vals[0];
    #pragma unroll
    for (int i = 1; i < 8; ++i) lm = fmaxf(lm, vals[i]);
    lm = fmaxf(lm, __shfl_xor(lm, 16));
    lm = fmaxf(lm, __shfl_xor(lm, 32));
    if (q == 0) sred[wv][m16] = lm;
    __syncthreads();
    float bmax = fmaxf(fmaxf(sred[0][m16], sred[1][m16]), fmaxf(sred[2][m16], sred[3][m16]));
    __syncthreads();
    float ls = 0.f;
    #pragma unroll
    for (int i = 0; i < 8; ++i) ls += __expf(vals[i] - bmax);
    ls += __shfl_xor(ls, 16);
    ls += __shfl_xor(ls, 32);
    if (q == 0) sred[wv][m16] = ls;
    __syncthreads();
    if (wv == 0 && lane < 16) {
        float tot = sred[0][m16] + sred[1][m16] + sred[2][m16] + sred[3][m16];
        pmax[((long)b * NWAY + m16) * 63 + blockIdx.x] = bmax;
        psum[((long)b * NWAY + m16) * 63 + blockIdx.x] = tot;
    }
}

// =============== combine partials -> row max & 1/sum (+ zero ov) ===============
__global__ void k_combine(const float* __restrict__ pmax, const float* __restrict__ psum,
                          float* __restrict__ rmax, float* __restrict__ rinv,
                          float* __restrict__ ov) {
    int b = blockIdx.x, t = threadIdx.x;
    float4 z = make_float4(0.f, 0.f, 0.f, 0.f);
    for (int i = t; i < 2048; i += 256)
        *(float4*)(ov + ((long)b * 2048 + i) * 4) = z;
    int w = t >> 4, l = t & 15;
    long base = ((long)b * NWAY + w) * 63;
    float m = -1e30f;
    for (int i = l; i < 63; i += 16) m = fmaxf(m, pmax[base + i]);
    m = fmaxf(m, __shfl_xor(m, 1)); m = fmaxf(m, __shfl_xor(m, 2));
    m = fmaxf(m, __shfl_xor(m, 4)); m = fmaxf(m, __shfl_xor(m, 8));
    float s = 0.f;
    for (int i = l; i < 63; i += 16) s += psum[base + i] * __expf(pmax[base + i] - m);
    s += __shfl_xor(s, 1); s += __shfl_xor(s, 2);
    s += __shfl_xor(s, 4); s += __shfl_xor(s, 8);
    if (l == 0) { rmax[b * NWAY + w] = m; rinv[b * NWAY + w] = 1.0f / s; }
}

// =============== ov = softmax(scores) @ bwh, exp fused, unroll-8 ===============
__global__ void k_ov(const float* __restrict__ scores, const float* __restrict__ rmax,
                     const float* __restrict__ rinv, const us* __restrict__ bwh,
                     float* __restrict__ ov) {
    int b = blockIdx.x, ch = blockIdx.y;  // 50 chunks of 160 rows
    int t = threadIdx.x;
    __shared__ float pr[NWAY][160];
    for (int i = t; i < NWAY * 160; i += 256) {
        int w = i / 160, j = i % 160;
        float sc = scores[((long)b * NWAY + w) * NBASE + (long)ch * 160 + j];
        pr[w][j] = __expf(sc - rmax[b * NWAY + w]) * rinv[b * NWAY + w];
    }
    __syncthreads();
    float a0[NWAY], a1[NWAY];
    #pragma unroll
    for (int w = 0; w < NWAY; ++w) { a0[w] = 0.f; a1[w] = 0.f; }
    const us* bp = bwh + ((long)b * NBASE + (long)ch * 160) * FEAT + 2 * t;
    for (int j0 = 0; j0 < 160; j0 += 8) {
        us2 u[8];
        #pragma unroll
        for (int uu = 0; uu < 8; ++uu)
            u[uu] = *(const us2*)(bp + (long)(j0 + uu) * FEAT);
        #pragma unroll
        for (int uu = 0; uu < 8; ++uu) {
            float v0 = bf2f(u[uu].x), v1 = bf2f(u[uu].y);
            #pragma unroll
            for (int w = 0; w < NWAY; ++w) {
                a0[w] += pr[w][j0 + uu] * v0;
                a1[w] += pr[w][j0 + uu] * v1;
            }
        }
    }
    for (int w = 0; w < NWAY; ++w) {
        atomicAdd(&ov[((long)b * NWAY + w) * FEAT + 2 * t], a0[w]);
        atomicAdd(&ov[((long)b * NWAY + w) * FEAT + 2 * t + 1], a1[w]);
    }
}

// =============== fused output: out = (ov @ wvsT) @ fcwT + sf ===============
__global__ __launch_bounds__(256) void k_out(const float* __restrict__ ov,
        const us* __restrict__ wvsT, const us* __restrict__ fcwT,
        const float* __restrict__ sf, float* __restrict__ out) {
    __shared__ us Os[16][520];
    __shared__ us Ts[16][520];
    const int bx = blockIdx.x;
    const int t = threadIdx.x;
    const int wv = t >> 6, lane = t & 63;
    const int m16 = lane & 15, q = lane >> 4;
    const long r0 = (long)bx * NWAY;
    for (int i = t; i < 16 * 128; i += 256) {
        int r = i >> 7, c4 = (i & 127) * 4;
        float4 v = *(const float4*)(ov + (r0 + r) * FEAT + c4);
        us4 u; u.x = f2bf(v.x); u.y = f2bf(v.y); u.z = f2bf(v.z); u.w = f2bf(v.w);
        *(us4*)(&Os[r][c4]) = u;
    }
    __syncthreads();
    {
        f32x4 acc[8];
        #pragma unroll
        for (int i = 0; i < 8; ++i) acc[i] = (f32x4){0.f, 0.f, 0.f, 0.f};
        for (int ks = 0; ks < 16; ++ks) {
            bf16x8 a = *(const bf16x8*)(&Os[m16][ks * 32 + q * 8]);
            #pragma unroll
            for (int ct = 0; ct < 8; ++ct) {
                int nr = wv * 128 + ct * 16 + m16;
                bf16x8 bb = *(const bf16x8*)(wvsT + (long)nr * 512 + ks * 32 + q * 8);
                acc[ct] = __builtin_amdgcn_mfma_f32_16x16x32_bf16(a, bb, acc[ct], 0, 0, 0);
            }
        }
        #pragma unroll
        for (int ct = 0; ct < 8; ++ct) {
            int col = wv * 128 + ct * 16 + m16;
            #pragma unroll
            for (int r = 0; r < 4; ++r) Ts[q * 4 + r][col] = f2bf(acc[ct][r]);
        }
    }
    __syncthreads();
    {
        f32x4 acc[8];
        #pragma unroll
        for (int i = 0; i < 8; ++i) acc[i] = (f32x4){0.f, 0.f, 0.f, 0.f};
        for (int ks = 0; ks < 16; ++ks) {
            bf16x8 a = *(const bf16x8*)(&Ts[m16][ks * 32 + q * 8]);
            #pragma unroll
            for (int ct = 0; ct < 8; ++ct) {
                int nr = wv * 128 + ct * 16 + m16;
                bf16x8 bb = *(const bf16x8*)(fcwT + (long)nr * 512 + ks * 32 + q * 8);
                acc[ct] = __builtin_amdgcn_mfma_f32_16x16x32_bf16(a, bb, acc[ct], 0, 0, 0);
            }
        }
        #pragma unroll
        for (int ct = 0; ct < 8; ++ct) {
            int col = wv * 128 + ct * 16 + m16;
            #pragma unroll
            for (int r = 0; r < 4; ++r) {
                long row = r0 + q * 4 + r;
                out[row * FEAT + col] = acc[ct][r] + sf[row * FEAT + col];
            }
        }
    }
}

extern "C" void kernel_launch(void* const* d_in, const int* in_sizes, int n_in,
                              void* d_out, int out_size, void* d_ws, size_t ws_size,
                              hipStream_t stream) {
    (void)in_sizes; (void)n_in; (void)out_size; (void)ws_size;
    const float* sf   = (const float*)d_in[0];
    const float* bw   = (const float*)d_in[1];
    const float* ssm  = (const float*)d_in[2];
    const float* bsm  = (const float*)d_in[3];
    const float* mw1  = (const float*)d_in[4];
    const float* mb1  = (const float*)d_in[5];
    const float* mw2  = (const float*)d_in[6];
    const float* mb2  = (const float*)d_in[7];
    const float* vfw  = (const float*)d_in[8];
    const float* vfb  = (const float*)d_in[9];
    const float* sfw  = (const float*)d_in[10];
    const float* sfb  = (const float*)d_in[11];
    const float* wqs  = (const float*)d_in[12];
    const float* wks  = (const float*)d_in[13];
    const float* wvs  = (const float*)d_in[14];
    const float* wqss = (const float*)d_in[15];
    const float* wkss = (const float*)d_in[16];
    const float* fcw  = (const float*)d_in[17];

    float* out = (float*)d_out;
    float* scores = out + NB * NWAY * FEAT;  // d_out = [out | attn_score]

    char* wsb = (char*)d_ws;
    us* bwh    = (us*)(wsb + O_BWH);
    us* h      = (us*)(wsb + O_H);
    us* w1t    = (us*)(wsb + O_W1T);
    us* w2t    = (us*)(wsb + O_W2T);
    us* qwT    = (us*)(wsb + O_QWT);
    us* wvsT   = (us*)(wsb + O_WVST);
    us* fcwT   = (us*)(wsb + O_FCWT);
    us* pqt    = (us*)(wsb + O_PQT);
    us* wksT   = (us*)(wsb + O_WKST);
    us* wkssT  = (us*)(wsb + O_WKSST);
    us* w2n    = (us*)(wsb + O_W2N);
    us* sfh    = (us*)(wsb + O_SFH);
    us* ssmh   = (us*)(wsb + O_SSMH);
    us* h1g    = (us*)(wsb + O_H1G);
    us* sscg   = (us*)(wsb + O_SSCG);
    us* qtotg  = (us*)(wsb + O_QTG);
    us* psemG  = (us*)(wsb + O_PSG);
    float* pmax   = (float*)(wsb + O_PMAX);
    float* psum   = (float*)(wsb + O_PSUM);
    float* rmax   = (float*)(wsb + O_RMAX);
    float* rinv   = (float*)(wsb + O_RINV);
    float* mbw    = (float*)(wsb + O_MBW);
    float* mh     = (float*)(wsb + O_MH);
    float* gv     = (float*)(wsb + O_GV);
    float* gs     = (float*)(wsb + O_GS);
    float* ov     = (float*)(wsb + O_OV);
    float* cconst = (float*)(wsb + O_CC);

    k_prep<<<dim3(1664, 11), 256, 0, stream>>>(mw1, mw2, wqs, wqss, wvs, fcw, wks, wkss,
                                               sf, ssm,
                                               w1t, w2t, qwT, wvsT, fcwT, wksT, wkssT, w2n,
                                               sfh, ssmh, mbw, cconst, pqt);
    k_cvt_mlp1<<<1010, 256, 0, stream>>>(bw, bwh, mbw, ssmh, w1t, mb1, h1g);
    k_hg_mlp2<<<514, 256, 0, stream>>>(bsm, w1t, mb1, h, mh, h1g, w2t, mb2, sscg);
    k_gates_qtot<<<120, 256, 0, stream>>>(mbw, mh, mw2, mb2, vfw, vfb, sfw, sfb, gv, gs,
                                          sfh, sscg, qwT, qtotg);
    k_projgate<<<26, 256, 0, stream>>>(qtotg, wksT, wkssT, gv, gs, mb2, pqt, psemG, cconst);
    k_sem2<<<10, 256, 0, stream>>>(psemG, w2n, pqt);
    k_scores_mfma<<<dim3(63, NB), 256, 0, stream>>>(bwh, h, pqt, cconst, scores, pmax, psum);
    k_combine<<<NB, 256, 0, stream>>>(pmax, psum, rmax, rinv, ov);
    k_ov<<<dim3(NB, 50), 256, 0, stream>>>(scores, rmax, rinv, bwh, ov);
    k_out<<<NB, 256, 0, stream>>>(ov, wvsT, fcwT, sf, out);
}

// Round 5
// 522.152 us; speedup vs baseline: 1.3083x; 1.0897x over previous
//
#include <hip/hip_runtime.h>

#define NB 8
#define NWAY 16
#define NBASE 8000
#define FEAT 512
#define SEM 300
#define CAT (FEAT + SEM)  // 812
#define HLD 304           // padded h leading dim (16B-aligned rows)

typedef __attribute__((ext_vector_type(8))) short bf16x8;
typedef __attribute__((ext_vector_type(4))) float f32x4;
typedef __attribute__((ext_vector_type(8))) unsigned short us8;
typedef __attribute__((ext_vector_type(4))) unsigned short us4;
typedef __attribute__((ext_vector_type(2))) unsigned short us2;
typedef unsigned short us;

__device__ __forceinline__ us f2bf(float x) {
    union { float f; unsigned int u; } v; v.f = x;
    unsigned int r = v.u + 0x7FFFu + ((v.u >> 16) & 1u);
    return (us)(r >> 16);
}
__device__ __forceinline__ float bf2f(us u) {
    union { unsigned int u; float f; } v; v.u = ((unsigned int)u) << 16;
    return v.f;
}

// =============== workspace byte offsets (all 16B aligned) ===============
constexpr long O_BWH   = 0L;            // 8*8000*512*2 = 65,536,000
constexpr long O_H     = 65536000L;     // 8*8000*304*2 = 38,912,000
constexpr long O_W1T   = 104448000L;    // 320*320*2 = 204,800
constexpr long O_W2T   = 104652800L;    // 204,800
constexpr long O_QWT   = 104857600L;    // 512*832*2 = 851,968
constexpr long O_WVST  = 106496000L;    // 512*512*2 = 524,288
constexpr long O_FCWT  = 107020288L;    // 524,288
constexpr long O_PQT   = 107544576L;    // 8*16*840*2 = 215,040
constexpr long O_PMAX  = 107759616L;    // 8*16*63*4 = 32,256
constexpr long O_PSUM  = 107791872L;    // 32,256
constexpr long O_RMAX  = 107824128L;    // 512
constexpr long O_RINV  = 107824640L;    // 512
constexpr long O_F     = 107825152L;
constexpr long O_MBW   = O_F;            // 16,384 (mbw) + 9,600 (mh) contiguous
constexpr long O_MH    = O_F + 16384;
constexpr long O_GV    = O_F + 25984;    // 16,384
constexpr long O_GS    = O_F + 42368;    // 9,600
// time-multiplexed zone A (77,952..233,600):
//   ssmh bf16 128x320 (L1->L2), then qtotg bf16 128x512 (L4->L5), then tmp bf16 (k_out1->k_out2)
constexpr long O_SSMH  = O_F + 77952;    // 81,920
constexpr long O_QTG   = O_F + 77952;    // 131,072 (aliases ssmh, disjoint in time)
constexpr long O_OV    = O_F + 233600;   // 128*512*4 = 262,144 (ov accumulator)
// time-multiplexed zone B (540,800..802,944):
//   sfh bf16 128x512 (L1->L4) @ +0, then psemG bf16 128x320 (L5->L6) @ +0
//   h1g bf16 128x320 (L2->L3) @ +131,072
constexpr long O_SFH   = O_F + 540800;   // 131,072
constexpr long O_PSG   = O_F + 540800;   // 81,920 (aliases sfh, disjoint in time)
constexpr long O_H1G   = O_F + 671872;   // 81,920
constexpr long O_CC    = O_F + 802944;   // 512
constexpr long O_WKST  = O_F + 803456;   // 512*512*2 = 524,288 (wks bf16)
constexpr long O_WKSST = O_F + 1327744;  // 320*512*2 = 327,680 (wkss bf16, row-pad)
constexpr long O_W2N   = O_F + 1655424;  // 320*320*2 = 204,800 (mw2 bf16 natural)
constexpr long O_SSCG  = O_F + 1860224;  // 128*320*2 = 81,920 (ssc bf16, L3->L4)

// =============== weight prep: bf16 converts/transposes + zero scratch ===============
__global__ void k_prep(const float* __restrict__ w1, const float* __restrict__ w2,
                       const float* __restrict__ wqs, const float* __restrict__ wqss,
                       const float* __restrict__ wvs, const float* __restrict__ fcw,
                       const float* __restrict__ wks, const float* __restrict__ wkss,
                       const float* __restrict__ sf, const float* __restrict__ ssm,
                       us* __restrict__ w1t, us* __restrict__ w2t, us* __restrict__ qwT,
                       us* __restrict__ wvsT, us* __restrict__ fcwT,
                       us* __restrict__ wksT, us* __restrict__ wkssT, us* __restrict__ w2n,
                       us* __restrict__ sfh, us* __restrict__ ssmh,
                       float* __restrict__ mz, float* __restrict__ cz, us* __restrict__ pqt) {
    long e = (long)blockIdx.x * 256 + threadIdx.x;
    switch (blockIdx.y) {
    case 0: if (e < 320 * 320) { int n = e / 320, k = e % 320;
            w1t[e] = f2bf((n < SEM && k < SEM) ? w1[(long)k * SEM + n] : 0.f); } break;
    case 1: if (e < 320 * 320) { int n = e / 320, k = e % 320;
            w2t[e] = f2bf((n < SEM && k < SEM) ? w2[(long)k * SEM + n] : 0.f); } break;
    case 2: if (e < 512 * 832) { int n = e / 832, k = e % 832;
            float v = 0.f;
            if (k < FEAT) v = wqs[(long)k * FEAT + n];
            else if (k < CAT) v = wqss[(long)(k - FEAT) * FEAT + n];
            qwT[e] = f2bf(v); } break;
    case 3: if (e < 512 * 512) { int n = e / 512, k = e % 512;
            wvsT[e] = f2bf(wvs[(long)k * FEAT + n]); } break;
    case 4: if (e < 512 * 512) { int n = e / 512, k = e % 512;
            fcwT[e] = f2bf(fcw[(long)k * FEAT + n]); } break;
    case 5:
        if (e < NB * FEAT + NB * SEM) mz[e] = 0.f;               // mbw + mh
        if (e < NB * NWAY) cz[e] = 0.f;                          // cconst
        if (e < 128 * 28) pqt[(e / 28) * 840 + 812 + (e % 28)] = 0;  // pqt pad cols
        break;
    case 6: if (e < 512 * 512) wksT[e] = f2bf(wks[e]); break;           // [fi][fo], straight
    case 7: if (e < 320 * 512) { int n = e / 512, k = e % 512;
            wkssT[e] = (n < SEM) ? f2bf(wkss[(long)n * FEAT + k]) : (us)0; } break;
    case 8: if (e < 320 * 320) { int n = e / 320, k = e % 320;
            w2n[e] = (n < SEM && k < SEM) ? f2bf(w2[(long)n * SEM + k]) : (us)0; } break;
    case 9: if (e < 128 * 512) sfh[e] = f2bf(sf[e]); break;
    case 10: if (e < 128 * 320) { int n = e / 320, k = e % 320;
            ssmh[e] = (k < SEM) ? f2bf(ssm[(long)n * SEM + k]) : (us)0; } break;
    }
}

// =============== L2: bw->bf16 + colsums, fused with mlp1 (h1) ===============
// blocks 0..9: mlp1 (h1 = leaky(ssm @ w1 + b1), 64rows x 64cols per block)
// blocks 10..1009: cvt_bw
__global__ __launch_bounds__(256) void k_cvt_mlp1(
        const float* __restrict__ bw, us* __restrict__ bwh, float* __restrict__ mbw,
        const us* __restrict__ ssmh, const us* __restrict__ w1t,
        const float* __restrict__ b1, us* __restrict__ h1g) {
    __shared__ float red[128][4];
    const int bid = blockIdx.x;
    const int t = threadIdx.x;
    if (bid < 10) {
        const int ctile = bid % 5, rh = bid / 5;
        const int wv = t >> 6, lane = t & 63;
        const int m16 = lane & 15, q = lane >> 4;
        const int nc0 = ctile * 64;
        const int n = nc0 + wv * 16 + m16;
        f32x4 acc[4];
        #pragma unroll
        for (int i = 0; i < 4; ++i) acc[i] = (f32x4){0.f, 0.f, 0.f, 0.f};
        for (int ks = 0; ks < 10; ++ks) {
            const int k = ks * 32 + q * 8;
            bf16x8 bb = *(const bf16x8*)(w1t + (long)n * 320 + k);
            #pragma unroll
            for (int mt = 0; mt < 4; ++mt) {
                bf16x8 a = *(const bf16x8*)(ssmh + (long)(rh * 64 + mt * 16 + m16) * 320 + k);
                acc[mt] = __builtin_amdgcn_mfma_f32_16x16x32_bf16(a, bb, acc[mt], 0, 0, 0);
            }
        }
        const int col = n;
        const float bias = (col < SEM) ? b1[col] : 0.f;
        #pragma unroll
        for (int mt = 0; mt < 4; ++mt)
            #pragma unroll
            for (int r = 0; r < 4; ++r) {
                float v = acc[mt][r] + bias;
                v = v > 0.f ? v : 0.1f * v;
                const int gr = rh * 64 + mt * 16 + q * 4 + r;
                h1g[(long)gr * 320 + col] = (col < SEM) ? f2bf(v) : (us)0;
            }
        return;
    }
    const int fb = bid - 10;
    const int b = fb / 125, ch = fb % 125;
    int cg = t & 127, rs = t >> 7;
    long base = ((long)b * NBASE + (long)ch * 64) * FEAT + cg * 4;
    float s0 = 0.f, s1 = 0.f, s2 = 0.f, s3 = 0.f;
    for (int r0 = rs * 4; r0 < 64; r0 += 8) {
        float4 v[4];
        #pragma unroll
        for (int u = 0; u < 4; ++u)
            v[u] = *(const float4*)(bw + base + (long)(r0 + u) * FEAT);
        #pragma unroll
        for (int u = 0; u < 4; ++u) {
            us4 o; o.x = f2bf(v[u].x); o.y = f2bf(v[u].y); o.z = f2bf(v[u].z); o.w = f2bf(v[u].w);
            *(us4*)(bwh + base + (long)(r0 + u) * FEAT) = o;
            s0 += v[u].x; s1 += v[u].y; s2 += v[u].z; s3 += v[u].w;
        }
    }
    if (rs == 1) { red[cg][0] = s0; red[cg][1] = s1; red[cg][2] = s2; red[cg][3] = s3; }
    __syncthreads();
    if (rs == 0) {
        atomicAdd(&mbw[b * FEAT + cg * 4 + 0], s0 + red[cg][0]);
        atomicAdd(&mbw[b * FEAT + cg * 4 + 1], s1 + red[cg][1]);
        atomicAdd(&mbw[b * FEAT + cg * 4 + 2], s2 + red[cg][2]);
        atomicAdd(&mbw[b * FEAT + cg * 4 + 3], s3 + red[cg][3]);
    }
}

// =============== L3: h-GEMM fused with mlp2 (ssc) ===============
// blocks 0..9: mlp2 (ssc = h1 @ w2 + b2); blocks 10..513: hgemm
__global__ __launch_bounds__(256, 2) void k_hg_mlp2(const float* __restrict__ X,
        const us* __restrict__ W1T, const float* __restrict__ b1,
        us* __restrict__ H, float* __restrict__ mh,
        const us* __restrict__ h1g, const us* __restrict__ w2t,
        const float* __restrict__ b2, us* __restrict__ sscg) {
    __shared__ char smem[128 * 304 * 2];  // 77,824 B
    const int bid = blockIdx.x;
    const int t = threadIdx.x;
    const int wv = t >> 6, lane = t & 63;
    const int m16 = lane & 15, q = lane >> 4;
    if (bid < 10) {
        const int ctile = bid % 5, rh = bid / 5;
        const int n = ctile * 64 + wv * 16 + m16;
        f32x4 acc[4];
        #pragma unroll
        for (int i = 0; i < 4; ++i) acc[i] = (f32x4){0.f, 0.f, 0.f, 0.f};
        for (int ks = 0; ks < 10; ++ks) {
            const int k = ks * 32 + q * 8;
            bf16x8 bb = *(const bf16x8*)(w2t + (long)n * 320 + k);
            #pragma unroll
            for (int mt = 0; mt < 4; ++mt) {
                bf16x8 a = *(const bf16x8*)(h1g + (long)(rh * 64 + mt * 16 + m16) * 320 + k);
                acc[mt] = __builtin_amdgcn_mfma_f32_16x16x32_bf16(a, bb, acc[mt], 0, 0, 0);
            }
        }
        const int col = n;
        const float bias = (col < SEM) ? b2[col] : 0.f;
        #pragma unroll
        for (int mt = 0; mt < 4; ++mt)
            #pragma unroll
            for (int r = 0; r < 4; ++r) {
                const int gr = rh * 64 + mt * 16 + q * 4 + r;
                sscg[(long)gr * 320 + col] = (col < SEM) ? f2bf(acc[mt][r] + bias) : (us)0;
            }
        return;
    }
    us (*As)[72] = (us(*)[72])smem;                    // 128*72*2 = 18,432
    us (*Bs)[72] = (us(*)[72])(smem + 18432);          // 320*72*2 = 46,080
    us (*Cs)[HLD] = (us(*)[HLD])smem;                  // epilogue alias
    const int fb = bid - 10;
    const int b = fb / 63;
    const int bm = (fb % 63) * 128;
    const long rowbase = (long)b * NBASE;
    f32x4 acc[8][5];
    #pragma unroll
    for (int i = 0; i < 8; ++i)
        #pragma unroll
        for (int j = 0; j < 5; ++j) acc[i][j] = (f32x4){0.f, 0.f, 0.f, 0.f};
    for (int ks = 0; ks < 5; ++ks) {
        const int k0 = ks * 64;
        #pragma unroll
        for (int it = 0; it < 8; ++it) {
            int c = t + it * 256;
            int row = c >> 4, j = c & 15;
            int gk = k0 + j * 4;
            float4 v = make_float4(0.f, 0.f, 0.f, 0.f);
            if (gk < SEM && bm + row < NBASE)
                v = *(const float4*)(X + (rowbase + bm + row) * SEM + gk);
            us4 u; u.x = f2bf(v.x); u.y = f2bf(v.y); u.z = f2bf(v.z); u.w = f2bf(v.w);
            *(us4*)(&As[row][j * 4]) = u;
        }
        #pragma unroll
        for (int it = 0; it < 10; ++it) {
            int c = t + it * 256;
            int n = c >> 3, j = c & 7;
            int4 v = *(const int4*)(W1T + (long)n * 320 + k0 + j * 8);
            *(int4*)(&Bs[n][j * 8]) = v;
        }
        __syncthreads();
        #pragma unroll
        for (int kc = 0; kc < 64; kc += 32) {
            bf16x8 a[8], bb[5];
            #pragma unroll
            for (int rt = 0; rt < 8; ++rt)
                a[rt] = *(const bf16x8*)(&As[rt * 16 + m16][kc + q * 8]);
            #pragma unroll
            for (int ct = 0; ct < 5; ++ct)
                bb[ct] = *(const bf16x8*)(&Bs[(wv * 5 + ct) * 16 + m16][kc + q * 8]);
            #pragma unroll
            for (int rt = 0; rt < 8; ++rt)
                #pragma unroll
                for (int ct = 0; ct < 5; ++ct)
                    acc[rt][ct] = __builtin_amdgcn_mfma_f32_16x16x32_bf16(a[rt], bb[ct], acc[rt][ct], 0, 0, 0);
        }
        __syncthreads();
    }
    float csum[5] = {0.f, 0.f, 0.f, 0.f, 0.f};
    #pragma unroll
    for (int ct = 0; ct < 5; ++ct) {
        int col = (wv * 5 + ct) * 16 + m16;
        float bias = (col < SEM) ? b1[col] : 0.f;
        #pragma unroll
        for (int rt = 0; rt < 8; ++rt) {
            int rl = rt * 16 + q * 4;
            #pragma unroll
            for (int r = 0; r < 4; ++r) {
                float v = acc[rt][ct][r] + bias;
                v = v > 0.f ? v : 0.1f * v;
                if (col < SEM && bm + rl + r < NBASE) {
                    Cs[rl + r][col] = f2bf(v);
                    csum[ct] += v;
                }
            }
        }
    }
    if (t < 128) *(us4*)(&Cs[t][300]) = (us4){0, 0, 0, 0};
    #pragma unroll
    for (int ct = 0; ct < 5; ++ct) {
        float s = csum[ct];
        s += __shfl_xor(s, 16);
        s += __shfl_xor(s, 32);
        int col = (wv * 5 + ct) * 16 + m16;
        if (q == 0 && col < SEM) atomicAdd(&mh[b * SEM + col], s);
    }
    __syncthreads();
    for (int i = t; i < 128 * 76; i += 256) {
        int row = i / 76, j = i % 76;
        if (bm + row < NBASE)
            *(us4*)(H + (rowbase + bm + row) * HLD + j * 4) = *(const us4*)(&Cs[row][j * 4]);
    }
}

// =============== L4: gates fused with qtot ===============
// blocks 0..15: qtot = [sf|ssc] @ qwT^T; blocks 16..119: gates
__global__ __launch_bounds__(256) void k_gates_qtot(
        const float* __restrict__ mbw, const float* __restrict__ mh,
        const float* __restrict__ mw2, const float* __restrict__ mb2,
        const float* __restrict__ vfw, const float* __restrict__ vfb,
        const float* __restrict__ sfw, const float* __restrict__ sfb,
        float* __restrict__ gv, float* __restrict__ gs,
        const us* __restrict__ sfh, const us* __restrict__ sscg,
        const us* __restrict__ qwT, us* __restrict__ qtotg) {
    __shared__ float avgL[CAT];
    __shared__ float mhL[SEM];
    __shared__ float red[4][64];
    const int bid = blockIdx.x;
    const int t = threadIdx.x;
    if (bid < 16) {
        const int ctile = bid % 8, rh = bid / 8;
        const int wv = t >> 6, lane = t & 63;
        const int m16 = lane & 15, q = lane >> 4;
        const int n = ctile * 64 + wv * 16 + m16;
        f32x4 acc[4];
        #pragma unroll
        for (int i = 0; i < 4; ++i) acc[i] = (f32x4){0.f, 0.f, 0.f, 0.f};
        for (int ks = 0; ks < 26; ++ks) {
            const int k = ks * 32 + q * 8;
            bf16x8 bb = *(const bf16x8*)(qwT + (long)n * 832 + k);
            #pragma unroll
            for (int mt = 0; mt < 4; ++mt) {
                const int gr = rh * 64 + mt * 16 + m16;
                bf16x8 a = (k < FEAT)
                    ? *(const bf16x8*)(sfh + (long)gr * 512 + k)
                    : *(const bf16x8*)(sscg + (long)gr * 320 + (k - FEAT));
                acc[mt] = __builtin_amdgcn_mfma_f32_16x16x32_bf16(a, bb, acc[mt], 0, 0, 0);
            }
        }
        #pragma unroll
        for (int mt = 0; mt < 4; ++mt)
            #pragma unroll
            for (int r = 0; r < 4; ++r) {
                const int gr = rh * 64 + mt * 16 + q * 4 + r;
                qtotg[(long)gr * 512 + n] = f2bf(acc[mt][r]);
            }
        return;
    }
    const int tile = (bid - 16) % 13, b = (bid - 16) / 13;
    const float invN = 1.0f / NBASE;
    for (int i = t; i < SEM; i += 256) mhL[i] = mh[b * SEM + i] * invN;
    for (int i = t; i < FEAT; i += 256) avgL[i] = mbw[b * FEAT + i] * invN;
    __syncthreads();
    for (int s = t; s < SEM; s += 256) {
        float a = mb2[s];
        for (int c = 0; c < SEM; ++c) a += mhL[c] * mw2[(long)c * SEM + s];
        avgL[FEAT + s] = a;
    }
    __syncthreads();
    int l = t & 63, kq = t >> 6;
    float a = 0.f;
    if (tile < 8) {
        int f = tile * 64 + l;
        for (int c = kq * 203; c < kq * 203 + 203; ++c) a += avgL[c] * vfw[(long)c * FEAT + f];
        red[kq][l] = a;
        __syncthreads();
        if (kq == 0) {
            float s = red[0][l] + red[1][l] + red[2][l] + red[3][l] + vfb[f];
            gv[b * FEAT + f] = 1.f + 1.f / (1.f + expf(-s));
        }
    } else {
        int fs = (tile - 8) * 64 + l;
        if (fs < SEM)
            for (int c = kq * 203; c < kq * 203 + 203; ++c) a += avgL[c] * sfw[(long)c * SEM + fs];
        red[kq][l] = a;
        __syncthreads();
        if (kq == 0 && fs < SEM) {
            float s = red[0][l] + red[1][l] + red[2][l] + red[3][l] + sfb[fs];
            gs[b * SEM + fs] = 1.f + 1.f / (1.f + expf(-s));
        }
    }
}

// =============== L5: projections + gate apply + pqt assembly + cconst partials ===============
// 26 blocks: nslot 0..7 -> qvis 64-col tile into pqt[:,0:512); 8..12 -> psem tile
__global__ __launch_bounds__(256) void k_projgate(
        const us* __restrict__ qtotg, const us* __restrict__ wksT,
        const us* __restrict__ wkssT, const float* __restrict__ gv,
        const float* __restrict__ gs, const float* __restrict__ b2,
        us* __restrict__ pqt, us* __restrict__ psemG, float* __restrict__ cconst) {
    const int bid = blockIdx.x;
    const int nslot = bid % 13, rh = bid / 13;
    const int t = threadIdx.x;
    const int wv = t >> 6, lane = t & 63;
    const int m16 = lane & 15, q = lane >> 4;
    const bool isv = (nslot < 8);
    const int nc0 = isv ? nslot * 64 : (nslot - 8) * 64;
    const us* BT = isv ? wksT : wkssT;
    const int n = nc0 + wv * 16 + m16;
    f32x4 acc[4];
    #pragma unroll
    for (int i = 0; i < 4; ++i) acc[i] = (f32x4){0.f, 0.f, 0.f, 0.f};
    for (int ks = 0; ks < 16; ++ks) {
        const int k = ks * 32 + q * 8;
        bf16x8 bb = *(const bf16x8*)(BT + (long)n * 512 + k);
        #pragma unroll
        for (int mt = 0; mt < 4; ++mt) {
            bf16x8 a = *(const bf16x8*)(qtotg + (long)(rh * 64 + mt * 16 + m16) * 512 + k);
            acc[mt] = __builtin_amdgcn_mfma_f32_16x16x32_bf16(a, bb, acc[mt], 0, 0, 0);
        }
    }
    const int col = n;
    if (isv) {
        #pragma unroll
        for (int mt = 0; mt < 4; ++mt)
            #pragma unroll
            for (int r = 0; r < 4; ++r) {
                const int gr = rh * 64 + mt * 16 + q * 4 + r;
                const int b = gr >> 4;
                pqt[(long)gr * 840 + col] = f2bf(acc[mt][r] * gv[b * FEAT + col]);
            }
    } else {
        const float b2c = (col < SEM) ? b2[col] : 0.f;
        #pragma unroll
        for (int mt = 0; mt < 4; ++mt)
            #pragma unroll
            for (int r = 0; r < 4; ++r) {
                const int gr = rh * 64 + mt * 16 + q * 4 + r;
                const int b = gr >> 4;
                float p = (col < SEM) ? acc[mt][r] * gs[b * SEM + col] : 0.f;
                psemG[(long)gr * 320 + col] = (col < SEM) ? f2bf(p) : (us)0;
                float ps = p * b2c;  // cconst = dot(psem_gated, b2)
                ps += __shfl_xor(ps, 1); ps += __shfl_xor(ps, 2);
                ps += __shfl_xor(ps, 4); ps += __shfl_xor(ps, 8);
                if (m16 == 0) atomicAdd(&cconst[b * NWAY + (gr & 15)], ps);
            }
    }
}

// =============== L6: pqt[:,512:812) = psemG @ w2n^T ===============
__global__ __launch_bounds__(256) void k_sem2(const us* __restrict__ psemG,
        const us* __restrict__ w2n, us* __restrict__ pqt) {
    const int bid = blockIdx.x;
    const int ctile = bid % 5, rh = bid / 5;
    const int t = threadIdx.x;
    const int wv = t >> 6, lane = t & 63;
    const int m16 = lane & 15, q = lane >> 4;
    const int n = ctile * 64 + wv * 16 + m16;
    f32x4 acc[4];
    #pragma unroll
    for (int i = 0; i < 4; ++i) acc[i] = (f32x4){0.f, 0.f, 0.f, 0.f};
    for (int ks = 0; ks < 10; ++ks) {
        const int k = ks * 32 + q * 8;
        bf16x8 bb = *(const bf16x8*)(w2n + (long)n * 320 + k);
        #pragma unroll
        for (int mt = 0; mt < 4; ++mt) {
            bf16x8 a = *(const bf16x8*)(psemG + (long)(rh * 64 + mt * 16 + m16) * 320 + k);
            acc[mt] = __builtin_amdgcn_mfma_f32_16x16x32_bf16(a, bb, acc[mt], 0, 0, 0);
        }
    }
    const int col = n;
    if (col < SEM) {
        #pragma unroll
        for (int mt = 0; mt < 4; ++mt)
            #pragma unroll
            for (int r = 0; r < 4; ++r) {
                const int gr = rh * 64 + mt * 16 + q * 4 + r;
                pqt[(long)gr * 840 + 512 + col] = f2bf(acc[mt][r]);
            }
    }
}

// =============== scores + fused per-block softmax partials (KB=64 stages) ===============
__global__ __launch_bounds__(256) void k_scores_mfma(const us* __restrict__ bwh,
        const us* __restrict__ h, const us* __restrict__ pqt,
        const float* __restrict__ cconst, float* __restrict__ scores,
        float* __restrict__ pmax, float* __restrict__ psum) {
    __shared__ us As[128][72];       // [m][64k] +8 pad
    __shared__ us Bs[NWAY][840];
    __shared__ float sred[4][16];
    const int b = blockIdx.y;
    const int bm = blockIdx.x * 128;
    const int t = threadIdx.x;
    const int wv = t >> 6, lane = t & 63;
    const int m16 = lane & 15, q = lane >> 4;
    for (int c = t; c < NWAY * 105; c += 256) {
        int n = c / 105, j = c % 105;
        *(int4*)(&Bs[n][j * 8]) = *(const int4*)(pqt + ((long)b * NWAY + n) * 840 + j * 8);
    }
    f32x4 acc[2];
    acc[0] = (f32x4){0, 0, 0, 0};
    acc[1] = (f32x4){0, 0, 0, 0};
    for (int ks = 0; ks < 13; ++ks) {
        int k0 = ks * 64;
        #pragma unroll
        for (int it = 0; it < 4; ++it) {
            int c = t + it * 256;
            int row = c >> 3, j = c & 7;
            int gm = bm + row, gk = k0 + j * 8;
            us8 u = (us8){0, 0, 0, 0, 0, 0, 0, 0};
            if (gk < FEAT)      u = *(const us8*)(bwh + ((long)b * NBASE + gm) * FEAT + gk);
            else if (gk < CAT)  u = *(const us8*)(h + ((long)b * NBASE + gm) * HLD + (gk - FEAT));
            *(us8*)(&As[row][j * 8]) = u;
        }
        __syncthreads();
        #pragma unroll
        for (int kc = 0; kc < 64; kc += 32) {
            bf16x8 bb = *(const bf16x8*)(&Bs[m16][k0 + kc + q * 8]);
            #pragma unroll
            for (int rt = 0; rt < 2; ++rt) {
                bf16x8 a = *(const bf16x8*)(&As[wv * 32 + rt * 16 + m16][kc + q * 8]);
                acc[rt] = __builtin_amdgcn_mfma_f32_16x16x32_bf16(a, bb, acc[rt], 0, 0, 0);
            }
        }
        __syncthreads();
    }
    const float invT = 0.04419417382415922f;  // 1/sqrt(512)
    float cadd = cconst[b * NWAY + m16];
    float vals[8];
    #pragma unroll
    for (int rt = 0; rt < 2; ++rt) {
        int nrow = bm + wv * 32 + rt * 16 + q * 4;
        #pragma unroll
        for (int r = 0; r < 4; ++r) {
            float v = (nrow + r < NBASE) ? (acc[rt][r] + cadd) * invT : -1e30f;
            vals[rt * 4 + r] = v;
        }
        if (nrow + 3 < NBASE) {
            float4 st = make_float4(vals[rt * 4], vals[rt * 4 + 1], vals[rt * 4 + 2], vals[rt * 4 + 3]);
            *(float4*)(scores + ((long)b * NWAY + m16) * NBASE + nrow) = st;
        } else {
            for (int r = 0; r < 4; ++r)
                if (nrow + r < NBASE)
                    scores[((long)b * NWAY + m16) * NBASE + nrow + r] = vals[rt * 4 + r];
        }
    }
    float lm = vals[0];
    #pragma unroll
    for (int i = 1; i < 8; ++i) lm = fmaxf(lm, vals[i]);
    lm = fmaxf(lm, __shfl_xor(lm, 16));
    lm = fmaxf(lm, __shfl_xor(lm, 32));
    if (q == 0) sred[wv][m16] = lm;
    __syncthreads();
    float bmax = fmaxf(fmaxf(sred[0][m16], sred[1][m16]), fmaxf(sred[2][m16], sred[3][m16]));
    __syncthreads();
    float ls = 0.f;
    #pragma unroll
    for (int i = 0; i < 8; ++i) ls += __expf(vals[i] - bmax);
    ls += __shfl_xor(ls, 16);
    ls += __shfl_xor(ls, 32);
    if (q == 0) sred[wv][m16] = ls;
    __syncthreads();
    if (wv == 0 && lane < 16) {
        float tot = sred[0][m16] + sred[1][m16] + sred[2][m16] + sred[3][m16];
        pmax[((long)b * NWAY + m16) * 63 + blockIdx.x] = bmax;
        psum[((long)b * NWAY + m16) * 63 + blockIdx.x] = tot;
    }
}

// =============== combine partials -> row max & 1/sum (+ zero ov) ===============
__global__ void k_combine(const float* __restrict__ pmax, const float* __restrict__ psum,
                          float* __restrict__ rmax, float* __restrict__ rinv,
                          float* __restrict__ ov) {
    int b = blockIdx.x, t = threadIdx.x;
    float4 z = make_float4(0.f, 0.f, 0.f, 0.f);
    for (int i = t; i < 2048; i += 256)
        *(float4*)(ov + ((long)b * 2048 + i) * 4) = z;
    int w = t >> 4, l = t & 15;
    long base = ((long)b * NWAY + w) * 63;
    float m = -1e30f;
    for (int i = l; i < 63; i += 16) m = fmaxf(m, pmax[base + i]);
    m = fmaxf(m, __shfl_xor(m, 1)); m = fmaxf(m, __shfl_xor(m, 2));
    m = fmaxf(m, __shfl_xor(m, 4)); m = fmaxf(m, __shfl_xor(m, 8));
    float s = 0.f;
    for (int i = l; i < 63; i += 16) s += psum[base + i] * __expf(pmax[base + i] - m);
    s += __shfl_xor(s, 1); s += __shfl_xor(s, 2);
    s += __shfl_xor(s, 4); s += __shfl_xor(s, 8);
    if (l == 0) { rmax[b * NWAY + w] = m; rinv[b * NWAY + w] = 1.0f / s; }
}

// =============== ov = softmax(scores) @ bwh, exp fused, unroll-8 ===============
__global__ void k_ov(const float* __restrict__ scores, const float* __restrict__ rmax,
                     const float* __restrict__ rinv, const us* __restrict__ bwh,
                     float* __restrict__ ov) {
    int b = blockIdx.x, ch = blockIdx.y;  // 50 chunks of 160 rows
    int t = threadIdx.x;
    __shared__ float pr[NWAY][160];
    for (int i = t; i < NWAY * 160; i += 256) {
        int w = i / 160, j = i % 160;
        float sc = scores[((long)b * NWAY + w) * NBASE + (long)ch * 160 + j];
        pr[w][j] = __expf(sc - rmax[b * NWAY + w]) * rinv[b * NWAY + w];
    }
    __syncthreads();
    float a0[NWAY], a1[NWAY];
    #pragma unroll
    for (int w = 0; w < NWAY; ++w) { a0[w] = 0.f; a1[w] = 0.f; }
    const us* bp = bwh + ((long)b * NBASE + (long)ch * 160) * FEAT + 2 * t;
    for (int j0 = 0; j0 < 160; j0 += 8) {
        us2 u[8];
        #pragma unroll
        for (int uu = 0; uu < 8; ++uu)
            u[uu] = *(const us2*)(bp + (long)(j0 + uu) * FEAT);
        #pragma unroll
        for (int uu = 0; uu < 8; ++uu) {
            float v0 = bf2f(u[uu].x), v1 = bf2f(u[uu].y);
            #pragma unroll
            for (int w = 0; w < NWAY; ++w) {
                a0[w] += pr[w][j0 + uu] * v0;
                a1[w] += pr[w][j0 + uu] * v1;
            }
        }
    }
    for (int w = 0; w < NWAY; ++w) {
        atomicAdd(&ov[((long)b * NWAY + w) * FEAT + 2 * t], a0[w]);
        atomicAdd(&ov[((long)b * NWAY + w) * FEAT + 2 * t + 1], a1[w]);
    }
}

// =============== k_out1: tmp = bf16(ov) @ wvsT, grid 16 = (8 ctiles x 2 rhalves) ===============
__global__ __launch_bounds__(256) void k_out1(const float* __restrict__ ov,
        const us* __restrict__ wvsT, us* __restrict__ tmp) {
    const int bid = blockIdx.x;
    const int ctile = bid & 7, rh = bid >> 3;
    const int t = threadIdx.x;
    const int wv = t >> 6, lane = t & 63;
    const int m16 = lane & 15, q = lane >> 4;
    const int n = ctile * 64 + wv * 16 + m16;
    f32x4 acc[4];
    #pragma unroll
    for (int i = 0; i < 4; ++i) acc[i] = (f32x4){0.f, 0.f, 0.f, 0.f};
    #pragma unroll 4
    for (int ks = 0; ks < 16; ++ks) {
        const int k = ks * 32 + q * 8;
        bf16x8 bb = *(const bf16x8*)(wvsT + (long)n * 512 + k);
        #pragma unroll
        for (int mt = 0; mt < 4; ++mt) {
            const float* ap = ov + (long)(rh * 64 + mt * 16 + m16) * 512 + k;
            float4 x = *(const float4*)ap, y = *(const float4*)(ap + 4);
            bf16x8 a;
            a[0] = (short)f2bf(x.x); a[1] = (short)f2bf(x.y);
            a[2] = (short)f2bf(x.z); a[3] = (short)f2bf(x.w);
            a[4] = (short)f2bf(y.x); a[5] = (short)f2bf(y.y);
            a[6] = (short)f2bf(y.z); a[7] = (short)f2bf(y.w);
            acc[mt] = __builtin_amdgcn_mfma_f32_16x16x32_bf16(a, bb, acc[mt], 0, 0, 0);
        }
    }
    #pragma unroll
    for (int mt = 0; mt < 4; ++mt)
        #pragma unroll
        for (int r = 0; r < 4; ++r) {
            const int gr = rh * 64 + mt * 16 + q * 4 + r;
            tmp[(long)gr * 512 + n] = f2bf(acc[mt][r]);
        }
}

// =============== k_out2: out = tmp @ fcwT + sf, grid 16 ===============
__global__ __launch_bounds__(256) void k_out2(const us* __restrict__ tmp,
        const us* __restrict__ fcwT, const float* __restrict__ sf,
        float* __restrict__ out) {
    const int bid = blockIdx.x;
    const int ctile = bid & 7, rh = bid >> 3;
    const int t = threadIdx.x;
    const int wv = t >> 6, lane = t & 63;
    const int m16 = lane & 15, q = lane >> 4;
    const int n = ctile * 64 + wv * 16 + m16;
    f32x4 acc[4];
    #pragma unroll
    for (int i = 0; i < 4; ++i) acc[i] = (f32x4){0.f, 0.f, 0.f, 0.f};
    #pragma unroll 4
    for (int ks = 0; ks < 16; ++ks) {
        const int k = ks * 32 + q * 8;
        bf16x8 bb = *(const bf16x8*)(fcwT + (long)n * 512 + k);
        #pragma unroll
        for (int mt = 0; mt < 4; ++mt) {
            bf16x8 a = *(const bf16x8*)(tmp + (long)(rh * 64 + mt * 16 + m16) * 512 + k);
            acc[mt] = __builtin_amdgcn_mfma_f32_16x16x32_bf16(a, bb, acc[mt], 0, 0, 0);
        }
    }
    #pragma unroll
    for (int mt = 0; mt < 4; ++mt)
        #pragma unroll
        for (int r = 0; r < 4; ++r) {
            const long gr = rh * 64 + mt * 16 + q * 4 + r;
            out[gr * FEAT + n] = acc[mt][r] + sf[gr * FEAT + n];
        }
}

extern "C" void kernel_launch(void* const* d_in, const int* in_sizes, int n_in,
                              void* d_out, int out_size, void* d_ws, size_t ws_size,
                              hipStream_t stream) {
    (void)in_sizes; (void)n_in; (void)out_size; (void)ws_size;
    const float* sf   = (const float*)d_in[0];
    const float* bw   = (const float*)d_in[1];
    const float* ssm  = (const float*)d_in[2];
    const float* bsm  = (const float*)d_in[3];
    const float* mw1  = (const float*)d_in[4];
    const float* mb1  = (const float*)d_in[5];
    const float* mw2  = (const float*)d_in[6];
    const float* mb2  = (const float*)d_in[7];
    const float* vfw  = (const float*)d_in[8];
    const float* vfb  = (const float*)d_in[9];
    const float* sfw  = (const float*)d_in[10];
    const float* sfb  = (const float*)d_in[11];
    const float* wqs  = (const float*)d_in[12];
    const float* wks  = (const float*)d_in[13];
    const float* wvs  = (const float*)d_in[14];
    const float* wqss = (const float*)d_in[15];
    const float* wkss = (const float*)d_in[16];
    const float* fcw  = (const float*)d_in[17];

    float* out = (float*)d_out;
    float* scores = out + NB * NWAY * FEAT;  // d_out = [out | attn_score]

    char* wsb = (char*)d_ws;
    us* bwh    = (us*)(wsb + O_BWH);
    us* h      = (us*)(wsb + O_H);
    us* w1t    = (us*)(wsb + O_W1T);
    us* w2t    = (us*)(wsb + O_W2T);
    us* qwT    = (us*)(wsb + O_QWT);
    us* wvsT   = (us*)(wsb + O_WVST);
    us* fcwT   = (us*)(wsb + O_FCWT);
    us* pqt    = (us*)(wsb + O_PQT);
    us* wksT   = (us*)(wsb + O_WKST);
    us* wkssT  = (us*)(wsb + O_WKSST);
    us* w2n    = (us*)(wsb + O_W2N);
    us* sfh    = (us*)(wsb + O_SFH);
    us* ssmh   = (us*)(wsb + O_SSMH);
    us* h1g    = (us*)(wsb + O_H1G);
    us* sscg   = (us*)(wsb + O_SSCG);
    us* qtotg  = (us*)(wsb + O_QTG);
    us* psemG  = (us*)(wsb + O_PSG);
    float* pmax   = (float*)(wsb + O_PMAX);
    float* psum   = (float*)(wsb + O_PSUM);
    float* rmax   = (float*)(wsb + O_RMAX);
    float* rinv   = (float*)(wsb + O_RINV);
    float* mbw    = (float*)(wsb + O_MBW);
    float* mh     = (float*)(wsb + O_MH);
    float* gv     = (float*)(wsb + O_GV);
    float* gs     = (float*)(wsb + O_GS);
    float* ov     = (float*)(wsb + O_OV);
    float* cconst = (float*)(wsb + O_CC);

    k_prep<<<dim3(1664, 11), 256, 0, stream>>>(mw1, mw2, wqs, wqss, wvs, fcw, wks, wkss,
                                               sf, ssm,
                                               w1t, w2t, qwT, wvsT, fcwT, wksT, wkssT, w2n,
                                               sfh, ssmh, mbw, cconst, pqt);
    k_cvt_mlp1<<<1010, 256, 0, stream>>>(bw, bwh, mbw, ssmh, w1t, mb1, h1g);
    k_hg_mlp2<<<514, 256, 0, stream>>>(bsm, w1t, mb1, h, mh, h1g, w2t, mb2, sscg);
    k_gates_qtot<<<120, 256, 0, stream>>>(mbw, mh, mw2, mb2, vfw, vfb, sfw, sfb, gv, gs,
                                          sfh, sscg, qwT, qtotg);
    k_projgate<<<26, 256, 0, stream>>>(qtotg, wksT, wkssT, gv, gs, mb2, pqt, psemG, cconst);
    k_sem2<<<10, 256, 0, stream>>>(psemG, w2n, pqt);
    k_scores_mfma<<<dim3(63, NB), 256, 0, stream>>>(bwh, h, pqt, cconst, scores, pmax, psum);
    k_combine<<<NB, 256, 0, stream>>>(pmax, psum, rmax, rinv, ov);
    k_ov<<<dim3(NB, 50), 256, 0, stream>>>(scores, rmax, rinv, bwh, ov);
    k_out1<<<16, 256, 0, stream>>>(ov, wvsT, qtotg);
    k_out2<<<16, 256, 0, stream>>>(qtotg, fcwT, sf, out);
}

// Round 7
// 496.231 us; speedup vs baseline: 1.3767x; 1.0522x over previous
//
#include <hip/hip_runtime.h>

#define NB 8
#define NWAY 16
#define NBASE 8000
#define FEAT 512
#define SEM 300
#define CAT (FEAT + SEM)  // 812
#define HLD 304           // padded h leading dim (16B-aligned rows)

typedef __attribute__((ext_vector_type(8))) short bf16x8;
typedef __attribute__((ext_vector_type(4))) float f32x4;
typedef __attribute__((ext_vector_type(8))) unsigned short us8;
typedef __attribute__((ext_vector_type(4))) unsigned short us4;
typedef __attribute__((ext_vector_type(2))) unsigned short us2;
typedef unsigned short us;

__device__ __forceinline__ us f2bf(float x) {
    union { float f; unsigned int u; } v; v.f = x;
    unsigned int r = v.u + 0x7FFFu + ((v.u >> 16) & 1u);
    return (us)(r >> 16);
}
__device__ __forceinline__ float bf2f(us u) {
    union { unsigned int u; float f; } v; v.u = ((unsigned int)u) << 16;
    return v.f;
}

// =============== workspace byte offsets (all 16B aligned) ===============
constexpr long O_BWH   = 0L;            // 8*8000*512*2 = 65,536,000
constexpr long O_H     = 65536000L;     // 8*8000*304*2 = 38,912,000
constexpr long O_W1T   = 104448000L;    // 320*320*2 = 204,800
constexpr long O_W2T   = 104652800L;    // 204,800
constexpr long O_QWT   = 104857600L;    // 512*832*2 = 851,968
constexpr long O_WVST  = 106496000L;    // 512*512*2 = 524,288
constexpr long O_FCWT  = 107020288L;    // 524,288
constexpr long O_PQT   = 107544576L;    // 8*16*840*2 = 215,040
constexpr long O_PMAX  = 107759616L;    // 8*16*63*4 = 32,256
constexpr long O_PSUM  = 107791872L;    // 32,256
constexpr long O_RMAX  = 107824128L;    // 512 (unused)
constexpr long O_RINV  = 107824640L;    // 512 (unused)
constexpr long O_F     = 107825152L;
constexpr long O_MBW   = O_F;            // 16,384 (mbw) + 9,600 (mh) contiguous
constexpr long O_MH    = O_F + 16384;
constexpr long O_GV    = O_F + 25984;    // 16,384
constexpr long O_GS    = O_F + 42368;    // 9,600
// time-multiplexed zone A (77,952..233,600):
//   ssmh bf16 128x320 (prep->L2), then qtotg bf16 128x512 (L4->L5), then tmp bf16 (out1->out2)
constexpr long O_SSMH  = O_F + 77952;    // 81,920
constexpr long O_QTG   = O_F + 77952;    // 131,072 (aliases ssmh, disjoint in time)
constexpr long O_OV    = O_F + 233600;   // 128*512*4 = 262,144 (ov accumulator)
// time-multiplexed zone B (540,800..802,944):
//   sfh bf16 128x512 (prep->L4) @ +0, then psemG bf16 128x320 (L5->L6) @ +0
//   h1g bf16 128x320 (L2->L3) @ +131,072
constexpr long O_SFH   = O_F + 540800;   // 131,072
constexpr long O_PSG   = O_F + 540800;   // 81,920 (aliases sfh, disjoint in time)
constexpr long O_H1G   = O_F + 671872;   // 81,920
constexpr long O_CC    = O_F + 802944;   // 512
constexpr long O_WKST  = O_F + 803456;   // 512*512*2 = 524,288 (wks bf16)
constexpr long O_WKSST = O_F + 1327744;  // 320*512*2 = 327,680 (wkss bf16, row-pad)
constexpr long O_W2N   = O_F + 1655424;  // 320*320*2 = 204,800 (mw2 bf16 natural)
constexpr long O_SSCG  = O_F + 1860224;  // 128*320*2 = 81,920 (ssc bf16, L3->L4)

// =============== k_tr: LDS-tiled fp32->bf16 transposes (coalesced both sides) ===============
// blockIdx.y: 0=w1t 1=w2t 2=qwT 3=wvsT 4=fcwT. 64x64 tiles.
__global__ __launch_bounds__(256) void k_tr(
        const float* __restrict__ w1, const float* __restrict__ w2,
        const float* __restrict__ wqs, const float* __restrict__ wqss,
        const float* __restrict__ wvs, const float* __restrict__ fcw,
        us* __restrict__ w1t, us* __restrict__ w2t, us* __restrict__ qwT,
        us* __restrict__ wvsT, us* __restrict__ fcwT) {
    __shared__ us tile[64][66];
    const int cs = blockIdx.y;
    const int t = threadIdx.x;
    int tilesK, N, K, LD, srcN, srcK;
    const float* S0;
    us* D;
    switch (cs) {
    case 0:  tilesK = 5;  N = 320; K = 320; LD = 320; S0 = w1;  D = w1t;  srcN = 300; srcK = 300; break;
    case 1:  tilesK = 5;  N = 320; K = 320; LD = 320; S0 = w2;  D = w2t;  srcN = 300; srcK = 300; break;
    case 2:  tilesK = 13; N = 512; K = 832; LD = 832; S0 = wqs; D = qwT;  srcN = 512; srcK = 812; break;
    case 3:  tilesK = 8;  N = 512; K = 512; LD = 512; S0 = wvs; D = wvsT; srcN = 512; srcK = 512; break;
    default: tilesK = 8;  N = 512; K = 512; LD = 512; S0 = fcw; D = fcwT; srcN = 512; srcK = 512; break;
    }
    const int ntiles = tilesK * (N >> 6);
    if ((int)blockIdx.x >= ntiles) return;
    const int tk = (blockIdx.x % tilesK) * 64;
    const int tn = (blockIdx.x / tilesK) * 64;
    #pragma unroll
    for (int i = 0; i < 16; ++i) {      // load src[k][n], rows coalesced
        int idx = t + i * 256;
        int kk = idx >> 6, nn = idx & 63;
        int k = tk + kk, n = tn + nn;
        float v = 0.f;
        if (n < srcN && k < srcK) {
            if (cs == 2) v = (k < FEAT) ? wqs[(long)k * 512 + n] : wqss[(long)(k - FEAT) * 512 + n];
            else v = S0[(long)k * srcN + n];
        }
        tile[kk][nn] = f2bf(v);
    }
    __syncthreads();
    #pragma unroll
    for (int i = 0; i < 8; ++i) {       // store dest[n][k], us2 coalesced
        int idx = t + i * 256;          // over 64n x 32 kk-pairs
        int nn = idx >> 5, kp = (idx & 31) * 2;
        int n = tn + nn, k = tk + kp;
        if (n < N && k < K) {
            us2 o; o.x = tile[kp][nn]; o.y = tile[kp + 1][nn];
            *(us2*)(D + (long)n * LD + k) = o;
        }
    }
}

// =============== k_prep: natural-layout bf16 copies + zero scratch ===============
__global__ void k_prep(const float* __restrict__ wks, const float* __restrict__ wkss,
                       const float* __restrict__ w2, const float* __restrict__ sf,
                       const float* __restrict__ ssm,
                       us* __restrict__ wksT, us* __restrict__ wkssT, us* __restrict__ w2n,
                       us* __restrict__ sfh, us* __restrict__ ssmh,
                       float* __restrict__ mz, float* __restrict__ cz,
                       us* __restrict__ pqt, float* __restrict__ ovz) {
    long e = (long)blockIdx.x * 256 + threadIdx.x;
    switch (blockIdx.y) {
    case 0:
        if (e < NB * FEAT + NB * SEM) mz[e] = 0.f;                   // mbw + mh
        if (e < NB * NWAY) cz[e] = 0.f;                              // cconst
        if (e < 128 * 28) pqt[(e / 28) * 840 + 812 + (e % 28)] = 0;  // pqt pad cols
        if (e < NB * NWAY * FEAT) ovz[e] = 0.f;                      // ov accumulator
        break;
    case 1: if (e < 512 * 512) wksT[e] = f2bf(wks[e]); break;
    case 2: if (e < 320 * 512) { int n = e / 512, k = e % 512;
            wkssT[e] = (n < SEM) ? f2bf(wkss[(long)n * FEAT + k]) : (us)0; } break;
    case 3: if (e < 320 * 320) { int n = e / 320, k = e % 320;
            w2n[e] = (n < SEM && k < SEM) ? f2bf(w2[(long)n * SEM + k]) : (us)0; } break;
    case 4: if (e < 128 * 512) sfh[e] = f2bf(sf[e]); break;
    case 5: if (e < 128 * 320) { int n = e / 320, k = e % 320;
            ssmh[e] = (k < SEM) ? f2bf(ssm[(long)n * SEM + k]) : (us)0; } break;
    }
}

// =============== L2: bw->bf16 + colsums, fused with mlp1 (h1) ===============
__global__ __launch_bounds__(256) void k_cvt_mlp1(
        const float* __restrict__ bw, us* __restrict__ bwh, float* __restrict__ mbw,
        const us* __restrict__ ssmh, const us* __restrict__ w1t,
        const float* __restrict__ b1, us* __restrict__ h1g) {
    __shared__ float red[128][4];
    const int bid = blockIdx.x;
    const int t = threadIdx.x;
    if (bid < 10) {
        const int ctile = bid % 5, rh = bid / 5;
        const int wv = t >> 6, lane = t & 63;
        const int m16 = lane & 15, q = lane >> 4;
        const int n = ctile * 64 + wv * 16 + m16;
        f32x4 acc[4];
        #pragma unroll
        for (int i = 0; i < 4; ++i) acc[i] = (f32x4){0.f, 0.f, 0.f, 0.f};
        for (int ks = 0; ks < 10; ++ks) {
            const int k = ks * 32 + q * 8;
            bf16x8 bb = *(const bf16x8*)(w1t + (long)n * 320 + k);
            #pragma unroll
            for (int mt = 0; mt < 4; ++mt) {
                bf16x8 a = *(const bf16x8*)(ssmh + (long)(rh * 64 + mt * 16 + m16) * 320 + k);
                acc[mt] = __builtin_amdgcn_mfma_f32_16x16x32_bf16(a, bb, acc[mt], 0, 0, 0);
            }
        }
        const int col = n;
        const float bias = (col < SEM) ? b1[col] : 0.f;
        #pragma unroll
        for (int mt = 0; mt < 4; ++mt)
            #pragma unroll
            for (int r = 0; r < 4; ++r) {
                float v = acc[mt][r] + bias;
                v = v > 0.f ? v : 0.1f * v;
                const int gr = rh * 64 + mt * 16 + q * 4 + r;
                h1g[(long)gr * 320 + col] = (col < SEM) ? f2bf(v) : (us)0;
            }
        return;
    }
    const int fb = bid - 10;
    const int b = fb / 125, ch = fb % 125;
    int cg = t & 127, rs = t >> 7;
    long base = ((long)b * NBASE + (long)ch * 64) * FEAT + cg * 4;
    float s0 = 0.f, s1 = 0.f, s2 = 0.f, s3 = 0.f;
    for (int r0 = rs * 4; r0 < 64; r0 += 8) {
        float4 v[4];
        #pragma unroll
        for (int u = 0; u < 4; ++u)
            v[u] = *(const float4*)(bw + base + (long)(r0 + u) * FEAT);
        #pragma unroll
        for (int u = 0; u < 4; ++u) {
            us4 o; o.x = f2bf(v[u].x); o.y = f2bf(v[u].y); o.z = f2bf(v[u].z); o.w = f2bf(v[u].w);
            *(us4*)(bwh + base + (long)(r0 + u) * FEAT) = o;
            s0 += v[u].x; s1 += v[u].y; s2 += v[u].z; s3 += v[u].w;
        }
    }
    if (rs == 1) { red[cg][0] = s0; red[cg][1] = s1; red[cg][2] = s2; red[cg][3] = s3; }
    __syncthreads();
    if (rs == 0) {
        atomicAdd(&mbw[b * FEAT + cg * 4 + 0], s0 + red[cg][0]);
        atomicAdd(&mbw[b * FEAT + cg * 4 + 1], s1 + red[cg][1]);
        atomicAdd(&mbw[b * FEAT + cg * 4 + 2], s2 + red[cg][2]);
        atomicAdd(&mbw[b * FEAT + cg * 4 + 3], s3 + red[cg][3]);
    }
}

// =============== L3: h-GEMM fused with mlp2 (ssc) ===============
__global__ __launch_bounds__(256, 2) void k_hg_mlp2(const float* __restrict__ X,
        const us* __restrict__ W1T, const float* __restrict__ b1,
        us* __restrict__ H, float* __restrict__ mh,
        const us* __restrict__ h1g, const us* __restrict__ w2t,
        const float* __restrict__ b2, us* __restrict__ sscg) {
    __shared__ char smem[128 * 304 * 2];  // 77,824 B
    const int bid = blockIdx.x;
    const int t = threadIdx.x;
    const int wv = t >> 6, lane = t & 63;
    const int m16 = lane & 15, q = lane >> 4;
    if (bid < 10) {
        const int ctile = bid % 5, rh = bid / 5;
        const int n = ctile * 64 + wv * 16 + m16;
        f32x4 acc[4];
        #pragma unroll
        for (int i = 0; i < 4; ++i) acc[i] = (f32x4){0.f, 0.f, 0.f, 0.f};
        for (int ks = 0; ks < 10; ++ks) {
            const int k = ks * 32 + q * 8;
            bf16x8 bb = *(const bf16x8*)(w2t + (long)n * 320 + k);
            #pragma unroll
            for (int mt = 0; mt < 4; ++mt) {
                bf16x8 a = *(const bf16x8*)(h1g + (long)(rh * 64 + mt * 16 + m16) * 320 + k);
                acc[mt] = __builtin_amdgcn_mfma_f32_16x16x32_bf16(a, bb, acc[mt], 0, 0, 0);
            }
        }
        const int col = n;
        const float bias = (col < SEM) ? b2[col] : 0.f;
        #pragma unroll
        for (int mt = 0; mt < 4; ++mt)
            #pragma unroll
            for (int r = 0; r < 4; ++r) {
                const int gr = rh * 64 + mt * 16 + q * 4 + r;
                sscg[(long)gr * 320 + col] = (col < SEM) ? f2bf(acc[mt][r] + bias) : (us)0;
            }
        return;
    }
    us (*As)[72] = (us(*)[72])smem;                    // 128*72*2 = 18,432
    us (*Bs)[72] = (us(*)[72])(smem + 18432);          // 320*72*2 = 46,080
    us (*Cs)[HLD] = (us(*)[HLD])smem;                  // epilogue alias
    const int fb = bid - 10;
    const int b = fb / 63;
    const int bm = (fb % 63) * 128;
    const long rowbase = (long)b * NBASE;
    f32x4 acc[8][5];
    #pragma unroll
    for (int i = 0; i < 8; ++i)
        #pragma unroll
        for (int j = 0; j < 5; ++j) acc[i][j] = (f32x4){0.f, 0.f, 0.f, 0.f};
    for (int ks = 0; ks < 5; ++ks) {
        const int k0 = ks * 64;
        #pragma unroll
        for (int it = 0; it < 8; ++it) {
            int c = t + it * 256;
            int row = c >> 4, j = c & 15;
            int gk = k0 + j * 4;
            float4 v = make_float4(0.f, 0.f, 0.f, 0.f);
            if (gk < SEM && bm + row < NBASE)
                v = *(const float4*)(X + (rowbase + bm + row) * SEM + gk);
            us4 u; u.x = f2bf(v.x); u.y = f2bf(v.y); u.z = f2bf(v.z); u.w = f2bf(v.w);
            *(us4*)(&As[row][j * 4]) = u;
        }
        #pragma unroll
        for (int it = 0; it < 10; ++it) {
            int c = t + it * 256;
            int n = c >> 3, j = c & 7;
            int4 v = *(const int4*)(W1T + (long)n * 320 + k0 + j * 8);
            *(int4*)(&Bs[n][j * 8]) = v;
        }
        __syncthreads();
        #pragma unroll
        for (int kc = 0; kc < 64; kc += 32) {
            bf16x8 a[8], bb[5];
            #pragma unroll
            for (int rt = 0; rt < 8; ++rt)
                a[rt] = *(const bf16x8*)(&As[rt * 16 + m16][kc + q * 8]);
            #pragma unroll
            for (int ct = 0; ct < 5; ++ct)
                bb[ct] = *(const bf16x8*)(&Bs[(wv * 5 + ct) * 16 + m16][kc + q * 8]);
            #pragma unroll
            for (int rt = 0; rt < 8; ++rt)
                #pragma unroll
                for (int ct = 0; ct < 5; ++ct)
                    acc[rt][ct] = __builtin_amdgcn_mfma_f32_16x16x32_bf16(a[rt], bb[ct], acc[rt][ct], 0, 0, 0);
        }
        __syncthreads();
    }
    float csum[5] = {0.f, 0.f, 0.f, 0.f, 0.f};
    #pragma unroll
    for (int ct = 0; ct < 5; ++ct) {
        int col = (wv * 5 + ct) * 16 + m16;
        float bias = (col < SEM) ? b1[col] : 0.f;
        #pragma unroll
        for (int rt = 0; rt < 8; ++rt) {
            int rl = rt * 16 + q * 4;
            #pragma unroll
            for (int r = 0; r < 4; ++r) {
                float v = acc[rt][ct][r] + bias;
                v = v > 0.f ? v : 0.1f * v;
                if (col < SEM && bm + rl + r < NBASE) {
                    Cs[rl + r][col] = f2bf(v);
                    csum[ct] += v;
                }
            }
        }
    }
    if (t < 128) *(us4*)(&Cs[t][300]) = (us4){0, 0, 0, 0};
    #pragma unroll
    for (int ct = 0; ct < 5; ++ct) {
        float s = csum[ct];
        s += __shfl_xor(s, 16);
        s += __shfl_xor(s, 32);
        int col = (wv * 5 + ct) * 16 + m16;
        if (q == 0 && col < SEM) atomicAdd(&mh[b * SEM + col], s);
    }
    __syncthreads();
    for (int i = t; i < 128 * 76; i += 256) {
        int row = i / 76, j = i % 76;
        if (bm + row < NBASE)
            *(us4*)(H + (rowbase + bm + row) * HLD + j * 4) = *(const us4*)(&Cs[row][j * 4]);
    }
}

// =============== L4: gates fused with qtot (qtot now 32 blocks of 32 rows) ===============
__global__ __launch_bounds__(256) void k_gates_qtot(
        const float* __restrict__ mbw, const float* __restrict__ mh,
        const float* __restrict__ mw2, const float* __restrict__ mb2,
        const float* __restrict__ vfw, const float* __restrict__ vfb,
        const float* __restrict__ sfw, const float* __restrict__ sfb,
        float* __restrict__ gv, float* __restrict__ gs,
        const us* __restrict__ sfh, const us* __restrict__ sscg,
        const us* __restrict__ qwT, us* __restrict__ qtotg) {
    __shared__ float avgL[CAT];
    __shared__ float mhL[SEM];
    __shared__ float red[4][64];
    const int bid = blockIdx.x;
    const int t = threadIdx.x;
    if (bid < 32) {
        const int ctile = bid % 8, rh = bid / 8;  // rh 0..3, 32 rows each
        const int wv = t >> 6, lane = t & 63;
        const int m16 = lane & 15, q = lane >> 4;
        const int n = ctile * 64 + wv * 16 + m16;
        f32x4 acc[2];
        acc[0] = (f32x4){0.f, 0.f, 0.f, 0.f};
        acc[1] = (f32x4){0.f, 0.f, 0.f, 0.f};
        for (int ks = 0; ks < 26; ++ks) {
            const int k = ks * 32 + q * 8;
            bf16x8 bb = *(const bf16x8*)(qwT + (long)n * 832 + k);
            #pragma unroll
            for (int mt = 0; mt < 2; ++mt) {
                const int gr = rh * 32 + mt * 16 + m16;
                bf16x8 a = (k < FEAT)
                    ? *(const bf16x8*)(sfh + (long)gr * 512 + k)
                    : *(const bf16x8*)(sscg + (long)gr * 320 + (k - FEAT));
                acc[mt] = __builtin_amdgcn_mfma_f32_16x16x32_bf16(a, bb, acc[mt], 0, 0, 0);
            }
        }
        #pragma unroll
        for (int mt = 0; mt < 2; ++mt)
            #pragma unroll
            for (int r = 0; r < 4; ++r) {
                const int gr = rh * 32 + mt * 16 + q * 4 + r;
                qtotg[(long)gr * 512 + n] = f2bf(acc[mt][r]);
            }
        return;
    }
    const int tile = (bid - 32) % 13, b = (bid - 32) / 13;
    const float invN = 1.0f / NBASE;
    for (int i = t; i < SEM; i += 256) mhL[i] = mh[b * SEM + i] * invN;
    for (int i = t; i < FEAT; i += 256) avgL[i] = mbw[b * FEAT + i] * invN;
    __syncthreads();
    for (int s = t; s < SEM; s += 256) {
        float a = mb2[s];
        for (int c = 0; c < SEM; ++c) a += mhL[c] * mw2[(long)c * SEM + s];
        avgL[FEAT + s] = a;
    }
    __syncthreads();
    int l = t & 63, kq = t >> 6;
    float a = 0.f;
    if (tile < 8) {
        int f = tile * 64 + l;
        for (int c = kq * 203; c < kq * 203 + 203; ++c) a += avgL[c] * vfw[(long)c * FEAT + f];
        red[kq][l] = a;
        __syncthreads();
        if (kq == 0) {
            float s = red[0][l] + red[1][l] + red[2][l] + red[3][l] + vfb[f];
            gv[b * FEAT + f] = 1.f + 1.f / (1.f + expf(-s));
        }
    } else {
        int fs = (tile - 8) * 64 + l;
        if (fs < SEM)
            for (int c = kq * 203; c < kq * 203 + 203; ++c) a += avgL[c] * sfw[(long)c * SEM + fs];
        red[kq][l] = a;
        __syncthreads();
        if (kq == 0 && fs < SEM) {
            float s = red[0][l] + red[1][l] + red[2][l] + red[3][l] + sfb[fs];
            gs[b * SEM + fs] = 1.f + 1.f / (1.f + expf(-s));
        }
    }
}

// =============== L5: projections + gate apply + pqt + cconst (52 blocks of 32 rows) ===============
__global__ __launch_bounds__(256) void k_projgate(
        const us* __restrict__ qtotg, const us* __restrict__ wksT,
        const us* __restrict__ wkssT, const float* __restrict__ gv,
        const float* __restrict__ gs, const float* __restrict__ b2,
        us* __restrict__ pqt, us* __restrict__ psemG, float* __restrict__ cconst) {
    const int bid = blockIdx.x;
    const int nslot = bid % 13, rh = bid / 13;  // rh 0..3
    const int t = threadIdx.x;
    const int wv = t >> 6, lane = t & 63;
    const int m16 = lane & 15, q = lane >> 4;
    const bool isv = (nslot < 8);
    const int nc0 = isv ? nslot * 64 : (nslot - 8) * 64;
    const us* BT = isv ? wksT : wkssT;
    const int n = nc0 + wv * 16 + m16;
    f32x4 acc[2];
    acc[0] = (f32x4){0.f, 0.f, 0.f, 0.f};
    acc[1] = (f32x4){0.f, 0.f, 0.f, 0.f};
    for (int ks = 0; ks < 16; ++ks) {
        const int k = ks * 32 + q * 8;
        bf16x8 bb = *(const bf16x8*)(BT + (long)n * 512 + k);
        #pragma unroll
        for (int mt = 0; mt < 2; ++mt) {
            bf16x8 a = *(const bf16x8*)(qtotg + (long)(rh * 32 + mt * 16 + m16) * 512 + k);
            acc[mt] = __builtin_amdgcn_mfma_f32_16x16x32_bf16(a, bb, acc[mt], 0, 0, 0);
        }
    }
    const int col = n;
    if (isv) {
        #pragma unroll
        for (int mt = 0; mt < 2; ++mt)
            #pragma unroll
            for (int r = 0; r < 4; ++r) {
                const int gr = rh * 32 + mt * 16 + q * 4 + r;
                const int b = gr >> 4;
                pqt[(long)gr * 840 + col] = f2bf(acc[mt][r] * gv[b * FEAT + col]);
            }
    } else {
        const float b2c = (col < SEM) ? b2[col] : 0.f;
        #pragma unroll
        for (int mt = 0; mt < 2; ++mt)
            #pragma unroll
            for (int r = 0; r < 4; ++r) {
                const int gr = rh * 32 + mt * 16 + q * 4 + r;
                const int b = gr >> 4;
                float p = (col < SEM) ? acc[mt][r] * gs[b * SEM + col] : 0.f;
                psemG[(long)gr * 320 + col] = (col < SEM) ? f2bf(p) : (us)0;
                float ps = p * b2c;  // cconst = dot(psem_gated, b2)
                ps += __shfl_xor(ps, 1); ps += __shfl_xor(ps, 2);
                ps += __shfl_xor(ps, 4); ps += __shfl_xor(ps, 8);
                if (m16 == 0) atomicAdd(&cconst[b * NWAY + (gr & 15)], ps);
            }
    }
}

// =============== L6: pqt[:,512:812) = psemG @ w2n^T (20 blocks of 32 rows) ===============
__global__ __launch_bounds__(256) void k_sem2(const us* __restrict__ psemG,
        const us* __restrict__ w2n, us* __restrict__ pqt) {
    const int bid = blockIdx.x;
    const int ctile = bid % 5, rh = bid / 5;  // rh 0..3
    const int t = threadIdx.x;
    const int wv = t >> 6, lane = t & 63;
    const int m16 = lane & 15, q = lane >> 4;
    const int n = ctile * 64 + wv * 16 + m16;
    f32x4 acc[2];
    acc[0] = (f32x4){0.f, 0.f, 0.f, 0.f};
    acc[1] = (f32x4){0.f, 0.f, 0.f, 0.f};
    for (int ks = 0; ks < 10; ++ks) {
        const int k = ks * 32 + q * 8;
        bf16x8 bb = *(const bf16x8*)(w2n + (long)n * 320 + k);
        #pragma unroll
        for (int mt = 0; mt < 2; ++mt) {
            bf16x8 a = *(const bf16x8*)(psemG + (long)(rh * 32 + mt * 16 + m16) * 320 + k);
            acc[mt] = __builtin_amdgcn_mfma_f32_16x16x32_bf16(a, bb, acc[mt], 0, 0, 0);
        }
    }
    const int col = n;
    if (col < SEM) {
        #pragma unroll
        for (int mt = 0; mt < 2; ++mt)
            #pragma unroll
            for (int r = 0; r < 4; ++r) {
                const int gr = rh * 32 + mt * 16 + q * 4 + r;
                pqt[(long)gr * 840 + 512 + col] = f2bf(acc[mt][r]);
            }
    }
}

// =============== scores + fused per-block softmax partials (KB=64 stages) ===============
__global__ __launch_bounds__(256) void k_scores_mfma(const us* __restrict__ bwh,
        const us* __restrict__ h, const us* __restrict__ pqt,
        const float* __restrict__ cconst, float* __restrict__ scores,
        float* __restrict__ pmax, float* __restrict__ psum) {
    __shared__ us As[128][72];       // [m][64k] +8 pad
    __shared__ us Bs[NWAY][840];
    __shared__ float sred[4][16];
    const int b = blockIdx.y;
    const int bm = blockIdx.x * 128;
    const int t = threadIdx.x;
    const int wv = t >> 6, lane = t & 63;
    const int m16 = lane & 15, q = lane >> 4;
    for (int c = t; c < NWAY * 105; c += 256) {
        int n = c / 105, j = c % 105;
        *(int4*)(&Bs[n][j * 8]) = *(const int4*)(pqt + ((long)b * NWAY + n) * 840 + j * 8);
    }
    f32x4 acc[2];
    acc[0] = (f32x4){0, 0, 0, 0};
    acc[1] = (f32x4){0, 0, 0, 0};
    for (int ks = 0; ks < 13; ++ks) {
        int k0 = ks * 64;
        #pragma unroll
        for (int it = 0; it < 4; ++it) {
            int c = t + it * 256;
            int row = c >> 3, j = c & 7;
            int gm = bm + row, gk = k0 + j * 8;
            us8 u = (us8){0, 0, 0, 0, 0, 0, 0, 0};
            if (gk < FEAT)      u = *(const us8*)(bwh + ((long)b * NBASE + gm) * FEAT + gk);
            else if (gk < CAT)  u = *(const us8*)(h + ((long)b * NBASE + gm) * HLD + (gk - FEAT));
            *(us8*)(&As[row][j * 8]) = u;
        }
        __syncthreads();
        #pragma unroll
        for (int kc = 0; kc < 64; kc += 32) {
            bf16x8 bb = *(const bf16x8*)(&Bs[m16][k0 + kc + q * 8]);
            #pragma unroll
            for (int rt = 0; rt < 2; ++rt) {
                bf16x8 a = *(const bf16x8*)(&As[wv * 32 + rt * 16 + m16][kc + q * 8]);
                acc[rt] = __builtin_amdgcn_mfma_f32_16x16x32_bf16(a, bb, acc[rt], 0, 0, 0);
            }
        }
        __syncthreads();
    }
    const float invT = 0.04419417382415922f;  // 1/sqrt(512)
    float cadd = cconst[b * NWAY + m16];
    float vals[8];
    #pragma unroll
    for (int rt = 0; rt < 2; ++rt) {
        int nrow = bm + wv * 32 + rt * 16 + q * 4;
        #pragma unroll
        for (int r = 0; r < 4; ++r) {
            float v = (nrow + r < NBASE) ? (acc[rt][r] + cadd) * invT : -1e30f;
            vals[rt * 4 + r] = v;
        }
        if (nrow + 3 < NBASE) {
            float4 st = make_float4(vals[rt * 4], vals[rt * 4 + 1], vals[rt * 4 + 2], vals[rt * 4 + 3]);
            *(float4*)(scores + ((long)b * NWAY + m16) * NBASE + nrow) = st;
        } else {
            for (int r = 0; r < 4; ++r)
                if (nrow + r < NBASE)
                    scores[((long)b * NWAY + m16) * NBASE + nrow + r] = vals[rt * 4 + r];
        }
    }
    float lm = vals[0];
    #pragma unroll
    for (int i = 1; i < 8; ++i) lm = fmaxf(lm, vals[i]);
    lm = fmaxf(lm, __shfl_xor(lm, 16));
    lm = fmaxf(lm, __shfl_xor(lm, 32));
    if (q == 0) sred[wv][m16] = lm;
    __syncthreads();
    float bmax = fmaxf(fmaxf(sred[0][m16], sred[1][m16]), fmaxf(sred[2][m16], sred[3][m16]));
    __syncthreads();
    float ls = 0.f;
    #pragma unroll
    for (int i = 0; i < 8; ++i) ls += __expf(vals[i] - bmax);
    ls += __shfl_xor(ls, 16);
    ls += __shfl_xor(ls, 32);
    if (q == 0) sred[wv][m16] = ls;
    __syncthreads();
    if (wv == 0 && lane < 16) {
        float tot = sred[0][m16] + sred[1][m16] + sred[2][m16] + sred[3][m16];
        pmax[((long)b * NWAY + m16) * 63 + blockIdx.x] = bmax;
        psum[((long)b * NWAY + m16) * 63 + blockIdx.x] = tot;
    }
}

// =============== ov = softmax(scores) @ bwh, combine folded in ===============
__global__ void k_ov(const float* __restrict__ scores, const float* __restrict__ pmax,
                     const float* __restrict__ psum, const us* __restrict__ bwh,
                     float* __restrict__ ov) {
    int b = blockIdx.x, ch = blockIdx.y;  // 50 chunks of 160 rows
    int t = threadIdx.x;
    __shared__ float pr[NWAY][160];
    __shared__ float rm[NWAY], ri[NWAY];
    {   // redundant per-block combine (reads 63x16 partials, L2-hot)
        int w = t >> 4, l = t & 15;
        long base = ((long)b * NWAY + w) * 63;
        float m = -1e30f;
        for (int i = l; i < 63; i += 16) m = fmaxf(m, pmax[base + i]);
        m = fmaxf(m, __shfl_xor(m, 1)); m = fmaxf(m, __shfl_xor(m, 2));
        m = fmaxf(m, __shfl_xor(m, 4)); m = fmaxf(m, __shfl_xor(m, 8));
        float s = 0.f;
        for (int i = l; i < 63; i += 16) s += psum[base + i] * __expf(pmax[base + i] - m);
        s += __shfl_xor(s, 1); s += __shfl_xor(s, 2);
        s += __shfl_xor(s, 4); s += __shfl_xor(s, 8);
        if (l == 0) { rm[w] = m; ri[w] = 1.0f / s; }
    }
    __syncthreads();
    for (int i = t; i < NWAY * 160; i += 256) {
        int w = i / 160, j = i % 160;
        float sc = scores[((long)b * NWAY + w) * NBASE + (long)ch * 160 + j];
        pr[w][j] = __expf(sc - rm[w]) * ri[w];
    }
    __syncthreads();
    float a0[NWAY], a1[NWAY];
    #pragma unroll
    for (int w = 0; w < NWAY; ++w) { a0[w] = 0.f; a1[w] = 0.f; }
    const us* bp = bwh + ((long)b * NBASE + (long)ch * 160) * FEAT + 2 * t;
    for (int j0 = 0; j0 < 160; j0 += 8) {
        us2 u[8];
        #pragma unroll
        for (int uu = 0; uu < 8; ++uu)
            u[uu] = *(const us2*)(bp + (long)(j0 + uu) * FEAT);
        #pragma unroll
        for (int uu = 0; uu < 8; ++uu) {
            float v0 = bf2f(u[uu].x), v1 = bf2f(u[uu].y);
            #pragma unroll
            for (int w = 0; w < NWAY; ++w) {
                a0[w] += pr[w][j0 + uu] * v0;
                a1[w] += pr[w][j0 + uu] * v1;
            }
        }
    }
    for (int w = 0; w < NWAY; ++w) {
        atomicAdd(&ov[((long)b * NWAY + w) * FEAT + 2 * t], a0[w]);
        atomicAdd(&ov[((long)b * NWAY + w) * FEAT + 2 * t + 1], a1[w]);
    }
}

// =============== k_out1: tmp = bf16(ov) @ wvsT, 32 blocks of 32 rows ===============
__global__ __launch_bounds__(256) void k_out1(const float* __restrict__ ov,
        const us* __restrict__ wvsT, us* __restrict__ tmp) {
    const int bid = blockIdx.x;
    const int ctile = bid & 7, rh = bid >> 3;  // rh 0..3
    const int t = threadIdx.x;
    const int wv = t >> 6, lane = t & 63;
    const int m16 = lane & 15, q = lane >> 4;
    const int n = ctile * 64 + wv * 16 + m16;
    f32x4 acc[2];
    acc[0] = (f32x4){0.f, 0.f, 0.f, 0.f};
    acc[1] = (f32x4){0.f, 0.f, 0.f, 0.f};
    #pragma unroll 4
    for (int ks = 0; ks < 16; ++ks) {
        const int k = ks * 32 + q * 8;
        bf16x8 bb = *(const bf16x8*)(wvsT + (long)n * 512 + k);
        #pragma unroll
        for (int mt = 0; mt < 2; ++mt) {
            const float* ap = ov + (long)(rh * 32 + mt * 16 + m16) * 512 + k;
            float4 x = *(const float4*)ap, y = *(const float4*)(ap + 4);
            bf16x8 a;
            a[0] = (short)f2bf(x.x); a[1] = (short)f2bf(x.y);
            a[2] = (short)f2bf(x.z); a[3] = (short)f2bf(x.w);
            a[4] = (short)f2bf(y.x); a[5] = (short)f2bf(y.y);
            a[6] = (short)f2bf(y.z); a[7] = (short)f2bf(y.w);
            acc[mt] = __builtin_amdgcn_mfma_f32_16x16x32_bf16(a, bb, acc[mt], 0, 0, 0);
        }
    }
    #pragma unroll
    for (int mt = 0; mt < 2; ++mt)
        #pragma unroll
        for (int r = 0; r < 4; ++r) {
            const int gr = rh * 32 + mt * 16 + q * 4 + r;
            tmp[(long)gr * 512 + n] = f2bf(acc[mt][r]);
        }
}

// =============== k_out2: out = tmp @ fcwT + sf, 32 blocks of 32 rows ===============
__global__ __launch_bounds__(256) void k_out2(const us* __restrict__ tmp,
        const us* __restrict__ fcwT, const float* __restrict__ sf,
        float* __restrict__ out) {
    const int bid = blockIdx.x;
    const int ctile = bid & 7, rh = bid >> 3;  // rh 0..3
    const int t = threadIdx.x;
    const int wv = t >> 6, lane = t & 63;
    const int m16 = lane & 15, q = lane >> 4;
    const int n = ctile * 64 + wv * 16 + m16;
    f32x4 acc[2];
    acc[0] = (f32x4){0.f, 0.f, 0.f, 0.f};
    acc[1] = (f32x4){0.f, 0.f, 0.f, 0.f};
    #pragma unroll 4
    for (int ks = 0; ks < 16; ++ks) {
        const int k = ks * 32 + q * 8;
        bf16x8 bb = *(const bf16x8*)(fcwT + (long)n * 512 + k);
        #pragma unroll
        for (int mt = 0; mt < 2; ++mt) {
            bf16x8 a = *(const bf16x8*)(tmp + (long)(rh * 32 + mt * 16 + m16) * 512 + k);
            acc[mt] = __builtin_amdgcn_mfma_f32_16x16x32_bf16(a, bb, acc[mt], 0, 0, 0);
        }
    }
    #pragma unroll
    for (int mt = 0; mt < 2; ++mt)
        #pragma unroll
        for (int r = 0; r < 4; ++r) {
            const long gr = rh * 32 + mt * 16 + q * 4 + r;
            out[gr * FEAT + n] = acc[mt][r] + sf[gr * FEAT + n];
        }
}

extern "C" void kernel_launch(void* const* d_in, const int* in_sizes, int n_in,
                              void* d_out, int out_size, void* d_ws, size_t ws_size,
                              hipStream_t stream) {
    (void)in_sizes; (void)n_in; (void)out_size; (void)ws_size;
    const float* sf   = (const float*)d_in[0];
    const float* bw   = (const float*)d_in[1];
    const float* ssm  = (const float*)d_in[2];
    const float* bsm  = (const float*)d_in[3];
    const float* mw1  = (const float*)d_in[4];
    const float* mb1  = (const float*)d_in[5];
    const float* mw2  = (const float*)d_in[6];
    const float* mb2  = (const float*)d_in[7];
    const float* vfw  = (const float*)d_in[8];
    const float* vfb  = (const float*)d_in[9];
    const float* sfw  = (const float*)d_in[10];
    const float* sfb  = (const float*)d_in[11];
    const float* wqs  = (const float*)d_in[12];
    const float* wks  = (const float*)d_in[13];
    const float* wvs  = (const float*)d_in[14];
    const float* wqss = (const float*)d_in[15];
    const float* wkss = (const float*)d_in[16];
    const float* fcw  = (const float*)d_in[17];

    float* out = (float*)d_out;
    float* scores = out + NB * NWAY * FEAT;  // d_out = [out | attn_score]

    char* wsb = (char*)d_ws;
    us* bwh    = (us*)(wsb + O_BWH);
    us* h      = (us*)(wsb + O_H);
    us* w1t    = (us*)(wsb + O_W1T);
    us* w2t    = (us*)(wsb + O_W2T);
    us* qwT    = (us*)(wsb + O_QWT);
    us* wvsT   = (us*)(wsb + O_WVST);
    us* fcwT   = (us*)(wsb + O_FCWT);
    us* pqt    = (us*)(wsb + O_PQT);
    us* wksT   = (us*)(wsb + O_WKST);
    us* wkssT  = (us*)(wsb + O_WKSST);
    us* w2n    = (us*)(wsb + O_W2N);
    us* sfh    = (us*)(wsb + O_SFH);
    us* ssmh   = (us*)(wsb + O_SSMH);
    us* h1g    = (us*)(wsb + O_H1G);
    us* sscg   = (us*)(wsb + O_SSCG);
    us* qtotg  = (us*)(wsb + O_QTG);
    us* psemG  = (us*)(wsb + O_PSG);
    float* pmax   = (float*)(wsb + O_PMAX);
    float* psum   = (float*)(wsb + O_PSUM);
    float* mbw    = (float*)(wsb + O_MBW);
    float* mh     = (float*)(wsb + O_MH);
    float* gv     = (float*)(wsb + O_GV);
    float* gs     = (float*)(wsb + O_GS);
    float* ov     = (float*)(wsb + O_OV);
    float* cconst = (float*)(wsb + O_CC);

    k_tr<<<dim3(104, 5), 256, 0, stream>>>(mw1, mw2, wqs, wqss, wvs, fcw,
                                           w1t, w2t, qwT, wvsT, fcwT);
    k_prep<<<dim3(1024, 6), 256, 0, stream>>>(wks, wkss, mw2, sf, ssm,
                                              wksT, wkssT, w2n, sfh, ssmh,
                                              mbw, cconst, pqt, ov);
    k_cvt_mlp1<<<1010, 256, 0, stream>>>(bw, bwh, mbw, ssmh, w1t, mb1, h1g);
    k_hg_mlp2<<<514, 256, 0, stream>>>(bsm, w1t, mb1, h, mh, h1g, w2t, mb2, sscg);
    k_gates_qtot<<<136, 256, 0, stream>>>(mbw, mh, mw2, mb2, vfw, vfb, sfw, sfb, gv, gs,
                                          sfh, sscg, qwT, qtotg);
    k_projgate<<<52, 256, 0, stream>>>(qtotg, wksT, wkssT, gv, gs, mb2, pqt, psemG, cconst);
    k_sem2<<<20, 256, 0, stream>>>(psemG, w2n, pqt);
    k_scores_mfma<<<dim3(63, NB), 256, 0, stream>>>(bwh, h, pqt, cconst, scores, pmax, psum);
    k_ov<<<dim3(NB, 50), 256, 0, stream>>>(scores, pmax, psum, bwh, ov);
    k_out1<<<32, 256, 0, stream>>>(ov, wvsT, qtotg);
    k_out2<<<32, 256, 0, stream>>>(qtotg, fcwT, sf, out);
}